// Round 17
// baseline (127.190 us; speedup 1.0000x reference)
//
#include <hip/hip_runtime.h>
#include <hip/hip_bf16.h>
#include <hip/hip_fp16.h>
#include <math.h>

#define Bb 2
#define NQn 256
#define NSn 1024
#define Dn 256
#define Hn 8
#define DHn 32
#define FFNn 1024
#define RPEn 512
#define SCALEf 0.17677669529663687f
#define EPSf 1e-5f

// async global->LDS, 16B per lane. LDS dest must be linear in lane order
// (wave-uniform base + lane*16); global src is per-lane (pre-swizzled).
#define GLDS16(g, l)                                                         \
  __builtin_amdgcn_global_load_lds(                                          \
      (const __attribute__((address_space(1))) void*)(const void*)(g),       \
      (__attribute__((address_space(3))) void*)(void*)(l), 16, 0, 0)

// ---------------------------------------------------------------------------
// gemm64 body: 64x64 tile, 512 threads, K-step 32, float4 loads, reg prefetch.
// trsh != 0: write transposed head-major FP16 Ch[((b*H+h)<<trsh)+kseq][32].
// ---------------------------------------------------------------------------
__device__ __forceinline__ void gemm64_body(
    float* __restrict__ C, __half* __restrict__ Ch, int ldc,
    const float* __restrict__ A, const float* __restrict__ A2, int ld,
    const float* __restrict__ W, const float* __restrict__ bias,
    int K, int bm, int bnC, int bnW, float scale, int do_relu, int trsh,
    float (*As)[33], float (*WsT)[68])
{
  const int tid = threadIdx.x;
  const int tx = tid & 15, ty = tid >> 4;       // ty 0..31
  const int lr = tid >> 3, lc = (tid & 7) * 4;  // staging coords
  float4 ra, rw;
  {
    ra = *(const float4*)(A + (size_t)(bm + lr) * ld + lc);
    if (A2) {
      float4 t = *(const float4*)(A2 + (size_t)(bm + lr) * ld + lc);
      ra.x += t.x; ra.y += t.y; ra.z += t.z; ra.w += t.w;
    }
    rw = *(const float4*)(W + (size_t)(bnW + lr) * ld + lc);
  }
  float acc[2][4] = {};
  for (int k0 = 0; k0 < K; k0 += 32) {
    As[lr][lc] = ra.x; As[lr][lc + 1] = ra.y;
    As[lr][lc + 2] = ra.z; As[lr][lc + 3] = ra.w;
    WsT[lc][lr] = rw.x; WsT[lc + 1][lr] = rw.y;
    WsT[lc + 2][lr] = rw.z; WsT[lc + 3][lr] = rw.w;
    __syncthreads();
    if (k0 + 32 < K) {
      ra = *(const float4*)(A + (size_t)(bm + lr) * ld + k0 + 32 + lc);
      if (A2) {
        float4 t = *(const float4*)(A2 + (size_t)(bm + lr) * ld + k0 + 32 + lc);
        ra.x += t.x; ra.y += t.y; ra.z += t.z; ra.w += t.w;
      }
      rw = *(const float4*)(W + (size_t)(bnW + lr) * ld + k0 + 32 + lc);
    }
#pragma unroll
    for (int k = 0; k < 32; ++k) {
      float a0 = As[ty][k], a1 = As[ty + 32][k];
      float4 w = *(const float4*)&WsT[k][tx * 4];
      acc[0][0] += a0 * w.x; acc[0][1] += a0 * w.y;
      acc[0][2] += a0 * w.z; acc[0][3] += a0 * w.w;
      acc[1][0] += a1 * w.x; acc[1][1] += a1 * w.y;
      acc[1][2] += a1 * w.z; acc[1][3] += a1 * w.w;
    }
    __syncthreads();
  }
#pragma unroll
  for (int i = 0; i < 2; ++i) {
    int m = bm + ty + i * 32;
#pragma unroll
    for (int j = 0; j < 4; ++j) {
      float v = acc[i][j];
      if (bias) v += bias[bnW + tx * 4 + j];
      v *= scale;
      if (do_relu) v = fmaxf(v, 0.f);
      if (trsh == 0) {
        C[(size_t)m * ldc + bnC + tx * 4 + j] = v;
      } else {
        const int nC = bnC + tx * 4 + j;
        const int bb = m >> trsh, kseq = m & ((1 << trsh) - 1);
        const int hh = nC >> 5, d = nC & 31;
        Ch[((((size_t)(bb * Hn + hh)) << trsh) + kseq) * 32 + d] =
            __float2half(v);
      }
    }
  }
}

// ---------------------------------------------------------------------------
// prep: build_cpb (1 blk) + self QKV (96) + cross KV (256) + qpos@qw^T (32)
// + LN-fold vector precomputes (3). 512 threads/block, 388 blocks.
// ---------------------------------------------------------------------------
__global__ __launch_bounds__(512) void prep_kernel(
    float* __restrict__ qSb, __half* __restrict__ kSb, __half* __restrict__ vSb,
    __half* __restrict__ kCb, __half* __restrict__ vCb,
    const float* __restrict__ tgt, const float* __restrict__ qpos,
    const float* __restrict__ src, const float* __restrict__ spe,
    const float* __restrict__ ipw, const float* __restrict__ ipb,
    const float* __restrict__ kw, const float* __restrict__ kb,
    const float* __restrict__ vw, const float* __restrict__ vb,
    const float* __restrict__ w1p, const float* __restrict__ b1p,
    const float* __restrict__ w2p,
    float* __restrict__ tout, float* __restrict__ Stab, float* __restrict__ Btab,
    const float* __restrict__ qw, const float* __restrict__ qb,
    const float* __restrict__ ln2g, const float* __restrict__ ln2b,
    const float* __restrict__ ln1g, const float* __restrict__ ln1b,
    const float* __restrict__ ff1w, const float* __restrict__ ff1b,
    float* __restrict__ qposq, float* __restrict__ gq, float* __restrict__ cqv,
    float* __restrict__ gf, float* __restrict__ bfv)
{
  __shared__ float smem[4288];  // As 64*33=2112 + WsT 32*68=2176
  const int bx = blockIdx.x;
  const int tid = threadIdx.x;
  if (bx < 96) {
    float (*As)[33] = (float(*)[33])smem;
    float (*WsT)[68] = (float(*)[68])(smem + 2112);
    int my = bx & 7, nx = bx >> 3;
    int sec = nx >> 2;
    gemm64_body(qSb, sec == 1 ? kSb : vSb, Dn, tgt,
                sec < 2 ? qpos : nullptr, Dn, ipw, ipb,
                Dn, my * 64, (nx & 3) * 64, nx * 64,
                sec == 0 ? SCALEf : 1.f, 0, sec == 0 ? 0 : 8, As, WsT);
    return;
  }
  if (bx < 96 + 256) {
    float (*As)[33] = (float(*)[33])smem;
    float (*WsT)[68] = (float(*)[68])(smem + 2112);
    int idx = bx - 96;
    int my = idx & 31, nx = idx >> 5;
    int sec = nx >> 2;
    gemm64_body(nullptr, sec ? vCb : kCb, Dn, src, sec ? nullptr : spe, Dn,
                sec ? vw : kw, sec ? vb : kb,
                Dn, my * 64, (nx & 3) * 64, (nx & 3) * 64, 1.f, 0, 10, As, WsT);
    return;
  }
  if (bx >= 353 && bx < 385) {
    // qposq = qpos @ qw^T (moves cross-q's qpos term off the critical chain)
    float (*As)[33] = (float(*)[33])smem;
    float (*WsT)[68] = (float(*)[68])(smem + 2112);
    int idx = bx - 353;
    int my = idx & 7, nx = idx >> 3;
    gemm64_body(qposq, nullptr, Dn, qpos, nullptr, Dn, qw, nullptr,
                Dn, my * 64, nx * 64, nx * 64, 1.f, 0, 0, As, WsT);
    return;
  }
  if (bx == 385) {
    // gq[n] = ln2g @ qw[n]; cqv[n] = ln2b @ qw[n] + qb[n]
    if (tid < 256) {
      float s = 0.f;
      for (int k = 0; k < Dn; k += 4) {
        float4 g4 = *(const float4*)(ln2g + k);
        float4 w4 = *(const float4*)(qw + (size_t)tid * Dn + k);
        s += g4.x * w4.x + g4.y * w4.y + g4.z * w4.z + g4.w * w4.w;
      }
      gq[tid] = s;
    } else {
      const int n = tid - 256;
      float s = 0.f;
      for (int k = 0; k < Dn; k += 4) {
        float4 b4 = *(const float4*)(ln2b + k);
        float4 w4 = *(const float4*)(qw + (size_t)n * Dn + k);
        s += b4.x * w4.x + b4.y * w4.y + b4.z * w4.z + b4.w * w4.w;
      }
      cqv[n] = s + qb[n];
    }
    return;
  }
  if (bx == 386 || bx == 387) {
    // gf[n] = ln1g @ ff1w[n]; bfv[n] = ln1b @ ff1w[n] + ff1b[n]
    const int n = (bx - 386) * 512 + tid;
    float sg = 0.f, sb = 0.f;
    for (int k = 0; k < Dn; k += 4) {
      float4 g4 = *(const float4*)(ln1g + k);
      float4 b4 = *(const float4*)(ln1b + k);
      float4 w4 = *(const float4*)(ff1w + (size_t)n * Dn + k);
      sg += g4.x * w4.x + g4.y * w4.y + g4.z * w4.z + g4.w * w4.w;
      sb += b4.x * w4.x + b4.y * w4.y + b4.z * w4.z + b4.w * w4.w;
    }
    gf[n] = sg;
    bfv[n] = sb + ff1b[n];
    return;
  }
  // ---- bx == 352: cpb piecewise-linear table build (verified r1-16) ----
  float* key = smem;
  int* pidx = (int*)(smem + 512);
  float* w1s = smem + 1024;
  float* b1s = smem + 1536;
  {
    float w = w1p[tid], bb = b1p[tid];
    key[tid] = (w != 0.f) ? (-bb / w) : 3.0e38f;
    pidx[tid] = tid;
  }
  __syncthreads();
  for (int k = 2; k <= RPEn; k <<= 1) {
    for (int j = k >> 1; j > 0; j >>= 1) {
      int ixj = tid ^ j;
      if (ixj > tid) {
        float a = key[tid], c = key[ixj];
        bool asc = ((tid & k) == 0);
        bool sw = asc ? (a > c) : (a < c);
        if (sw) {
          key[tid] = c; key[ixj] = a;
          int tmp = pidx[tid]; pidx[tid] = pidx[ixj]; pidx[ixj] = tmp;
        }
      }
      __syncthreads();
    }
  }
  w1s[tid] = w1p[pidx[tid]];
  b1s[tid] = b1p[pidx[tid]];
  tout[tid] = key[tid];
  __syncthreads();
  const int lane = tid & 63;
  const int h = tid >> 6;
  const int j0 = lane * 8;
  float sp[8], bp[8], sn[8], bn[8];
  float csp = 0.f, cbp = 0.f, csn = 0.f, cbn = 0.f, ccc = 0.f;
#pragma unroll
  for (int e = 0; e < 8; ++e) {
    int j = j0 + e;
    float w = w1s[j], b = b1s[j];
    float c = w2p[h * RPEn + pidx[j]];
    sp[e] = csp; bp[e] = cbp; sn[e] = csn; bn[e] = cbn;
    if (w > 0.f)      { csp += w * c; cbp += b * c; }
    else if (w < 0.f) { csn += w * c; cbn += b * c; }
    else              { ccc += fmaxf(b, 0.f) * c; }
  }
  float isp = csp, ibp = cbp, isn = csn, ibn = cbn, icc = ccc;
#pragma unroll
  for (int d = 1; d < 64; d <<= 1) {
    float t0 = __shfl_up(isp, d);
    float t1 = __shfl_up(ibp, d);
    float t2 = __shfl_up(isn, d);
    float t3 = __shfl_up(ibn, d);
    if (lane >= d) { isp += t0; ibp += t1; isn += t2; ibn += t3; }
    icc += __shfl_xor(icc, d);
  }
  const float tsn = __shfl(isn, 63);
  const float tbn = __shfl(ibn, 63);
  const float esp = isp - csp, ebp = ibp - cbp;
  const float esn = isn - csn, ebn = ibn - cbn;
#pragma unroll
  for (int e = 0; e < 8; ++e) {
    int j = j0 + e;
    Stab[j * Hn + h] = (esp + sp[e]) + (tsn - (esn + sn[e]));
    Btab[j * Hn + h] = (ebp + bp[e]) + (tbn - (ebn + bn[e])) + icc;
  }
  if (lane == 63) {
    Stab[RPEn * Hn + h] = isp;
    Btab[RPEn * Hn + h] = ibp + icc;
  }
}

// ---------------------------------------------------------------------------
// bias body: fp16 bias[b,h,q,k] = Sh[lo]*m + Bh[lo] - 100*pad. One block per
// (b,q); search once per (b,q,k), applied to 8 heads. LDS carved from smem.
// ---------------------------------------------------------------------------
__device__ __forceinline__ void bias_body(
    char* smemraw, int idx,
    __half* __restrict__ biasb, const float* __restrict__ rel,
    const float* __restrict__ pad, const float* __restrict__ tsg,
    const float* __restrict__ Stabg, const float* __restrict__ Btabg)
{
  float* ts = (float*)smemraw;                    // 512 f
  float* Sh = (float*)(smemraw + 2048);           // 4104 f
  float* Bh = (float*)(smemraw + 18464);          // 4104 f
  const int tid = threadIdx.x;
  const int b = idx >> 8, q = idx & 255;
  ts[tid] = tsg[tid];
  ts[tid + 256] = tsg[tid + 256];
  for (int i = tid; i < (RPEn + 1) * Hn; i += 256) {
    Sh[i] = Stabg[i];
    Bh[i] = Btabg[i];
  }
  __syncthreads();
#pragma unroll
  for (int j = 0; j < 4; ++j) {
    const int k = tid + j * 256;
    const float m = rel[((size_t)b * NQn + q) * NSn + k];
    const float padv = -100.f * pad[b * NSn + k];
    int lo = 0, hi = RPEn;
#pragma unroll
    for (int it = 0; it < 9; ++it) {
      int mid = (lo + hi) >> 1;
      if (ts[mid] < m) lo = mid + 1; else hi = mid;
    }
#pragma unroll
    for (int h = 0; h < Hn; ++h) {
      biasb[(((size_t)(b * Hn + h)) * NQn + q) * NSn + k] =
          __float2half(Sh[lo * Hn + h] * m + Bh[lo * Hn + h] + padv);
    }
  }
}

// ---------------------------------------------------------------------------
// Flash body (verified rounds 14-16), templated on CHUNK.
// ---------------------------------------------------------------------------
template <int CHUNK>
__device__ __forceinline__ void flash_body(
    char* smemraw, int qb, int bh,
    float* __restrict__ O, const float* __restrict__ Q,
    const __half* __restrict__ kT, const __half* __restrict__ vT,
    const __half* __restrict__ biasb, int NK)
{
  constexpr int NJ = CHUNK / 64;
  constexpr int NS = CHUNK / 64;
  float4 (*Ks)[CHUNK * 4] = (float4(*)[CHUNK * 4])smemraw;
  float4 (*Vs)[CHUNK * 4] = (float4(*)[CHUNK * 4])(smemraw + CHUNK * 128);
  float4* Qs = (float4*)(smemraw + CHUNK * 256);
  const int b = bh >> 3, h = bh & 7;
  const int q0 = qb * 8;
  const int tid = threadIdx.x;
  const int w = tid >> 6, kc = tid & 63;
  const float4* Ktp = (const float4*)kT + (size_t)bh * NK * 4;
  const float4* Vtp = (const float4*)vT + (size_t)bh * NK * 4;
  if (tid < 64)
    Qs[tid] = ((const float4*)Q)[(size_t)(b * NQn + q0 + (tid >> 3)) * 64 +
                                 h * 8 + (tid & 7)];

  const __half* brow0 =
      biasb ? biasb + ((size_t)bh * NQn + q0 + 2 * w) * NK : nullptr;
  const __half* brow1 = biasb ? brow0 + NK : nullptr;

  auto stage = [&](int buf, int kb0) {
#pragma unroll
    for (int u = 0; u < NS; ++u) {
      const int s = tid + u * 256;
      const int k = s >> 2, e = s & 3;
      const int ok = (k + (k >> 2)) & 3;
      const int g = (kb0 + k) * 4 + ((e - ok) & 3);
      GLDS16(Ktp + g, &Ks[buf][s]);
      GLDS16(Vtp + g, &Vs[buf][s]);
    }
  };

  stage(0, 0);
  float cb[2][NJ];
  if (biasb) {
#pragma unroll
    for (int j = 0; j < NJ; ++j) {
      cb[0][j] = __half2float(brow0[kc + j * 64]);
      cb[1][j] = __half2float(brow1[kc + j * 64]);
    }
  }
  __syncthreads();

  float4 q[2][8];
#pragma unroll
  for (int dd = 0; dd < 8; ++dd) {
    q[0][dd] = Qs[(2 * w) * 8 + dd];
    q[1][dd] = Qs[(2 * w + 1) * 8 + dd];
  }
  float4 o[2][8] = {};
  float m_run[2] = {-3.0e38f, -3.0e38f};
  float l_run[2] = {0.f, 0.f};
  const int nchunk = NK / CHUNK;
  const int ox = (kc + (kc >> 2)) & 3;

  for (int c = 0; c < nchunk; ++c) {
    const int cur = c & 1;
    float nb[2][NJ];
    if (c + 1 < nchunk) {
      stage(cur ^ 1, (c + 1) * CHUNK);
      if (biasb) {
#pragma unroll
        for (int j = 0; j < NJ; ++j) {
          nb[0][j] = __half2float(brow0[(c + 1) * CHUNK + kc + j * 64]);
          nb[1][j] = __half2float(brow1[(c + 1) * CHUNK + kc + j * 64]);
        }
      }
    }
    float s[2][NJ];
#pragma unroll
    for (int j = 0; j < NJ; ++j) {
      const int kbase = (kc + j * 64) * 4;
      float a0 = 0.f, a1 = 0.f;
#pragma unroll
      for (int u = 0; u < 4; ++u) {
        float4 raw = Ks[cur][kbase + ((u + ox) & 3)];
        const __half2* hp = (const __half2*)&raw;
        float2 f0 = __half22float2(hp[0]);
        float2 f1 = __half22float2(hp[1]);
        float2 f2 = __half22float2(hp[2]);
        float2 f3 = __half22float2(hp[3]);
        a0 += q[0][2 * u].x * f0.x + q[0][2 * u].y * f0.y +
              q[0][2 * u].z * f1.x + q[0][2 * u].w * f1.y +
              q[0][2 * u + 1].x * f2.x + q[0][2 * u + 1].y * f2.y +
              q[0][2 * u + 1].z * f3.x + q[0][2 * u + 1].w * f3.y;
        a1 += q[1][2 * u].x * f0.x + q[1][2 * u].y * f0.y +
              q[1][2 * u].z * f1.x + q[1][2 * u].w * f1.y +
              q[1][2 * u + 1].x * f2.x + q[1][2 * u + 1].y * f2.y +
              q[1][2 * u + 1].z * f3.x + q[1][2 * u + 1].w * f3.y;
      }
      s[0][j] = a0;
      s[1][j] = a1;
      if (biasb) { s[0][j] += cb[0][j]; s[1][j] += cb[1][j]; }
    }
    float f[2];
#pragma unroll
    for (int r = 0; r < 2; ++r) {
      float cmax = s[r][0];
#pragma unroll
      for (int j = 1; j < NJ; ++j) cmax = fmaxf(cmax, s[r][j]);
#pragma unroll
      for (int off = 1; off < 64; off <<= 1)
        cmax = fmaxf(cmax, __shfl_xor(cmax, off));
      const float m_new = fmaxf(m_run[r], cmax);
      f[r] = __expf(m_run[r] - m_new);
      float ls = 0.f;
#pragma unroll
      for (int j = 0; j < NJ; ++j) {
        s[r][j] = __expf(s[r][j] - m_new);
        ls += s[r][j];
      }
#pragma unroll
      for (int off = 1; off < 64; off <<= 1) ls += __shfl_xor(ls, off);
      l_run[r] = l_run[r] * f[r] + ls;
      m_run[r] = m_new;
    }
#pragma unroll
    for (int dd = 0; dd < 8; ++dd) {
      o[0][dd].x *= f[0]; o[0][dd].y *= f[0]; o[0][dd].z *= f[0]; o[0][dd].w *= f[0];
      o[1][dd].x *= f[1]; o[1][dd].y *= f[1]; o[1][dd].z *= f[1]; o[1][dd].w *= f[1];
    }
#pragma unroll
    for (int j = 0; j < NJ; ++j) {
      const int kbase = (kc + j * 64) * 4;
      const float p0 = s[0][j], p1 = s[1][j];
#pragma unroll
      for (int u = 0; u < 4; ++u) {
        float4 raw = Vs[cur][kbase + ((u + ox) & 3)];
        const __half2* hp = (const __half2*)&raw;
        float2 f0 = __half22float2(hp[0]);
        float2 f1 = __half22float2(hp[1]);
        float2 f2 = __half22float2(hp[2]);
        float2 f3 = __half22float2(hp[3]);
        o[0][2 * u].x += p0 * f0.x; o[0][2 * u].y += p0 * f0.y;
        o[0][2 * u].z += p0 * f1.x; o[0][2 * u].w += p0 * f1.y;
        o[0][2 * u + 1].x += p0 * f2.x; o[0][2 * u + 1].y += p0 * f2.y;
        o[0][2 * u + 1].z += p0 * f3.x; o[0][2 * u + 1].w += p0 * f3.y;
        o[1][2 * u].x += p1 * f0.x; o[1][2 * u].y += p1 * f0.y;
        o[1][2 * u].z += p1 * f1.x; o[1][2 * u].w += p1 * f1.y;
        o[1][2 * u + 1].x += p1 * f2.x; o[1][2 * u + 1].y += p1 * f2.y;
        o[1][2 * u + 1].z += p1 * f3.x; o[1][2 * u + 1].w += p1 * f3.y;
      }
    }
    if (biasb && c + 1 < nchunk) {
#pragma unroll
      for (int j = 0; j < NJ; ++j) {
        cb[0][j] = nb[0][j];
        cb[1][j] = nb[1][j];
      }
    }
    __syncthreads();
  }
#pragma unroll
  for (int off = 1; off < 64; off <<= 1) {
#pragma unroll
    for (int dd = 0; dd < 8; ++dd) {
      o[0][dd].x += __shfl_xor(o[0][dd].x, off);
      o[0][dd].y += __shfl_xor(o[0][dd].y, off);
      o[0][dd].z += __shfl_xor(o[0][dd].z, off);
      o[0][dd].w += __shfl_xor(o[0][dd].w, off);
      o[1][dd].x += __shfl_xor(o[1][dd].x, off);
      o[1][dd].y += __shfl_xor(o[1][dd].y, off);
      o[1][dd].z += __shfl_xor(o[1][dd].z, off);
      o[1][dd].w += __shfl_xor(o[1][dd].w, off);
    }
  }
  if (kc == 0) {
    const float inv = 1.f / l_run[0];
#pragma unroll
    for (int dd = 0; dd < 8; ++dd) {
      float4 v = o[0][dd];
      v.x *= inv; v.y *= inv; v.z *= inv; v.w *= inv;
      ((float4*)O)[(size_t)(b * NQn + q0 + 2 * w) * 64 + h * 8 + dd] = v;
    }
  } else if (kc == 1) {
    const float inv = 1.f / l_run[1];
#pragma unroll
    for (int dd = 0; dd < 8; ++dd) {
      float4 v = o[1][dd];
      v.x *= inv; v.y *= inv; v.z *= inv; v.w *= inv;
      ((float4*)O)[(size_t)(b * NQn + q0 + 2 * w + 1) * 64 + h * 8 + dd] = v;
    }
  }
}

// ---------------------------------------------------------------------------
// fsb: fused flash-self (blocks 0..511, CHUNK=128) + bias materialization.
// ---------------------------------------------------------------------------
__global__ __launch_bounds__(256, 2) void fsb_kernel(
    float* __restrict__ O, const float* __restrict__ Q,
    const __half* __restrict__ kT, const __half* __restrict__ vT,
    __half* __restrict__ biasb, const float* __restrict__ rel,
    const float* __restrict__ pad, const float* __restrict__ tsg,
    const float* __restrict__ Stabg, const float* __restrict__ Btabg)
{
  __shared__ __align__(16) char smem[34880];
  const int bx = blockIdx.x;
  if (bx < 512) {
    flash_body<128>(smem, bx & 31, bx >> 5, O, Q, kT, vT, nullptr, NQn);
  } else {
    bias_body(smem, bx - 512, biasb, rel, pad, tsg, Stabg, Btabg);
  }
}

// ---------------------------------------------------------------------------
// flash standalone (cross, CHUNK=256): grid (NQ/8, B*H), 256 threads.
// ---------------------------------------------------------------------------
__global__ __launch_bounds__(256, 2) void flash_kernel(
    float* __restrict__ O, const float* __restrict__ Q,
    const __half* __restrict__ kT, const __half* __restrict__ vT,
    const __half* __restrict__ biasb, int NK)
{
  __shared__ __align__(16) char smem[66560];
  flash_body<256>(smem, blockIdx.x, blockIdx.y, O, Q, kT, vT, biasb, NK);
}

// ---------------------------------------------------------------------------
// gemm32: 32x32 tile, 256 threads, K-step 32, float4 staging, reg prefetch.
// Split-K via blockIdx.z (partials at kz*M*N). relu opt.
// ---------------------------------------------------------------------------
__global__ __launch_bounds__(256) void gemm32_kernel(
    float* __restrict__ C, const float* __restrict__ A, const float* __restrict__ A2,
    const float* __restrict__ W, const float* __restrict__ bias,
    int N, int Kchunk, int Ktot, float scale, int do_relu)
{
  __shared__ float As[32][33];
  __shared__ float Ws[32][33];
  const int bm = blockIdx.y * 32, bn = blockIdx.x * 32;
  const int kz = blockIdx.z;
  const int M = gridDim.y * 32;
  float* Cp = C + (size_t)kz * M * N;
  const int tid = threadIdx.x;
  const int tx = tid & 15, ty = tid >> 4;
  const int lr = tid >> 3, lc = (tid & 7) * 4;
  float acc[2][2] = {};
  const int k00 = kz * Kchunk;
  float4 av, wv;
  {
    av = *(const float4*)(A + (size_t)(bm + lr) * Ktot + k00 + lc);
    if (A2) {
      float4 bv = *(const float4*)(A2 + (size_t)(bm + lr) * Ktot + k00 + lc);
      av.x += bv.x; av.y += bv.y; av.z += bv.z; av.w += bv.w;
    }
    wv = *(const float4*)(W + (size_t)(bn + lr) * Ktot + k00 + lc);
  }
  for (int k0 = k00; k0 < k00 + Kchunk; k0 += 32) {
    As[lr][lc] = av.x; As[lr][lc + 1] = av.y; As[lr][lc + 2] = av.z; As[lr][lc + 3] = av.w;
    Ws[lr][lc] = wv.x; Ws[lr][lc + 1] = wv.y; Ws[lr][lc + 2] = wv.z; Ws[lr][lc + 3] = wv.w;
    __syncthreads();
    if (k0 + 32 < k00 + Kchunk) {
      av = *(const float4*)(A + (size_t)(bm + lr) * Ktot + k0 + 32 + lc);
      if (A2) {
        float4 bv = *(const float4*)(A2 + (size_t)(bm + lr) * Ktot + k0 + 32 + lc);
        av.x += bv.x; av.y += bv.y; av.z += bv.z; av.w += bv.w;
      }
      wv = *(const float4*)(W + (size_t)(bn + lr) * Ktot + k0 + 32 + lc);
    }
#pragma unroll
    for (int k = 0; k < 32; ++k) {
      float a0 = As[ty * 2][k], a1 = As[ty * 2 + 1][k];
      float w0 = Ws[tx * 2][k], w1 = Ws[tx * 2 + 1][k];
      acc[0][0] += a0 * w0; acc[0][1] += a0 * w1;
      acc[1][0] += a1 * w0; acc[1][1] += a1 * w1;
    }
    __syncthreads();
  }
#pragma unroll
  for (int i = 0; i < 2; ++i) {
    int m = bm + ty * 2 + i;
#pragma unroll
    for (int j = 0; j < 2; ++j) {
      int n = bn + tx * 2 + j;
      float v = acc[i][j];
      if (bias) v += bias[n];
      v *= scale;
      if (do_relu) v = fmaxf(v, 0.f);
      Cp[(size_t)m * N + n] = v;
    }
  }
}

// ---------------------------------------------------------------------------
// gemm32ln body: computes LN(x)@W^T WITHOUT pre-materialized LN:
//   x = resid + part0 + part1 + cbias;  A-staged as x*g with row stats
//   epilogue: v = r*acc - r*mu*gW[n] + bW[n] (+addm[m][n]) ; *scale ; relu
// Identity: LN(x)@W^T = r*[(x.g)@W^T] - (r*mu)*(g@W^T) + (lnb@W^T).
// Row stats: each block's K-loop covers full rows; 8-lane shfl reduce.
// ---------------------------------------------------------------------------
__device__ __forceinline__ void gemm32ln_body(
    int bn0, int bm, float* __restrict__ C, int N,
    const float* __restrict__ resid, const float* __restrict__ part,
    const float* __restrict__ cbias, const float* __restrict__ lng,
    const float* __restrict__ W, const float* __restrict__ gW,
    const float* __restrict__ bW, const float* __restrict__ addm,
    float scale, int do_relu)
{
  __shared__ float As[32][33];
  __shared__ float Ws[32][33];
  __shared__ float mu_s[32], rr_s[32];
  const int tid = threadIdx.x;
  const int tx = tid & 15, ty = tid >> 4;
  const int lr = tid >> 3, lc = (tid & 7) * 4;
  const size_t STR = (size_t)Bb * NQn * Dn;
  float acc[2][2] = {};
  float sx = 0.f, sx2 = 0.f;
  auto loadx = [&](int k0) {
    const size_t ix = (size_t)(bm + lr) * Dn + k0 + lc;
    float4 x0 = *(const float4*)(resid + ix);
    float4 p0 = *(const float4*)(part + ix);
    float4 p1 = *(const float4*)(part + ix + STR);
    float4 cb = *(const float4*)(cbias + k0 + lc);
    float4 g  = *(const float4*)(lng + k0 + lc);
    float4 x;
    x.x = x0.x + p0.x + p1.x + cb.x;
    x.y = x0.y + p0.y + p1.y + cb.y;
    x.z = x0.z + p0.z + p1.z + cb.z;
    x.w = x0.w + p0.w + p1.w + cb.w;
    sx += x.x + x.y + x.z + x.w;
    sx2 += x.x * x.x + x.y * x.y + x.z * x.z + x.w * x.w;
    float4 r;
    r.x = x.x * g.x; r.y = x.y * g.y; r.z = x.z * g.z; r.w = x.w * g.w;
    return r;
  };
  float4 av = loadx(0);
  float4 wv = *(const float4*)(W + (size_t)(bn0 + lr) * Dn + lc);
  for (int k0 = 0; k0 < Dn; k0 += 32) {
    As[lr][lc] = av.x; As[lr][lc + 1] = av.y; As[lr][lc + 2] = av.z; As[lr][lc + 3] = av.w;
    Ws[lr][lc] = wv.x; Ws[lr][lc + 1] = wv.y; Ws[lr][lc + 2] = wv.z; Ws[lr][lc + 3] = wv.w;
    __syncthreads();
    if (k0 + 32 < Dn) {
      av = loadx(k0 + 32);
      wv = *(const float4*)(W + (size_t)(bn0 + lr) * Dn + k0 + 32 + lc);
    }
#pragma unroll
    for (int k = 0; k < 32; ++k) {
      float a0 = As[ty * 2][k], a1 = As[ty * 2 + 1][k];
      float w0 = Ws[tx * 2][k], w1 = Ws[tx * 2 + 1][k];
      acc[0][0] += a0 * w0; acc[0][1] += a0 * w1;
      acc[1][0] += a1 * w0; acc[1][1] += a1 * w1;
    }
    __syncthreads();
  }
  // 8 lanes (same lr) hold disjoint 32-element partial sums of the row
  sx += __shfl_xor(sx, 1); sx += __shfl_xor(sx, 2); sx += __shfl_xor(sx, 4);
  sx2 += __shfl_xor(sx2, 1); sx2 += __shfl_xor(sx2, 2); sx2 += __shfl_xor(sx2, 4);
  if ((tid & 7) == 0) {
    const float mean = sx * (1.f / Dn);
    const float var = sx2 * (1.f / Dn) - mean * mean;
    mu_s[lr] = mean;
    rr_s[lr] = rsqrtf(var + EPSf);
  }
  __syncthreads();
#pragma unroll
  for (int i = 0; i < 2; ++i) {
    const int mrow = ty * 2 + i;
    const int m = bm + mrow;
    const float mu = mu_s[mrow], r = rr_s[mrow];
#pragma unroll
    for (int j = 0; j < 2; ++j) {
      const int n = bn0 + tx * 2 + j;
      float v = r * acc[i][j] - r * mu * gW[n] + bW[n];
      if (addm) v += addm[(size_t)m * N + n];
      v *= scale;
      if (do_relu) v = fmaxf(v, 0.f);
      C[(size_t)m * N + n] = v;
    }
  }
}

// ---------------------------------------------------------------------------
// rln device body: out = LayerNorm(resid + part0 + part1 + bias)*g + b.
// ---------------------------------------------------------------------------
__device__ __forceinline__ void rln_body(
    int row, float* __restrict__ out, const float* __restrict__ part,
    const float* __restrict__ bias, const float* __restrict__ resid,
    const float* __restrict__ g, const float* __restrict__ bt, int nsplit)
{
  const int t = threadIdx.x;
  const size_t idx = (size_t)row * Dn + t;
  const size_t STR = (size_t)Bb * NQn * Dn;
  float v = bias[t] + resid[idx];
  for (int s = 0; s < nsplit; ++s) v += part[idx + (size_t)s * STR];
  float sm = v, s2 = v * v;
#pragma unroll
  for (int off = 32; off > 0; off >>= 1) {
    sm += __shfl_down(sm, off);
    s2 += __shfl_down(s2, off);
  }
  __shared__ float rs[4], rs2[4], fin[2];
  const int lane = t & 63, wid = t >> 6;
  if (lane == 0) { rs[wid] = sm; rs2[wid] = s2; }
  __syncthreads();
  if (t == 0) {
    float a = rs[0] + rs[1] + rs[2] + rs[3];
    float a2 = rs2[0] + rs2[1] + rs2[2] + rs2[3];
    float mean = a * (1.f / Dn);
    float var = a2 * (1.f / Dn) - mean * mean;
    fin[0] = mean;
    fin[1] = rsqrtf(var + EPSf);
  }
  __syncthreads();
  out[idx] = (v - fin[0]) * fin[1] * g[t] + bt[t];
}

// ---------------------------------------------------------------------------
// qcln: fused cross-q (LN2 folded, 128 blocks) + tgt2 materialization (512).
// ---------------------------------------------------------------------------
__global__ __launch_bounds__(256) void qcln_kernel(
    float* __restrict__ qCb, float* __restrict__ tgt2,
    const float* __restrict__ tgt, const float* __restrict__ part,
    const float* __restrict__ outb, const float* __restrict__ ln2g,
    const float* __restrict__ ln2b, const float* __restrict__ qw,
    const float* __restrict__ gq, const float* __restrict__ cqv,
    const float* __restrict__ qposq)
{
  const int bx = blockIdx.x;
  if (bx < 128) {
    gemm32ln_body((bx & 7) * 32, (bx >> 3) * 32, qCb, Dn,
                  tgt, part, outb, ln2g, qw, gq, cqv, qposq, SCALEf, 0);
  } else {
    rln_body(bx - 128, tgt2, part, outb, tgt, ln2g, ln2b, 2);
  }
}

// ---------------------------------------------------------------------------
// ffn1ln: fused FFN1 (LN1 folded, 512 blocks) + tgt3 materialization (512).
// ---------------------------------------------------------------------------
__global__ __launch_bounds__(256) void ffn1ln_kernel(
    float* __restrict__ ffh, float* __restrict__ tgt3,
    const float* __restrict__ tgt2, const float* __restrict__ part,
    const float* __restrict__ projb, const float* __restrict__ ln1g,
    const float* __restrict__ ln1b, const float* __restrict__ ff1w,
    const float* __restrict__ gf, const float* __restrict__ bfv)
{
  const int bx = blockIdx.x;
  if (bx < 512) {
    gemm32ln_body((bx & 31) * 32, (bx >> 5) * 32, ffh, FFNn,
                  tgt2, part, projb, ln1g, ff1w, gf, bfv, nullptr, 1.f, 1);
  } else {
    rln_body(bx - 512, tgt3, part, projb, tgt2, ln1g, ln1b, 2);
  }
}

// ---------------------------------------------------------------------------
// reduce_ln standalone (LN3, nsplit=4).
// ---------------------------------------------------------------------------
__global__ __launch_bounds__(256) void reduce_ln_kernel(
    float* __restrict__ out, const float* __restrict__ part,
    const float* __restrict__ bias, const float* __restrict__ resid,
    const float* __restrict__ g, const float* __restrict__ bt, int nsplit)
{
  const int row = blockIdx.x;
  const int t = threadIdx.x;
  const size_t idx = (size_t)row * Dn + t;
  const size_t STR = (size_t)Bb * NQn * Dn;
  float v = bias[t] + resid[idx];
  for (int s = 0; s < nsplit; ++s) v += part[idx + (size_t)s * STR];
  float sm = v, s2 = v * v;
#pragma unroll
  for (int off = 32; off > 0; off >>= 1) {
    sm += __shfl_down(sm, off);
    s2 += __shfl_down(s2, off);
  }
  __shared__ float rs[4], rs2[4], fin[2];
  const int lane = t & 63, wid = t >> 6;
  if (lane == 0) { rs[wid] = sm; rs2[wid] = s2; }
  __syncthreads();
  if (t == 0) {
    float a = rs[0] + rs[1] + rs[2] + rs[3];
    float a2 = rs2[0] + rs2[1] + rs2[2] + rs2[3];
    float mean = a * (1.f / Dn);
    float var = a2 * (1.f / Dn) - mean * mean;
    fin[0] = mean;
    fin[1] = rsqrtf(var + EPSf);
  }
  __syncthreads();
  out[idx] = (v - fin[0]) * fin[1] * g[t] + bt[t];
}

extern "C" void kernel_launch(void* const* d_in, const int* in_sizes, int n_in,
                              void* d_out, int out_size, void* d_ws, size_t ws_size,
                              hipStream_t stream)
{
  const float* tgt   = (const float*)d_in[0];
  const float* qpos  = (const float*)d_in[1];
  const float* src   = (const float*)d_in[2];
  const float* spe   = (const float*)d_in[3];
  const float* pad   = (const float*)d_in[4];
  const float* rel   = (const float*)d_in[5];
  const float* qw    = (const float*)d_in[6];
  const float* qb    = (const float*)d_in[7];
  const float* kw    = (const float*)d_in[8];
  const float* kb    = (const float*)d_in[9];
  const float* vw    = (const float*)d_in[10];
  const float* vb    = (const float*)d_in[11];
  const float* projw = (const float*)d_in[12];
  const float* projb = (const float*)d_in[13];
  const float* cpbw1 = (const float*)d_in[14];
  const float* cpbb1 = (const float*)d_in[15];
  const float* cpbw2 = (const float*)d_in[16];
  const float* ipw   = (const float*)d_in[17];
  const float* ipb   = (const float*)d_in[18];
  const float* outw  = (const float*)d_in[19];
  const float* outb  = (const float*)d_in[20];
  const float* ln1g  = (const float*)d_in[21];
  const float* ln1b  = (const float*)d_in[22];
  const float* ln2g  = (const float*)d_in[23];
  const float* ln2b  = (const float*)d_in[24];
  const float* ln3g  = (const float*)d_in[25];
  const float* ln3b  = (const float*)d_in[26];
  const float* ff1w  = (const float*)d_in[27];
  const float* ff1b  = (const float*)d_in[28];
  const float* ff2w  = (const float*)d_in[29];
  const float* ff2b  = (const float*)d_in[30];
  float* out = (float*)d_out;
  float* ws = (float*)d_ws;

  constexpr size_t SZ_Q   = (size_t)Bb * NQn * Dn;   // 131072
  constexpr size_t SZ_S   = (size_t)Bb * NSn * Dn;   // 524288
  constexpr size_t SZ_FFH = (size_t)Bb * NQn * FFNn; // 524288

  float* qSb  = ws;
  __half* kSb = (__half*)(qSb + SZ_Q);   // head-major fp16 kT (self)
  __half* vSb = (__half*)(qSb + 2 * SZ_Q);
  float* oSb  = ws + 3 * SZ_Q;
  float* soP  = oSb + SZ_Q;
  float* tgt2 = soP + SZ_Q;
  float* qCb  = tgt2 + SZ_Q;
  __half* kCb = (__half*)(qCb + SZ_Q);   // head-major fp16 kT (cross)
  __half* vCb = (__half*)(qCb + SZ_Q + SZ_S);
  float* oCb  = qCb + SZ_Q + 2 * SZ_S;
  float* coP  = oCb + SZ_Q;
  float* tgt3 = coP + SZ_Q;
  float* ffh  = tgt3 + SZ_Q;
  float* part = ffh + SZ_FFH;            // 4 * SZ_Q partials scratch
  float* tsb  = part + 4 * SZ_Q;
  float* Stab = tsb + RPEn;
  float* Btab = Stab + (RPEn + 1) * Hn;
  __half* biasb = (__half*)(Btab + (RPEn + 1) * Hn);
  float* qposq = (float*)(biasb + (size_t)Bb * Hn * NQn * NSn);
  float* gq  = qposq + SZ_Q;
  float* cqv = gq + Dn;
  float* gf  = cqv + Dn;
  float* bfv = gf + FFNn;

  const int MQ = Bb * NQn;  // 512

  // 1. prep: cpb tables + self QKV + cross KV + qposq + LN-fold vectors
  prep_kernel<<<dim3(388), dim3(512), 0, stream>>>(
      qSb, kSb, vSb, kCb, vCb, tgt, qpos, src, spe, ipw, ipb,
      kw, kb, vw, vb, cpbw1, cpbb1, cpbw2, tsb, Stab, Btab,
      qw, qb, ln2g, ln2b, ln1g, ln1b, ff1w, ff1b,
      qposq, gq, cqv, gf, bfv);

  // 2. fused: flash self (512 blocks) + fp16 bias materialization (512)
  fsb_kernel<<<dim3(1024), dim3(256), 0, stream>>>(
      oSb, qSb, kSb, vSb, biasb, rel, pad, tsb, Stab, Btab);

  // 3. self out-proj, split-K x2 -> partials
  gemm32_kernel<<<dim3(Dn / 32, MQ / 32, 2), dim3(256), 0, stream>>>(
      part, oSb, nullptr, outw, nullptr, Dn, 128, Dn, 1.f, 0);

  // 4. fused: cross-q with folded LN2 (128 blocks) + tgt2 write (512 blocks)
  qcln_kernel<<<dim3(128 + 512), dim3(256), 0, stream>>>(
      qCb, tgt2, tgt, part, outb, ln2g, ln2b, qw, gq, cqv, qposq);

  // 5. cross attention (CHUNK=256 flash, fp16 K/V + fp16 staged bias)
  flash_kernel<<<dim3(NQn / 8, Bb * Hn), dim3(256), 0, stream>>>(
      oCb, qCb, kCb, vCb, biasb, NSn);

  // 6. cross out-proj, split-K x2 -> partials
  gemm32_kernel<<<dim3(Dn / 32, MQ / 32, 2), dim3(256), 0, stream>>>(
      part, oCb, nullptr, projw, nullptr, Dn, 128, Dn, 1.f, 0);

  // 7. fused: FFN1 with folded LN1 (512 blocks) + tgt3 write (512 blocks)
  ffn1ln_kernel<<<dim3(512 + 512), dim3(256), 0, stream>>>(
      ffh, tgt3, tgt2, part, projb, ln1g, ln1b, ff1w, gf, bfv);

  // 8. FFN2 split-K x4 -> partials
  gemm32_kernel<<<dim3(Dn / 32, MQ / 32, 4), dim3(256), 0, stream>>>(
      part, ffh, nullptr, ff2w, nullptr, Dn, 256, FFNn, 1.f, 0);

  // 9. out = LN3(tgt3 + sum(part) + ff2b)
  reduce_ln_kernel<<<dim3(MQ), dim3(256), 0, stream>>>(
      out, part, ff2b, tgt3, ln3g, ln3b, 4);
}

// Round 18
// 125.611 us; speedup vs baseline: 1.0126x; 1.0126x over previous
//
#include <hip/hip_runtime.h>
#include <hip/hip_bf16.h>
#include <hip/hip_fp16.h>
#include <math.h>

#define Bb 2
#define NQn 256
#define NSn 1024
#define Dn 256
#define Hn 8
#define DHn 32
#define FFNn 1024
#define RPEn 512
#define SCALEf 0.17677669529663687f
#define EPSf 1e-5f

// async global->LDS, 16B per lane. LDS dest must be linear in lane order
// (wave-uniform base + lane*16); global src is per-lane (pre-swizzled).
#define GLDS16(g, l)                                                         \
  __builtin_amdgcn_global_load_lds(                                          \
      (const __attribute__((address_space(1))) void*)(const void*)(g),       \
      (__attribute__((address_space(3))) void*)(void*)(l), 16, 0, 0)

// ---------------------------------------------------------------------------
// gemm64 body: 64x64 tile, 512 threads, K-step 32, float4 loads, reg prefetch.
// trsh != 0: write transposed head-major FP16 Ch[((b*H+h)<<trsh)+kseq][32].
// ---------------------------------------------------------------------------
__device__ __forceinline__ void gemm64_body(
    float* __restrict__ C, __half* __restrict__ Ch, int ldc,
    const float* __restrict__ A, const float* __restrict__ A2, int ld,
    const float* __restrict__ W, const float* __restrict__ bias,
    int K, int bm, int bnC, int bnW, float scale, int do_relu, int trsh,
    float (*As)[33], float (*WsT)[68])
{
  const int tid = threadIdx.x;
  const int tx = tid & 15, ty = tid >> 4;       // ty 0..31
  const int lr = tid >> 3, lc = (tid & 7) * 4;  // staging coords
  float4 ra, rw;
  {
    ra = *(const float4*)(A + (size_t)(bm + lr) * ld + lc);
    if (A2) {
      float4 t = *(const float4*)(A2 + (size_t)(bm + lr) * ld + lc);
      ra.x += t.x; ra.y += t.y; ra.z += t.z; ra.w += t.w;
    }
    rw = *(const float4*)(W + (size_t)(bnW + lr) * ld + lc);
  }
  float acc[2][4] = {};
  for (int k0 = 0; k0 < K; k0 += 32) {
    As[lr][lc] = ra.x; As[lr][lc + 1] = ra.y;
    As[lr][lc + 2] = ra.z; As[lr][lc + 3] = ra.w;
    WsT[lc][lr] = rw.x; WsT[lc + 1][lr] = rw.y;
    WsT[lc + 2][lr] = rw.z; WsT[lc + 3][lr] = rw.w;
    __syncthreads();
    if (k0 + 32 < K) {
      ra = *(const float4*)(A + (size_t)(bm + lr) * ld + k0 + 32 + lc);
      if (A2) {
        float4 t = *(const float4*)(A2 + (size_t)(bm + lr) * ld + k0 + 32 + lc);
        ra.x += t.x; ra.y += t.y; ra.z += t.z; ra.w += t.w;
      }
      rw = *(const float4*)(W + (size_t)(bnW + lr) * ld + k0 + 32 + lc);
    }
#pragma unroll
    for (int k = 0; k < 32; ++k) {
      float a0 = As[ty][k], a1 = As[ty + 32][k];
      float4 w = *(const float4*)&WsT[k][tx * 4];
      acc[0][0] += a0 * w.x; acc[0][1] += a0 * w.y;
      acc[0][2] += a0 * w.z; acc[0][3] += a0 * w.w;
      acc[1][0] += a1 * w.x; acc[1][1] += a1 * w.y;
      acc[1][2] += a1 * w.z; acc[1][3] += a1 * w.w;
    }
    __syncthreads();
  }
#pragma unroll
  for (int i = 0; i < 2; ++i) {
    int m = bm + ty + i * 32;
#pragma unroll
    for (int j = 0; j < 4; ++j) {
      float v = acc[i][j];
      if (bias) v += bias[bnW + tx * 4 + j];
      v *= scale;
      if (do_relu) v = fmaxf(v, 0.f);
      if (trsh == 0) {
        C[(size_t)m * ldc + bnC + tx * 4 + j] = v;
      } else {
        const int nC = bnC + tx * 4 + j;
        const int bb = m >> trsh, kseq = m & ((1 << trsh) - 1);
        const int hh = nC >> 5, d = nC & 31;
        Ch[((((size_t)(bb * Hn + hh)) << trsh) + kseq) * 32 + d] =
            __float2half(v);
      }
    }
  }
}

// ---------------------------------------------------------------------------
// prep: fused build_cpb (1 block) + self QKV GEMM (96 blocks; K/V written
// head-major transposed fp16) + cross KV GEMM (256 blocks). 512 threads.
// ---------------------------------------------------------------------------
__global__ __launch_bounds__(512) void prep_kernel(
    float* __restrict__ qSb, __half* __restrict__ kSb, __half* __restrict__ vSb,
    __half* __restrict__ kCb, __half* __restrict__ vCb,
    const float* __restrict__ tgt, const float* __restrict__ qpos,
    const float* __restrict__ src, const float* __restrict__ spe,
    const float* __restrict__ ipw, const float* __restrict__ ipb,
    const float* __restrict__ kw, const float* __restrict__ kb,
    const float* __restrict__ vw, const float* __restrict__ vb,
    const float* __restrict__ w1p, const float* __restrict__ b1p,
    const float* __restrict__ w2p,
    float* __restrict__ tout, float* __restrict__ Stab, float* __restrict__ Btab)
{
  __shared__ float smem[4288];  // As 64*33=2112 + WsT 32*68=2176
  const int bx = blockIdx.x;
  const int tid = threadIdx.x;
  if (bx < 96) {
    float (*As)[33] = (float(*)[33])smem;
    float (*WsT)[68] = (float(*)[68])(smem + 2112);
    int my = bx & 7, nx = bx >> 3;
    int sec = nx >> 2;
    gemm64_body(qSb, sec == 1 ? kSb : vSb, Dn, tgt,
                sec < 2 ? qpos : nullptr, Dn, ipw, ipb,
                Dn, my * 64, (nx & 3) * 64, nx * 64,
                sec == 0 ? SCALEf : 1.f, 0, sec == 0 ? 0 : 8, As, WsT);
    return;
  }
  if (bx < 96 + 256) {
    float (*As)[33] = (float(*)[33])smem;
    float (*WsT)[68] = (float(*)[68])(smem + 2112);
    int idx = bx - 96;
    int my = idx & 31, nx = idx >> 5;
    int sec = nx >> 2;
    gemm64_body(nullptr, sec ? vCb : kCb, Dn, src, sec ? nullptr : spe, Dn,
                sec ? vw : kw, sec ? vb : kb,
                Dn, my * 64, (nx & 3) * 64, (nx & 3) * 64, 1.f, 0, 10, As, WsT);
    return;
  }
  // ---- cpb piecewise-linear table build (verified rounds 1-17) ----
  float* key = smem;
  int* pidx = (int*)(smem + 512);
  float* w1s = smem + 1024;
  float* b1s = smem + 1536;
  {
    float w = w1p[tid], bb = b1p[tid];
    key[tid] = (w != 0.f) ? (-bb / w) : 3.0e38f;
    pidx[tid] = tid;
  }
  __syncthreads();
  for (int k = 2; k <= RPEn; k <<= 1) {
    for (int j = k >> 1; j > 0; j >>= 1) {
      int ixj = tid ^ j;
      if (ixj > tid) {
        float a = key[tid], c = key[ixj];
        bool asc = ((tid & k) == 0);
        bool sw = asc ? (a > c) : (a < c);
        if (sw) {
          key[tid] = c; key[ixj] = a;
          int tmp = pidx[tid]; pidx[tid] = pidx[ixj]; pidx[ixj] = tmp;
        }
      }
      __syncthreads();
    }
  }
  w1s[tid] = w1p[pidx[tid]];
  b1s[tid] = b1p[pidx[tid]];
  tout[tid] = key[tid];
  __syncthreads();
  const int lane = tid & 63;
  const int h = tid >> 6;
  const int j0 = lane * 8;
  float sp[8], bp[8], sn[8], bn[8];
  float csp = 0.f, cbp = 0.f, csn = 0.f, cbn = 0.f, ccc = 0.f;
#pragma unroll
  for (int e = 0; e < 8; ++e) {
    int j = j0 + e;
    float w = w1s[j], b = b1s[j];
    float c = w2p[h * RPEn + pidx[j]];
    sp[e] = csp; bp[e] = cbp; sn[e] = csn; bn[e] = cbn;
    if (w > 0.f)      { csp += w * c; cbp += b * c; }
    else if (w < 0.f) { csn += w * c; cbn += b * c; }
    else              { ccc += fmaxf(b, 0.f) * c; }
  }
  float isp = csp, ibp = cbp, isn = csn, ibn = cbn, icc = ccc;
#pragma unroll
  for (int d = 1; d < 64; d <<= 1) {
    float t0 = __shfl_up(isp, d);
    float t1 = __shfl_up(ibp, d);
    float t2 = __shfl_up(isn, d);
    float t3 = __shfl_up(ibn, d);
    if (lane >= d) { isp += t0; ibp += t1; isn += t2; ibn += t3; }
    icc += __shfl_xor(icc, d);
  }
  const float tsn = __shfl(isn, 63);
  const float tbn = __shfl(ibn, 63);
  const float esp = isp - csp, ebp = ibp - cbp;
  const float esn = isn - csn, ebn = ibn - cbn;
#pragma unroll
  for (int e = 0; e < 8; ++e) {
    int j = j0 + e;
    Stab[j * Hn + h] = (esp + sp[e]) + (tsn - (esn + sn[e]));
    Btab[j * Hn + h] = (ebp + bp[e]) + (tbn - (ebn + bn[e])) + icc;
  }
  if (lane == 63) {
    Stab[RPEn * Hn + h] = isp;
    Btab[RPEn * Hn + h] = ibp + icc;
  }
}

// ---------------------------------------------------------------------------
// bias body: fp16 bias[b,h,q,k] = Sh[lo]*m + Bh[lo] - 100*pad. One block per
// (b,q); search once per (b,q,k), applied to 8 heads. LDS carved from smem.
// ---------------------------------------------------------------------------
__device__ __forceinline__ void bias_body(
    char* smemraw, int idx,
    __half* __restrict__ biasb, const float* __restrict__ rel,
    const float* __restrict__ pad, const float* __restrict__ tsg,
    const float* __restrict__ Stabg, const float* __restrict__ Btabg)
{
  float* ts = (float*)smemraw;                    // 512 f
  float* Sh = (float*)(smemraw + 2048);           // 4104 f
  float* Bh = (float*)(smemraw + 18464);          // 4104 f
  const int tid = threadIdx.x;
  const int b = idx >> 8, q = idx & 255;
  ts[tid] = tsg[tid];
  ts[tid + 256] = tsg[tid + 256];
  for (int i = tid; i < (RPEn + 1) * Hn; i += 256) {
    Sh[i] = Stabg[i];
    Bh[i] = Btabg[i];
  }
  __syncthreads();
#pragma unroll
  for (int j = 0; j < 4; ++j) {
    const int k = tid + j * 256;
    const float m = rel[((size_t)b * NQn + q) * NSn + k];
    const float padv = -100.f * pad[b * NSn + k];
    int lo = 0, hi = RPEn;
#pragma unroll
    for (int it = 0; it < 9; ++it) {
      int mid = (lo + hi) >> 1;
      if (ts[mid] < m) lo = mid + 1; else hi = mid;
    }
#pragma unroll
    for (int h = 0; h < Hn; ++h) {
      biasb[(((size_t)(b * Hn + h)) * NQn + q) * NSn + k] =
          __float2half(Sh[lo * Hn + h] * m + Bh[lo * Hn + h] + padv);
    }
  }
}

// ---------------------------------------------------------------------------
// Flash body (verified rounds 14-16), templated on CHUNK (keys per LDS tile).
// R=2 rows/thread, HEAD-MAJOR FP16 K/V (kT/vT [b][h][k][32], rows = 64B =
// 4 float4 units). Rotation swizzle o(k)=(k+(k>>2))&3 in ADDRESS arithmetic
// only ((kc + j*64) preserves it: 80j = 0 mod 4). 256 threads = 4 waves;
// wave w owns rows {2w,2w+1}; lane kc handles keys kc + j*64, j<CHUNK/64.
// Double-buffered gload_lds; fp16 bias prefetched in registers.
// LDS: 2*CHUNK*64*2 + 1KB (=33.8KB @128, 66.5KB @256 -> 2 blocks/CU).
// ---------------------------------------------------------------------------
template <int CHUNK>
__device__ __forceinline__ void flash_body(
    char* smemraw, int qb, int bh,
    float* __restrict__ O, const float* __restrict__ Q,
    const __half* __restrict__ kT, const __half* __restrict__ vT,
    const __half* __restrict__ biasb, int NK)
{
  constexpr int NJ = CHUNK / 64;        // keys per lane per chunk
  constexpr int NS = CHUNK / 64;        // stage iters
  float4 (*Ks)[CHUNK * 4] = (float4(*)[CHUNK * 4])smemraw;
  float4 (*Vs)[CHUNK * 4] = (float4(*)[CHUNK * 4])(smemraw + CHUNK * 128);
  float4* Qs = (float4*)(smemraw + CHUNK * 256);
  const int b = bh >> 3, h = bh & 7;
  const int q0 = qb * 8;
  const int tid = threadIdx.x;
  const int w = tid >> 6, kc = tid & 63;
  const float4* Ktp = (const float4*)kT + (size_t)bh * NK * 4;
  const float4* Vtp = (const float4*)vT + (size_t)bh * NK * 4;
  if (tid < 64)
    Qs[tid] = ((const float4*)Q)[(size_t)(b * NQn + q0 + (tid >> 3)) * 64 +
                                 h * 8 + (tid & 7)];

  const __half* brow0 =
      biasb ? biasb + ((size_t)bh * NQn + q0 + 2 * w) * NK : nullptr;
  const __half* brow1 = biasb ? brow0 + NK : nullptr;

  auto stage = [&](int buf, int kb0) {
#pragma unroll
    for (int u = 0; u < NS; ++u) {
      const int s = tid + u * 256;   // linear LDS slot (lane order)
      const int k = s >> 2, e = s & 3;
      const int ok = (k + (k >> 2)) & 3;
      const int g = (kb0 + k) * 4 + ((e - ok) & 3);
      GLDS16(Ktp + g, &Ks[buf][s]);
      GLDS16(Vtp + g, &Vs[buf][s]);
    }
  };

  stage(0, 0);
  float cb[2][NJ];
  if (biasb) {
#pragma unroll
    for (int j = 0; j < NJ; ++j) {
      cb[0][j] = __half2float(brow0[kc + j * 64]);
      cb[1][j] = __half2float(brow1[kc + j * 64]);
    }
  }
  __syncthreads();  // drains vmcnt: chunk 0 + Qs ready

  float4 q[2][8];
#pragma unroll
  for (int dd = 0; dd < 8; ++dd) {
    q[0][dd] = Qs[(2 * w) * 8 + dd];
    q[1][dd] = Qs[(2 * w + 1) * 8 + dd];
  }
  float4 o[2][8] = {};
  float m_run[2] = {-3.0e38f, -3.0e38f};
  float l_run[2] = {0.f, 0.f};
  const int nchunk = NK / CHUNK;
  const int ox = (kc + (kc >> 2)) & 3;  // row-rot key, invariant to j*64

  for (int c = 0; c < nchunk; ++c) {
    const int cur = c & 1;
    float nb[2][NJ];
    if (c + 1 < nchunk) {
      stage(cur ^ 1, (c + 1) * CHUNK);  // prefetch flies under compute
      if (biasb) {
#pragma unroll
        for (int j = 0; j < NJ; ++j) {
          nb[0][j] = __half2float(brow0[(c + 1) * CHUNK + kc + j * 64]);
          nb[1][j] = __half2float(brow1[(c + 1) * CHUNK + kc + j * 64]);
        }
      }
    }
    float s[2][NJ];
#pragma unroll
    for (int j = 0; j < NJ; ++j) {
      const int kbase = (kc + j * 64) * 4;
      float a0 = 0.f, a1 = 0.f;
#pragma unroll
      for (int u = 0; u < 4; ++u) {
        float4 raw = Ks[cur][kbase + ((u + ox) & 3)];  // = unit u of row k
        const __half2* hp = (const __half2*)&raw;
        float2 f0 = __half22float2(hp[0]);
        float2 f1 = __half22float2(hp[1]);
        float2 f2 = __half22float2(hp[2]);
        float2 f3 = __half22float2(hp[3]);
        a0 += q[0][2 * u].x * f0.x + q[0][2 * u].y * f0.y +
              q[0][2 * u].z * f1.x + q[0][2 * u].w * f1.y +
              q[0][2 * u + 1].x * f2.x + q[0][2 * u + 1].y * f2.y +
              q[0][2 * u + 1].z * f3.x + q[0][2 * u + 1].w * f3.y;
        a1 += q[1][2 * u].x * f0.x + q[1][2 * u].y * f0.y +
              q[1][2 * u].z * f1.x + q[1][2 * u].w * f1.y +
              q[1][2 * u + 1].x * f2.x + q[1][2 * u + 1].y * f2.y +
              q[1][2 * u + 1].z * f3.x + q[1][2 * u + 1].w * f3.y;
      }
      s[0][j] = a0;
      s[1][j] = a1;
      if (biasb) { s[0][j] += cb[0][j]; s[1][j] += cb[1][j]; }
    }
    float f[2];
#pragma unroll
    for (int r = 0; r < 2; ++r) {
      float cmax = s[r][0];
#pragma unroll
      for (int j = 1; j < NJ; ++j) cmax = fmaxf(cmax, s[r][j]);
#pragma unroll
      for (int off = 1; off < 64; off <<= 1)
        cmax = fmaxf(cmax, __shfl_xor(cmax, off));
      const float m_new = fmaxf(m_run[r], cmax);
      f[r] = __expf(m_run[r] - m_new);
      float ls = 0.f;
#pragma unroll
      for (int j = 0; j < NJ; ++j) {
        s[r][j] = __expf(s[r][j] - m_new);
        ls += s[r][j];
      }
#pragma unroll
      for (int off = 1; off < 64; off <<= 1) ls += __shfl_xor(ls, off);
      l_run[r] = l_run[r] * f[r] + ls;
      m_run[r] = m_new;
    }
#pragma unroll
    for (int dd = 0; dd < 8; ++dd) {
      o[0][dd].x *= f[0]; o[0][dd].y *= f[0]; o[0][dd].z *= f[0]; o[0][dd].w *= f[0];
      o[1][dd].x *= f[1]; o[1][dd].y *= f[1]; o[1][dd].z *= f[1]; o[1][dd].w *= f[1];
    }
#pragma unroll
    for (int j = 0; j < NJ; ++j) {
      const int kbase = (kc + j * 64) * 4;
      const float p0 = s[0][j], p1 = s[1][j];
#pragma unroll
      for (int u = 0; u < 4; ++u) {
        float4 raw = Vs[cur][kbase + ((u + ox) & 3)];  // = unit u of row k
        const __half2* hp = (const __half2*)&raw;
        float2 f0 = __half22float2(hp[0]);
        float2 f1 = __half22float2(hp[1]);
        float2 f2 = __half22float2(hp[2]);
        float2 f3 = __half22float2(hp[3]);
        o[0][2 * u].x += p0 * f0.x; o[0][2 * u].y += p0 * f0.y;
        o[0][2 * u].z += p0 * f1.x; o[0][2 * u].w += p0 * f1.y;
        o[0][2 * u + 1].x += p0 * f2.x; o[0][2 * u + 1].y += p0 * f2.y;
        o[0][2 * u + 1].z += p0 * f3.x; o[0][2 * u + 1].w += p0 * f3.y;
        o[1][2 * u].x += p1 * f0.x; o[1][2 * u].y += p1 * f0.y;
        o[1][2 * u].z += p1 * f1.x; o[1][2 * u].w += p1 * f1.y;
        o[1][2 * u + 1].x += p1 * f2.x; o[1][2 * u + 1].y += p1 * f2.y;
        o[1][2 * u + 1].z += p1 * f3.x; o[1][2 * u + 1].w += p1 * f3.y;
      }
    }
    if (biasb && c + 1 < nchunk) {
#pragma unroll
      for (int j = 0; j < NJ; ++j) {
        cb[0][j] = nb[0][j];
        cb[1][j] = nb[1][j];
      }
    }
    __syncthreads();  // drains prefetch vmcnt + LDS reads before buffer reuse
  }
#pragma unroll
  for (int off = 1; off < 64; off <<= 1) {
#pragma unroll
    for (int dd = 0; dd < 8; ++dd) {
      o[0][dd].x += __shfl_xor(o[0][dd].x, off);
      o[0][dd].y += __shfl_xor(o[0][dd].y, off);
      o[0][dd].z += __shfl_xor(o[0][dd].z, off);
      o[0][dd].w += __shfl_xor(o[0][dd].w, off);
      o[1][dd].x += __shfl_xor(o[1][dd].x, off);
      o[1][dd].y += __shfl_xor(o[1][dd].y, off);
      o[1][dd].z += __shfl_xor(o[1][dd].z, off);
      o[1][dd].w += __shfl_xor(o[1][dd].w, off);
    }
  }
  if (kc == 0) {
    const float inv = 1.f / l_run[0];
#pragma unroll
    for (int dd = 0; dd < 8; ++dd) {
      float4 v = o[0][dd];
      v.x *= inv; v.y *= inv; v.z *= inv; v.w *= inv;
      ((float4*)O)[(size_t)(b * NQn + q0 + 2 * w) * 64 + h * 8 + dd] = v;
    }
  } else if (kc == 1) {
    const float inv = 1.f / l_run[1];
#pragma unroll
    for (int dd = 0; dd < 8; ++dd) {
      float4 v = o[1][dd];
      v.x *= inv; v.y *= inv; v.z *= inv; v.w *= inv;
      ((float4*)O)[(size_t)(b * NQn + q0 + 2 * w + 1) * 64 + h * 8 + dd] = v;
    }
  }
}

// ---------------------------------------------------------------------------
// fsb: fused flash-self (blocks 0..511, CHUNK=128) + bias materialization
// (512..1023). Independent work; bias's memory-bound work overlaps flash.
// ---------------------------------------------------------------------------
__global__ __launch_bounds__(256, 2) void fsb_kernel(
    float* __restrict__ O, const float* __restrict__ Q,
    const __half* __restrict__ kT, const __half* __restrict__ vT,
    __half* __restrict__ biasb, const float* __restrict__ rel,
    const float* __restrict__ pad, const float* __restrict__ tsg,
    const float* __restrict__ Stabg, const float* __restrict__ Btabg)
{
  __shared__ __align__(16) char smem[34880];
  const int bx = blockIdx.x;
  if (bx < 512) {
    flash_body<128>(smem, bx & 31, bx >> 5, O, Q, kT, vT, nullptr, NQn);
  } else {
    bias_body(smem, bx - 512, biasb, rel, pad, tsg, Stabg, Btabg);
  }
}

// ---------------------------------------------------------------------------
// flash standalone (cross, CHUNK=256): grid (NQ/8, B*H), 256 threads.
// 66.5 KB LDS -> 2 blocks/CU, 512 blocks in one round; 4 chunks of 256 keys
// amortize per-chunk barrier + softmax-chain overhead 2x vs CHUNK=128.
// ---------------------------------------------------------------------------
__global__ __launch_bounds__(256, 2) void flash_kernel(
    float* __restrict__ O, const float* __restrict__ Q,
    const __half* __restrict__ kT, const __half* __restrict__ vT,
    const __half* __restrict__ biasb, int NK)
{
  __shared__ __align__(16) char smem[66560];
  flash_body<256>(smem, blockIdx.x, blockIdx.y, O, Q, kT, vT, biasb, NK);
}

// ---------------------------------------------------------------------------
// gemm32: 32x32 tile, 256 threads, 2x2/thread, K-step 32, float4 staging with
// register prefetch. Split-K via blockIdx.z (partials at kz*M*N). relu opt.
// ---------------------------------------------------------------------------
__global__ __launch_bounds__(256) void gemm32_kernel(
    float* __restrict__ C, const float* __restrict__ A, const float* __restrict__ A2,
    const float* __restrict__ W, const float* __restrict__ bias,
    int N, int Kchunk, int Ktot, float scale, int do_relu)
{
  __shared__ float As[32][33];
  __shared__ float Ws[32][33];
  const int bm = blockIdx.y * 32, bn = blockIdx.x * 32;
  const int kz = blockIdx.z;
  const int M = gridDim.y * 32;
  float* Cp = C + (size_t)kz * M * N;
  const int tid = threadIdx.x;
  const int tx = tid & 15, ty = tid >> 4;
  const int lr = tid >> 3, lc = (tid & 7) * 4;
  float acc[2][2] = {};
  const int k00 = kz * Kchunk;
  float4 av, wv;
  {
    av = *(const float4*)(A + (size_t)(bm + lr) * Ktot + k00 + lc);
    if (A2) {
      float4 bv = *(const float4*)(A2 + (size_t)(bm + lr) * Ktot + k00 + lc);
      av.x += bv.x; av.y += bv.y; av.z += bv.z; av.w += bv.w;
    }
    wv = *(const float4*)(W + (size_t)(bn + lr) * Ktot + k00 + lc);
  }
  for (int k0 = k00; k0 < k00 + Kchunk; k0 += 32) {
    As[lr][lc] = av.x; As[lr][lc + 1] = av.y; As[lr][lc + 2] = av.z; As[lr][lc + 3] = av.w;
    Ws[lr][lc] = wv.x; Ws[lr][lc + 1] = wv.y; Ws[lr][lc + 2] = wv.z; Ws[lr][lc + 3] = wv.w;
    __syncthreads();
    if (k0 + 32 < k00 + Kchunk) {
      av = *(const float4*)(A + (size_t)(bm + lr) * Ktot + k0 + 32 + lc);
      if (A2) {
        float4 bv = *(const float4*)(A2 + (size_t)(bm + lr) * Ktot + k0 + 32 + lc);
        av.x += bv.x; av.y += bv.y; av.z += bv.z; av.w += bv.w;
      }
      wv = *(const float4*)(W + (size_t)(bn + lr) * Ktot + k0 + 32 + lc);
    }
#pragma unroll
    for (int k = 0; k < 32; ++k) {
      float a0 = As[ty * 2][k], a1 = As[ty * 2 + 1][k];
      float w0 = Ws[tx * 2][k], w1 = Ws[tx * 2 + 1][k];
      acc[0][0] += a0 * w0; acc[0][1] += a0 * w1;
      acc[1][0] += a1 * w0; acc[1][1] += a1 * w1;
    }
    __syncthreads();
  }
#pragma unroll
  for (int i = 0; i < 2; ++i) {
    int m = bm + ty * 2 + i;
#pragma unroll
    for (int j = 0; j < 2; ++j) {
      int n = bn + tx * 2 + j;
      float v = acc[i][j];
      if (bias) v += bias[n];
      v *= scale;
      if (do_relu) v = fmaxf(v, 0.f);
      Cp[(size_t)m * N + n] = v;
    }
  }
}

// ---------------------------------------------------------------------------
// out = LayerNorm(resid + sum_{s<nsplit} part[s] + bias) * g + b.
// Generalized split-K reducer + residual + LN. grid: rows, block = 256 = D.
// ---------------------------------------------------------------------------
__global__ __launch_bounds__(256) void reduce_ln_kernel(
    float* __restrict__ out, const float* __restrict__ part,
    const float* __restrict__ bias, const float* __restrict__ resid,
    const float* __restrict__ g, const float* __restrict__ bt, int nsplit)
{
  const int row = blockIdx.x;
  const int t = threadIdx.x;
  const size_t idx = (size_t)row * Dn + t;
  const size_t STR = (size_t)Bb * NQn * Dn;
  float v = bias[t] + resid[idx];
  for (int s = 0; s < nsplit; ++s) v += part[idx + (size_t)s * STR];
  float sm = v, s2 = v * v;
#pragma unroll
  for (int off = 32; off > 0; off >>= 1) {
    sm += __shfl_down(sm, off);
    s2 += __shfl_down(s2, off);
  }
  __shared__ float rs[4], rs2[4], fin[2];
  const int lane = t & 63, wid = t >> 6;
  if (lane == 0) { rs[wid] = sm; rs2[wid] = s2; }
  __syncthreads();
  if (t == 0) {
    float a = rs[0] + rs[1] + rs[2] + rs[3];
    float a2 = rs2[0] + rs2[1] + rs2[2] + rs2[3];
    float mean = a * (1.f / Dn);
    float var = a2 * (1.f / Dn) - mean * mean;
    fin[0] = mean;
    fin[1] = rsqrtf(var + EPSf);
  }
  __syncthreads();
  out[idx] = (v - fin[0]) * fin[1] * g[t] + bt[t];
}

extern "C" void kernel_launch(void* const* d_in, const int* in_sizes, int n_in,
                              void* d_out, int out_size, void* d_ws, size_t ws_size,
                              hipStream_t stream)
{
  const float* tgt   = (const float*)d_in[0];
  const float* qpos  = (const float*)d_in[1];
  const float* src   = (const float*)d_in[2];
  const float* spe   = (const float*)d_in[3];
  const float* pad   = (const float*)d_in[4];
  const float* rel   = (const float*)d_in[5];
  const float* qw    = (const float*)d_in[6];
  const float* qb    = (const float*)d_in[7];
  const float* kw    = (const float*)d_in[8];
  const float* kb    = (const float*)d_in[9];
  const float* vw    = (const float*)d_in[10];
  const float* vb    = (const float*)d_in[11];
  const float* projw = (const float*)d_in[12];
  const float* projb = (const float*)d_in[13];
  const float* cpbw1 = (const float*)d_in[14];
  const float* cpbb1 = (const float*)d_in[15];
  const float* cpbw2 = (const float*)d_in[16];
  const float* ipw   = (const float*)d_in[17];
  const float* ipb   = (const float*)d_in[18];
  const float* outw  = (const float*)d_in[19];
  const float* outb  = (const float*)d_in[20];
  const float* ln1g  = (const float*)d_in[21];
  const float* ln1b  = (const float*)d_in[22];
  const float* ln2g  = (const float*)d_in[23];
  const float* ln2b  = (const float*)d_in[24];
  const float* ln3g  = (const float*)d_in[25];
  const float* ln3b  = (const float*)d_in[26];
  const float* ff1w  = (const float*)d_in[27];
  const float* ff1b  = (const float*)d_in[28];
  const float* ff2w  = (const float*)d_in[29];
  const float* ff2b  = (const float*)d_in[30];
  float* out = (float*)d_out;
  float* ws = (float*)d_ws;

  constexpr size_t SZ_Q   = (size_t)Bb * NQn * Dn;   // 131072
  constexpr size_t SZ_S   = (size_t)Bb * NSn * Dn;   // 524288
  constexpr size_t SZ_FFH = (size_t)Bb * NQn * FFNn; // 524288

  float* qSb  = ws;
  __half* kSb = (__half*)(qSb + SZ_Q);   // head-major fp16 kT (self)
  __half* vSb = (__half*)(qSb + 2 * SZ_Q);
  float* oSb  = ws + 3 * SZ_Q;
  float* soP  = oSb + SZ_Q;              // (layout stability)
  float* tgt2 = soP + SZ_Q;
  float* qCb  = tgt2 + SZ_Q;
  __half* kCb = (__half*)(qCb + SZ_Q);   // head-major fp16 kT (cross)
  __half* vCb = (__half*)(qCb + SZ_Q + SZ_S);
  float* oCb  = qCb + SZ_Q + 2 * SZ_S;
  float* coP  = oCb + SZ_Q;              // (layout stability)
  float* tgt3 = coP + SZ_Q;
  float* ffh  = tgt3 + SZ_Q;
  float* part = ffh + SZ_FFH;            // 4 * SZ_Q partials scratch
  float* tsb  = part + 4 * SZ_Q;
  float* Stab = tsb + RPEn;
  float* Btab = Stab + (RPEn + 1) * Hn;
  __half* biasb = (__half*)(Btab + (RPEn + 1) * Hn);

  const int MQ = Bb * NQn;  // 512

  // 1. prep: cpb tables + self QKV + cross KV (K/V transposed fp16 head-major)
  prep_kernel<<<dim3(96 + 256 + 1), dim3(512), 0, stream>>>(
      qSb, kSb, vSb, kCb, vCb, tgt, qpos, src, spe, ipw, ipb,
      kw, kb, vw, vb, cpbw1, cpbb1, cpbw2, tsb, Stab, Btab);

  // 2. fused: flash self (512 blocks) + fp16 bias materialization (512 blocks)
  fsb_kernel<<<dim3(1024), dim3(256), 0, stream>>>(
      oSb, qSb, kSb, vSb, biasb, rel, pad, tsb, Stab, Btab);

  // 3. self out-proj, split-K x2 -> partials (bias deferred to reducer)
  gemm32_kernel<<<dim3(Dn / 32, MQ / 32, 2), dim3(256), 0, stream>>>(
      part, oSb, nullptr, outw, nullptr, Dn, 128, Dn, 1.f, 0);

  // 4. tgt2 = LN2(tgt + sum(part) + outb)
  reduce_ln_kernel<<<dim3(MQ), dim3(256), 0, stream>>>(
      tgt2, part, outb, tgt, ln2g, ln2b, 2);

  // 5. cross q
  gemm32_kernel<<<dim3(Dn / 32, MQ / 32, 1), dim3(256), 0, stream>>>(
      qCb, tgt2, qpos, qw, qb, Dn, Dn, Dn, SCALEf, 0);

  // 6. cross attention (CHUNK=256 flash, fp16 K/V + fp16 staged bias)
  flash_kernel<<<dim3(NQn / 8, Bb * Hn), dim3(256), 0, stream>>>(
      oCb, qCb, kCb, vCb, biasb, NSn);

  // 7. cross out-proj, split-K x2 -> partials
  gemm32_kernel<<<dim3(Dn / 32, MQ / 32, 2), dim3(256), 0, stream>>>(
      part, oCb, nullptr, projw, nullptr, Dn, 128, Dn, 1.f, 0);

  // 8. tgt3 = LN1(tgt2 + sum(part) + projb)
  reduce_ln_kernel<<<dim3(MQ), dim3(256), 0, stream>>>(
      tgt3, part, projb, tgt2, ln1g, ln1b, 2);

  // 9. FFN1 (relu) as gemm32: 512 blocks (full GPU)
  gemm32_kernel<<<dim3(FFNn / 32, MQ / 32, 1), dim3(256), 0, stream>>>(
      ffh, tgt3, nullptr, ff1w, ff1b, FFNn, Dn, Dn, 1.f, 1);

  // 10. FFN2 split-K x4 -> partials
  gemm32_kernel<<<dim3(Dn / 32, MQ / 32, 4), dim3(256), 0, stream>>>(
      part, ffh, nullptr, ff2w, nullptr, Dn, 256, FFNn, 1.f, 0);

  // 11. out = LN3(tgt3 + sum(part) + ff2b)
  reduce_ln_kernel<<<dim3(MQ), dim3(256), 0, stream>>>(
      out, part, ff2b, tgt3, ln3g, ln3b, 4);
}

// Round 19
// 121.131 us; speedup vs baseline: 1.0500x; 1.0370x over previous
//
#include <hip/hip_runtime.h>
#include <hip/hip_bf16.h>
#include <hip/hip_fp16.h>
#include <math.h>

#define Bb 2
#define NQn 256
#define NSn 1024
#define Dn 256
#define Hn 8
#define DHn 32
#define FFNn 1024
#define RPEn 512
#define SCALEf 0.17677669529663687f
#define EPSf 1e-5f

#if defined(__has_builtin)
#if __has_builtin(__builtin_amdgcn_fdot2)
#define HAS_FDOT2 1
#endif
#endif
#ifndef HAS_FDOT2
#define HAS_FDOT2 0
#endif

typedef _Float16 h2f __attribute__((ext_vector_type(2)));

// async global->LDS, 16B per lane. LDS dest must be linear in lane order
// (wave-uniform base + lane*16); global src is per-lane (pre-swizzled).
#define GLDS16(g, l)                                                         \
  __builtin_amdgcn_global_load_lds(                                          \
      (const __attribute__((address_space(1))) void*)(const void*)(g),       \
      (__attribute__((address_space(3))) void*)(void*)(l), 16, 0, 0)

// ---------------------------------------------------------------------------
// gemm64 body: 64x64 tile, 512 threads, K-step 32, float4 loads, reg prefetch.
// trsh != 0: write transposed head-major FP16 Ch[((b*H+h)<<trsh)+kseq][32].
// ---------------------------------------------------------------------------
__device__ __forceinline__ void gemm64_body(
    float* __restrict__ C, __half* __restrict__ Ch, int ldc,
    const float* __restrict__ A, const float* __restrict__ A2, int ld,
    const float* __restrict__ W, const float* __restrict__ bias,
    int K, int bm, int bnC, int bnW, float scale, int do_relu, int trsh,
    float (*As)[33], float (*WsT)[68])
{
  const int tid = threadIdx.x;
  const int tx = tid & 15, ty = tid >> 4;       // ty 0..31
  const int lr = tid >> 3, lc = (tid & 7) * 4;  // staging coords
  float4 ra, rw;
  {
    ra = *(const float4*)(A + (size_t)(bm + lr) * ld + lc);
    if (A2) {
      float4 t = *(const float4*)(A2 + (size_t)(bm + lr) * ld + lc);
      ra.x += t.x; ra.y += t.y; ra.z += t.z; ra.w += t.w;
    }
    rw = *(const float4*)(W + (size_t)(bnW + lr) * ld + lc);
  }
  float acc[2][4] = {};
  for (int k0 = 0; k0 < K; k0 += 32) {
    As[lr][lc] = ra.x; As[lr][lc + 1] = ra.y;
    As[lr][lc + 2] = ra.z; As[lr][lc + 3] = ra.w;
    WsT[lc][lr] = rw.x; WsT[lc + 1][lr] = rw.y;
    WsT[lc + 2][lr] = rw.z; WsT[lc + 3][lr] = rw.w;
    __syncthreads();
    if (k0 + 32 < K) {
      ra = *(const float4*)(A + (size_t)(bm + lr) * ld + k0 + 32 + lc);
      if (A2) {
        float4 t = *(const float4*)(A2 + (size_t)(bm + lr) * ld + k0 + 32 + lc);
        ra.x += t.x; ra.y += t.y; ra.z += t.z; ra.w += t.w;
      }
      rw = *(const float4*)(W + (size_t)(bnW + lr) * ld + k0 + 32 + lc);
    }
#pragma unroll
    for (int k = 0; k < 32; ++k) {
      float a0 = As[ty][k], a1 = As[ty + 32][k];
      float4 w = *(const float4*)&WsT[k][tx * 4];
      acc[0][0] += a0 * w.x; acc[0][1] += a0 * w.y;
      acc[0][2] += a0 * w.z; acc[0][3] += a0 * w.w;
      acc[1][0] += a1 * w.x; acc[1][1] += a1 * w.y;
      acc[1][2] += a1 * w.z; acc[1][3] += a1 * w.w;
    }
    __syncthreads();
  }
#pragma unroll
  for (int i = 0; i < 2; ++i) {
    int m = bm + ty + i * 32;
#pragma unroll
    for (int j = 0; j < 4; ++j) {
      float v = acc[i][j];
      if (bias) v += bias[bnW + tx * 4 + j];
      v *= scale;
      if (do_relu) v = fmaxf(v, 0.f);
      if (trsh == 0) {
        C[(size_t)m * ldc + bnC + tx * 4 + j] = v;
      } else {
        const int nC = bnC + tx * 4 + j;
        const int bb = m >> trsh, kseq = m & ((1 << trsh) - 1);
        const int hh = nC >> 5, d = nC & 31;
        Ch[((((size_t)(bb * Hn + hh)) << trsh) + kseq) * 32 + d] =
            __float2half(v);
      }
    }
  }
}

// ---------------------------------------------------------------------------
// prep: fused build_cpb (1 block) + self QKV GEMM (96 blocks; K/V written
// head-major transposed fp16) + cross KV GEMM (256 blocks). 512 threads.
// ---------------------------------------------------------------------------
__global__ __launch_bounds__(512) void prep_kernel(
    float* __restrict__ qSb, __half* __restrict__ kSb, __half* __restrict__ vSb,
    __half* __restrict__ kCb, __half* __restrict__ vCb,
    const float* __restrict__ tgt, const float* __restrict__ qpos,
    const float* __restrict__ src, const float* __restrict__ spe,
    const float* __restrict__ ipw, const float* __restrict__ ipb,
    const float* __restrict__ kw, const float* __restrict__ kb,
    const float* __restrict__ vw, const float* __restrict__ vb,
    const float* __restrict__ w1p, const float* __restrict__ b1p,
    const float* __restrict__ w2p,
    float* __restrict__ tout, float* __restrict__ Stab, float* __restrict__ Btab)
{
  __shared__ float smem[4288];  // As 64*33=2112 + WsT 32*68=2176
  const int bx = blockIdx.x;
  const int tid = threadIdx.x;
  if (bx < 96) {
    float (*As)[33] = (float(*)[33])smem;
    float (*WsT)[68] = (float(*)[68])(smem + 2112);
    int my = bx & 7, nx = bx >> 3;
    int sec = nx >> 2;
    gemm64_body(qSb, sec == 1 ? kSb : vSb, Dn, tgt,
                sec < 2 ? qpos : nullptr, Dn, ipw, ipb,
                Dn, my * 64, (nx & 3) * 64, nx * 64,
                sec == 0 ? SCALEf : 1.f, 0, sec == 0 ? 0 : 8, As, WsT);
    return;
  }
  if (bx < 96 + 256) {
    float (*As)[33] = (float(*)[33])smem;
    float (*WsT)[68] = (float(*)[68])(smem + 2112);
    int idx = bx - 96;
    int my = idx & 31, nx = idx >> 5;
    int sec = nx >> 2;
    gemm64_body(nullptr, sec ? vCb : kCb, Dn, src, sec ? nullptr : spe, Dn,
                sec ? vw : kw, sec ? vb : kb,
                Dn, my * 64, (nx & 3) * 64, (nx & 3) * 64, 1.f, 0, 10, As, WsT);
    return;
  }
  // ---- cpb piecewise-linear table build (verified rounds 1-18) ----
  float* key = smem;
  int* pidx = (int*)(smem + 512);
  float* w1s = smem + 1024;
  float* b1s = smem + 1536;
  {
    float w = w1p[tid], bb = b1p[tid];
    key[tid] = (w != 0.f) ? (-bb / w) : 3.0e38f;
    pidx[tid] = tid;
  }
  __syncthreads();
  for (int k = 2; k <= RPEn; k <<= 1) {
    for (int j = k >> 1; j > 0; j >>= 1) {
      int ixj = tid ^ j;
      if (ixj > tid) {
        float a = key[tid], c = key[ixj];
        bool asc = ((tid & k) == 0);
        bool sw = asc ? (a > c) : (a < c);
        if (sw) {
          key[tid] = c; key[ixj] = a;
          int tmp = pidx[tid]; pidx[tid] = pidx[ixj]; pidx[ixj] = tmp;
        }
      }
      __syncthreads();
    }
  }
  w1s[tid] = w1p[pidx[tid]];
  b1s[tid] = b1p[pidx[tid]];
  tout[tid] = key[tid];
  __syncthreads();
  const int lane = tid & 63;
  const int h = tid >> 6;
  const int j0 = lane * 8;
  float sp[8], bp[8], sn[8], bn[8];
  float csp = 0.f, cbp = 0.f, csn = 0.f, cbn = 0.f, ccc = 0.f;
#pragma unroll
  for (int e = 0; e < 8; ++e) {
    int j = j0 + e;
    float w = w1s[j], b = b1s[j];
    float c = w2p[h * RPEn + pidx[j]];
    sp[e] = csp; bp[e] = cbp; sn[e] = csn; bn[e] = cbn;
    if (w > 0.f)      { csp += w * c; cbp += b * c; }
    else if (w < 0.f) { csn += w * c; cbn += b * c; }
    else              { ccc += fmaxf(b, 0.f) * c; }
  }
  float isp = csp, ibp = cbp, isn = csn, ibn = cbn, icc = ccc;
#pragma unroll
  for (int d = 1; d < 64; d <<= 1) {
    float t0 = __shfl_up(isp, d);
    float t1 = __shfl_up(ibp, d);
    float t2 = __shfl_up(isn, d);
    float t3 = __shfl_up(ibn, d);
    if (lane >= d) { isp += t0; ibp += t1; isn += t2; ibn += t3; }
    icc += __shfl_xor(icc, d);
  }
  const float tsn = __shfl(isn, 63);
  const float tbn = __shfl(ibn, 63);
  const float esp = isp - csp, ebp = ibp - cbp;
  const float esn = isn - csn, ebn = ibn - cbn;
#pragma unroll
  for (int e = 0; e < 8; ++e) {
    int j = j0 + e;
    Stab[j * Hn + h] = (esp + sp[e]) + (tsn - (esn + sn[e]));
    Btab[j * Hn + h] = (ebp + bp[e]) + (tbn - (ebn + bn[e])) + icc;
  }
  if (lane == 63) {
    Stab[RPEn * Hn + h] = isp;
    Btab[RPEn * Hn + h] = ibp + icc;
  }
}

// ---------------------------------------------------------------------------
// bias body: fp16 bias[b,h,q,k] = Sh[lo]*m + Bh[lo] - 100*pad. One block per
// (b,q); search once per (b,q,k), applied to 8 heads. LDS carved from smem.
// ---------------------------------------------------------------------------
__device__ __forceinline__ void bias_body(
    char* smemraw, int idx,
    __half* __restrict__ biasb, const float* __restrict__ rel,
    const float* __restrict__ pad, const float* __restrict__ tsg,
    const float* __restrict__ Stabg, const float* __restrict__ Btabg)
{
  float* ts = (float*)smemraw;                    // 512 f
  float* Sh = (float*)(smemraw + 2048);           // 4104 f
  float* Bh = (float*)(smemraw + 18464);          // 4104 f
  const int tid = threadIdx.x;
  const int b = idx >> 8, q = idx & 255;
  ts[tid] = tsg[tid];
  ts[tid + 256] = tsg[tid + 256];
  for (int i = tid; i < (RPEn + 1) * Hn; i += 256) {
    Sh[i] = Stabg[i];
    Bh[i] = Btabg[i];
  }
  __syncthreads();
#pragma unroll
  for (int j = 0; j < 4; ++j) {
    const int k = tid + j * 256;
    const float m = rel[((size_t)b * NQn + q) * NSn + k];
    const float padv = -100.f * pad[b * NSn + k];
    int lo = 0, hi = RPEn;
#pragma unroll
    for (int it = 0; it < 9; ++it) {
      int mid = (lo + hi) >> 1;
      if (ts[mid] < m) lo = mid + 1; else hi = mid;
    }
#pragma unroll
    for (int h = 0; h < Hn; ++h) {
      biasb[(((size_t)(b * Hn + h)) * NQn + q) * NSn + k] =
          __float2half(Sh[lo * Hn + h] * m + Bh[lo * Hn + h] + padv);
    }
  }
}

// ---------------------------------------------------------------------------
// Flash body (verified rounds 14-18), templated on CHUNK (keys per LDS tile).
// R=2 rows/thread, HEAD-MAJOR FP16 K/V (kT/vT [b][h][k][32], rows = 64B =
// 4 float4 units). Rotation swizzle o(k)=(k+(k>>2))&3 in ADDRESS arithmetic
// only. 256 threads = 4 waves; wave w owns rows {2w,2w+1}; lane kc handles
// keys kc + j*64. Double-buffered gload_lds; fp16 bias in registers.
// NEW (r19): q held as packed fp16 (h2f[2][16], 32 VGPRs); QK inner product
// uses v_dot2_f32_f16 (8 fdot2 per unit per row-pair instead of 16 FMA +
// 8 cvt) -- 3x fewer QK VALU ops. PV unchanged (f32 accumulate).
// ---------------------------------------------------------------------------
template <int CHUNK>
__device__ __forceinline__ void flash_body(
    char* smemraw, int qb, int bh,
    float* __restrict__ O, const float* __restrict__ Q,
    const __half* __restrict__ kT, const __half* __restrict__ vT,
    const __half* __restrict__ biasb, int NK)
{
  constexpr int NJ = CHUNK / 64;        // keys per lane per chunk
  constexpr int NS = CHUNK / 64;        // stage iters
  float4 (*Ks)[CHUNK * 4] = (float4(*)[CHUNK * 4])smemraw;
  float4 (*Vs)[CHUNK * 4] = (float4(*)[CHUNK * 4])(smemraw + CHUNK * 128);
  float4* Qs = (float4*)(smemraw + CHUNK * 256);
  const int b = bh >> 3, h = bh & 7;
  const int q0 = qb * 8;
  const int tid = threadIdx.x;
  const int w = tid >> 6, kc = tid & 63;
  const float4* Ktp = (const float4*)kT + (size_t)bh * NK * 4;
  const float4* Vtp = (const float4*)vT + (size_t)bh * NK * 4;
  if (tid < 64)
    Qs[tid] = ((const float4*)Q)[(size_t)(b * NQn + q0 + (tid >> 3)) * 64 +
                                 h * 8 + (tid & 7)];

  const __half* brow0 =
      biasb ? biasb + ((size_t)bh * NQn + q0 + 2 * w) * NK : nullptr;
  const __half* brow1 = biasb ? brow0 + NK : nullptr;

  auto stage = [&](int buf, int kb0) {
#pragma unroll
    for (int u = 0; u < NS; ++u) {
      const int s = tid + u * 256;   // linear LDS slot (lane order)
      const int k = s >> 2, e = s & 3;
      const int ok = (k + (k >> 2)) & 3;
      const int g = (kb0 + k) * 4 + ((e - ok) & 3);
      GLDS16(Ktp + g, &Ks[buf][s]);
      GLDS16(Vtp + g, &Vs[buf][s]);
    }
  };

  stage(0, 0);
  float cb[2][NJ];
  if (biasb) {
#pragma unroll
    for (int j = 0; j < NJ; ++j) {
      cb[0][j] = __half2float(brow0[kc + j * 64]);
      cb[1][j] = __half2float(brow1[kc + j * 64]);
    }
  }
  __syncthreads();  // drains vmcnt: chunk 0 + Qs ready

  // q rows packed to fp16 pairs: qh[r][2*dd+p] covers elems {8dd+4p .. +3}/2
  h2f qh[2][16];
#pragma unroll
  for (int dd = 0; dd < 8; ++dd) {
    float4 v0 = Qs[(2 * w) * 8 + dd];
    float4 v1 = Qs[(2 * w + 1) * 8 + dd];
    h2f t;
    t.x = (_Float16)v0.x; t.y = (_Float16)v0.y; qh[0][2 * dd] = t;
    t.x = (_Float16)v0.z; t.y = (_Float16)v0.w; qh[0][2 * dd + 1] = t;
    t.x = (_Float16)v1.x; t.y = (_Float16)v1.y; qh[1][2 * dd] = t;
    t.x = (_Float16)v1.z; t.y = (_Float16)v1.w; qh[1][2 * dd + 1] = t;
  }
  float4 o[2][8] = {};
  float m_run[2] = {-3.0e38f, -3.0e38f};
  float l_run[2] = {0.f, 0.f};
  const int nchunk = NK / CHUNK;
  const int ox = (kc + (kc >> 2)) & 3;  // row-rot key, invariant to j*64

  for (int c = 0; c < nchunk; ++c) {
    const int cur = c & 1;
    float nb[2][NJ];
    if (c + 1 < nchunk) {
      stage(cur ^ 1, (c + 1) * CHUNK);  // prefetch flies under compute
      if (biasb) {
#pragma unroll
        for (int j = 0; j < NJ; ++j) {
          nb[0][j] = __half2float(brow0[(c + 1) * CHUNK + kc + j * 64]);
          nb[1][j] = __half2float(brow1[(c + 1) * CHUNK + kc + j * 64]);
        }
      }
    }
    float s[2][NJ];
#pragma unroll
    for (int j = 0; j < NJ; ++j) {
      const int kbase = (kc + j * 64) * 4;
      float a0 = 0.f, a1 = 0.f;
#pragma unroll
      for (int u = 0; u < 4; ++u) {
        float4 raw = Ks[cur][kbase + ((u + ox) & 3)];  // = unit u of row k
        const h2f* kp = (const h2f*)&raw;
#if HAS_FDOT2
#pragma unroll
        for (int m2 = 0; m2 < 4; ++m2) {
          a0 = __builtin_amdgcn_fdot2(qh[0][4 * u + m2], kp[m2], a0, false);
          a1 = __builtin_amdgcn_fdot2(qh[1][4 * u + m2], kp[m2], a1, false);
        }
#else
#pragma unroll
        for (int m2 = 0; m2 < 4; ++m2) {
          const h2f kk = kp[m2];
          const h2f q0h = qh[0][4 * u + m2];
          const h2f q1h = qh[1][4 * u + m2];
          a0 += (float)q0h.x * (float)kk.x + (float)q0h.y * (float)kk.y;
          a1 += (float)q1h.x * (float)kk.x + (float)q1h.y * (float)kk.y;
        }
#endif
      }
      s[0][j] = a0;
      s[1][j] = a1;
      if (biasb) { s[0][j] += cb[0][j]; s[1][j] += cb[1][j]; }
    }
    float f[2];
#pragma unroll
    for (int r = 0; r < 2; ++r) {
      float cmax = s[r][0];
#pragma unroll
      for (int j = 1; j < NJ; ++j) cmax = fmaxf(cmax, s[r][j]);
#pragma unroll
      for (int off = 1; off < 64; off <<= 1)
        cmax = fmaxf(cmax, __shfl_xor(cmax, off));
      const float m_new = fmaxf(m_run[r], cmax);
      f[r] = __expf(m_run[r] - m_new);
      float ls = 0.f;
#pragma unroll
      for (int j = 0; j < NJ; ++j) {
        s[r][j] = __expf(s[r][j] - m_new);
        ls += s[r][j];
      }
#pragma unroll
      for (int off = 1; off < 64; off <<= 1) ls += __shfl_xor(ls, off);
      l_run[r] = l_run[r] * f[r] + ls;
      m_run[r] = m_new;
    }
#pragma unroll
    for (int dd = 0; dd < 8; ++dd) {
      o[0][dd].x *= f[0]; o[0][dd].y *= f[0]; o[0][dd].z *= f[0]; o[0][dd].w *= f[0];
      o[1][dd].x *= f[1]; o[1][dd].y *= f[1]; o[1][dd].z *= f[1]; o[1][dd].w *= f[1];
    }
#pragma unroll
    for (int j = 0; j < NJ; ++j) {
      const int kbase = (kc + j * 64) * 4;
      const float p0 = s[0][j], p1 = s[1][j];
#pragma unroll
      for (int u = 0; u < 4; ++u) {
        float4 raw = Vs[cur][kbase + ((u + ox) & 3)];  // = unit u of row k
        const __half2* hp = (const __half2*)&raw;
        float2 f0 = __half22float2(hp[0]);
        float2 f1 = __half22float2(hp[1]);
        float2 f2 = __half22float2(hp[2]);
        float2 f3 = __half22float2(hp[3]);
        o[0][2 * u].x += p0 * f0.x; o[0][2 * u].y += p0 * f0.y;
        o[0][2 * u].z += p0 * f1.x; o[0][2 * u].w += p0 * f1.y;
        o[0][2 * u + 1].x += p0 * f2.x; o[0][2 * u + 1].y += p0 * f2.y;
        o[0][2 * u + 1].z += p0 * f3.x; o[0][2 * u + 1].w += p0 * f3.y;
        o[1][2 * u].x += p1 * f0.x; o[1][2 * u].y += p1 * f0.y;
        o[1][2 * u].z += p1 * f1.x; o[1][2 * u].w += p1 * f1.y;
        o[1][2 * u + 1].x += p1 * f2.x; o[1][2 * u + 1].y += p1 * f2.y;
        o[1][2 * u + 1].z += p1 * f3.x; o[1][2 * u + 1].w += p1 * f3.y;
      }
    }
    if (biasb && c + 1 < nchunk) {
#pragma unroll
      for (int j = 0; j < NJ; ++j) {
        cb[0][j] = nb[0][j];
        cb[1][j] = nb[1][j];
      }
    }
    __syncthreads();  // drains prefetch vmcnt + LDS reads before buffer reuse
  }
#pragma unroll
  for (int off = 1; off < 64; off <<= 1) {
#pragma unroll
    for (int dd = 0; dd < 8; ++dd) {
      o[0][dd].x += __shfl_xor(o[0][dd].x, off);
      o[0][dd].y += __shfl_xor(o[0][dd].y, off);
      o[0][dd].z += __shfl_xor(o[0][dd].z, off);
      o[0][dd].w += __shfl_xor(o[0][dd].w, off);
      o[1][dd].x += __shfl_xor(o[1][dd].x, off);
      o[1][dd].y += __shfl_xor(o[1][dd].y, off);
      o[1][dd].z += __shfl_xor(o[1][dd].z, off);
      o[1][dd].w += __shfl_xor(o[1][dd].w, off);
    }
  }
  if (kc == 0) {
    const float inv = 1.f / l_run[0];
#pragma unroll
    for (int dd = 0; dd < 8; ++dd) {
      float4 v = o[0][dd];
      v.x *= inv; v.y *= inv; v.z *= inv; v.w *= inv;
      ((float4*)O)[(size_t)(b * NQn + q0 + 2 * w) * 64 + h * 8 + dd] = v;
    }
  } else if (kc == 1) {
    const float inv = 1.f / l_run[1];
#pragma unroll
    for (int dd = 0; dd < 8; ++dd) {
      float4 v = o[1][dd];
      v.x *= inv; v.y *= inv; v.z *= inv; v.w *= inv;
      ((float4*)O)[(size_t)(b * NQn + q0 + 2 * w + 1) * 64 + h * 8 + dd] = v;
    }
  }
}

// ---------------------------------------------------------------------------
// fsb: fused flash-self (blocks 0..511, CHUNK=128) + bias materialization
// (512..1023). Independent work; bias's memory-bound work overlaps flash.
// ---------------------------------------------------------------------------
__global__ __launch_bounds__(256, 2) void fsb_kernel(
    float* __restrict__ O, const float* __restrict__ Q,
    const __half* __restrict__ kT, const __half* __restrict__ vT,
    __half* __restrict__ biasb, const float* __restrict__ rel,
    const float* __restrict__ pad, const float* __restrict__ tsg,
    const float* __restrict__ Stabg, const float* __restrict__ Btabg)
{
  __shared__ __align__(16) char smem[34880];
  const int bx = blockIdx.x;
  if (bx < 512) {
    flash_body<128>(smem, bx & 31, bx >> 5, O, Q, kT, vT, nullptr, NQn);
  } else {
    bias_body(smem, bx - 512, biasb, rel, pad, tsg, Stabg, Btabg);
  }
}

// ---------------------------------------------------------------------------
// flash standalone (cross, CHUNK=256): grid (NQ/8, B*H), 256 threads.
// 66.5 KB LDS -> 2 blocks/CU, 512 blocks in one round; 4 chunks of 256 keys.
// ---------------------------------------------------------------------------
__global__ __launch_bounds__(256, 2) void flash_kernel(
    float* __restrict__ O, const float* __restrict__ Q,
    const __half* __restrict__ kT, const __half* __restrict__ vT,
    const __half* __restrict__ biasb, int NK)
{
  __shared__ __align__(16) char smem[66560];
  flash_body<256>(smem, blockIdx.x, blockIdx.y, O, Q, kT, vT, biasb, NK);
}

// ---------------------------------------------------------------------------
// gemm32: 32x32 tile, 256 threads, 2x2/thread, K-step 32, float4 staging with
// register prefetch. Split-K via blockIdx.z (partials at kz*M*N). relu opt.
// ---------------------------------------------------------------------------
__global__ __launch_bounds__(256) void gemm32_kernel(
    float* __restrict__ C, const float* __restrict__ A, const float* __restrict__ A2,
    const float* __restrict__ W, const float* __restrict__ bias,
    int N, int Kchunk, int Ktot, float scale, int do_relu)
{
  __shared__ float As[32][33];
  __shared__ float Ws[32][33];
  const int bm = blockIdx.y * 32, bn = blockIdx.x * 32;
  const int kz = blockIdx.z;
  const int M = gridDim.y * 32;
  float* Cp = C + (size_t)kz * M * N;
  const int tid = threadIdx.x;
  const int tx = tid & 15, ty = tid >> 4;
  const int lr = tid >> 3, lc = (tid & 7) * 4;
  float acc[2][2] = {};
  const int k00 = kz * Kchunk;
  float4 av, wv;
  {
    av = *(const float4*)(A + (size_t)(bm + lr) * Ktot + k00 + lc);
    if (A2) {
      float4 bv = *(const float4*)(A2 + (size_t)(bm + lr) * Ktot + k00 + lc);
      av.x += bv.x; av.y += bv.y; av.z += bv.z; av.w += bv.w;
    }
    wv = *(const float4*)(W + (size_t)(bn + lr) * Ktot + k00 + lc);
  }
  for (int k0 = k00; k0 < k00 + Kchunk; k0 += 32) {
    As[lr][lc] = av.x; As[lr][lc + 1] = av.y; As[lr][lc + 2] = av.z; As[lr][lc + 3] = av.w;
    Ws[lr][lc] = wv.x; Ws[lr][lc + 1] = wv.y; Ws[lr][lc + 2] = wv.z; Ws[lr][lc + 3] = wv.w;
    __syncthreads();
    if (k0 + 32 < k00 + Kchunk) {
      av = *(const float4*)(A + (size_t)(bm + lr) * Ktot + k0 + 32 + lc);
      if (A2) {
        float4 bv = *(const float4*)(A2 + (size_t)(bm + lr) * Ktot + k0 + 32 + lc);
        av.x += bv.x; av.y += bv.y; av.z += bv.z; av.w += bv.w;
      }
      wv = *(const float4*)(W + (size_t)(bn + lr) * Ktot + k0 + 32 + lc);
    }
#pragma unroll
    for (int k = 0; k < 32; ++k) {
      float a0 = As[ty * 2][k], a1 = As[ty * 2 + 1][k];
      float w0 = Ws[tx * 2][k], w1 = Ws[tx * 2 + 1][k];
      acc[0][0] += a0 * w0; acc[0][1] += a0 * w1;
      acc[1][0] += a1 * w0; acc[1][1] += a1 * w1;
    }
    __syncthreads();
  }
#pragma unroll
  for (int i = 0; i < 2; ++i) {
    int m = bm + ty * 2 + i;
#pragma unroll
    for (int j = 0; j < 2; ++j) {
      int n = bn + tx * 2 + j;
      float v = acc[i][j];
      if (bias) v += bias[n];
      v *= scale;
      if (do_relu) v = fmaxf(v, 0.f);
      Cp[(size_t)m * N + n] = v;
    }
  }
}

// ---------------------------------------------------------------------------
// out = LayerNorm(resid + sum_{s<nsplit} part[s] + bias) * g + b.
// Generalized split-K reducer + residual + LN. grid: rows, block = 256 = D.
// ---------------------------------------------------------------------------
__global__ __launch_bounds__(256) void reduce_ln_kernel(
    float* __restrict__ out, const float* __restrict__ part,
    const float* __restrict__ bias, const float* __restrict__ resid,
    const float* __restrict__ g, const float* __restrict__ bt, int nsplit)
{
  const int row = blockIdx.x;
  const int t = threadIdx.x;
  const size_t idx = (size_t)row * Dn + t;
  const size_t STR = (size_t)Bb * NQn * Dn;
  float v = bias[t] + resid[idx];
  for (int s = 0; s < nsplit; ++s) v += part[idx + (size_t)s * STR];
  float sm = v, s2 = v * v;
#pragma unroll
  for (int off = 32; off > 0; off >>= 1) {
    sm += __shfl_down(sm, off);
    s2 += __shfl_down(s2, off);
  }
  __shared__ float rs[4], rs2[4], fin[2];
  const int lane = t & 63, wid = t >> 6;
  if (lane == 0) { rs[wid] = sm; rs2[wid] = s2; }
  __syncthreads();
  if (t == 0) {
    float a = rs[0] + rs[1] + rs[2] + rs[3];
    float a2 = rs2[0] + rs2[1] + rs2[2] + rs2[3];
    float mean = a * (1.f / Dn);
    float var = a2 * (1.f / Dn) - mean * mean;
    fin[0] = mean;
    fin[1] = rsqrtf(var + EPSf);
  }
  __syncthreads();
  out[idx] = (v - fin[0]) * fin[1] * g[t] + bt[t];
}

extern "C" void kernel_launch(void* const* d_in, const int* in_sizes, int n_in,
                              void* d_out, int out_size, void* d_ws, size_t ws_size,
                              hipStream_t stream)
{
  const float* tgt   = (const float*)d_in[0];
  const float* qpos  = (const float*)d_in[1];
  const float* src   = (const float*)d_in[2];
  const float* spe   = (const float*)d_in[3];
  const float* pad   = (const float*)d_in[4];
  const float* rel   = (const float*)d_in[5];
  const float* qw    = (const float*)d_in[6];
  const float* qb    = (const float*)d_in[7];
  const float* kw    = (const float*)d_in[8];
  const float* kb    = (const float*)d_in[9];
  const float* vw    = (const float*)d_in[10];
  const float* vb    = (const float*)d_in[11];
  const float* projw = (const float*)d_in[12];
  const float* projb = (const float*)d_in[13];
  const float* cpbw1 = (const float*)d_in[14];
  const float* cpbb1 = (const float*)d_in[15];
  const float* cpbw2 = (const float*)d_in[16];
  const float* ipw   = (const float*)d_in[17];
  const float* ipb   = (const float*)d_in[18];
  const float* outw  = (const float*)d_in[19];
  const float* outb  = (const float*)d_in[20];
  const float* ln1g  = (const float*)d_in[21];
  const float* ln1b  = (const float*)d_in[22];
  const float* ln2g  = (const float*)d_in[23];
  const float* ln2b  = (const float*)d_in[24];
  const float* ln3g  = (const float*)d_in[25];
  const float* ln3b  = (const float*)d_in[26];
  const float* ff1w  = (const float*)d_in[27];
  const float* ff1b  = (const float*)d_in[28];
  const float* ff2w  = (const float*)d_in[29];
  const float* ff2b  = (const float*)d_in[30];
  float* out = (float*)d_out;
  float* ws = (float*)d_ws;

  constexpr size_t SZ_Q   = (size_t)Bb * NQn * Dn;   // 131072
  constexpr size_t SZ_S   = (size_t)Bb * NSn * Dn;   // 524288
  constexpr size_t SZ_FFH = (size_t)Bb * NQn * FFNn; // 524288

  float* qSb  = ws;
  __half* kSb = (__half*)(qSb + SZ_Q);   // head-major fp16 kT (self)
  __half* vSb = (__half*)(qSb + 2 * SZ_Q);
  float* oSb  = ws + 3 * SZ_Q;
  float* soP  = oSb + SZ_Q;              // (layout stability)
  float* tgt2 = soP + SZ_Q;
  float* qCb  = tgt2 + SZ_Q;
  __half* kCb = (__half*)(qCb + SZ_Q);   // head-major fp16 kT (cross)
  __half* vCb = (__half*)(qCb + SZ_Q + SZ_S);
  float* oCb  = qCb + SZ_Q + 2 * SZ_S;
  float* coP  = oCb + SZ_Q;              // (layout stability)
  float* tgt3 = coP + SZ_Q;
  float* ffh  = tgt3 + SZ_Q;
  float* part = ffh + SZ_FFH;            // 4 * SZ_Q partials scratch
  float* tsb  = part + 4 * SZ_Q;
  float* Stab = tsb + RPEn;
  float* Btab = Stab + (RPEn + 1) * Hn;
  __half* biasb = (__half*)(Btab + (RPEn + 1) * Hn);

  const int MQ = Bb * NQn;  // 512

  // 1. prep: cpb tables + self QKV + cross KV (K/V transposed fp16 head-major)
  prep_kernel<<<dim3(96 + 256 + 1), dim3(512), 0, stream>>>(
      qSb, kSb, vSb, kCb, vCb, tgt, qpos, src, spe, ipw, ipb,
      kw, kb, vw, vb, cpbw1, cpbb1, cpbw2, tsb, Stab, Btab);

  // 2. fused: flash self (512 blocks) + fp16 bias materialization (512 blocks)
  fsb_kernel<<<dim3(1024), dim3(256), 0, stream>>>(
      oSb, qSb, kSb, vSb, biasb, rel, pad, tsb, Stab, Btab);

  // 3. self out-proj, split-K x2 -> partials (bias deferred to reducer)
  gemm32_kernel<<<dim3(Dn / 32, MQ / 32, 2), dim3(256), 0, stream>>>(
      part, oSb, nullptr, outw, nullptr, Dn, 128, Dn, 1.f, 0);

  // 4. tgt2 = LN2(tgt + sum(part) + outb)
  reduce_ln_kernel<<<dim3(MQ), dim3(256), 0, stream>>>(
      tgt2, part, outb, tgt, ln2g, ln2b, 2);

  // 5. cross q
  gemm32_kernel<<<dim3(Dn / 32, MQ / 32, 1), dim3(256), 0, stream>>>(
      qCb, tgt2, qpos, qw, qb, Dn, Dn, Dn, SCALEf, 0);

  // 6. cross attention (CHUNK=256 flash, fp16 K/V + fp16 staged bias)
  flash_kernel<<<dim3(NQn / 8, Bb * Hn), dim3(256), 0, stream>>>(
      oCb, qCb, kCb, vCb, biasb, NSn);

  // 7. cross out-proj, split-K x2 -> partials
  gemm32_kernel<<<dim3(Dn / 32, MQ / 32, 2), dim3(256), 0, stream>>>(
      part, oCb, nullptr, projw, nullptr, Dn, 128, Dn, 1.f, 0);

  // 8. tgt3 = LN1(tgt2 + sum(part) + projb)
  reduce_ln_kernel<<<dim3(MQ), dim3(256), 0, stream>>>(
      tgt3, part, projb, tgt2, ln1g, ln1b, 2);

  // 9. FFN1 (relu) as gemm32: 512 blocks (full GPU)
  gemm32_kernel<<<dim3(FFNn / 32, MQ / 32, 1), dim3(256), 0, stream>>>(
      ffh, tgt3, nullptr, ff1w, ff1b, FFNn, Dn, Dn, 1.f, 1);

  // 10. FFN2 split-K x4 -> partials
  gemm32_kernel<<<dim3(Dn / 32, MQ / 32, 4), dim3(256), 0, stream>>>(
      part, ffh, nullptr, ff2w, nullptr, Dn, 256, FFNn, 1.f, 0);

  // 11. out = LN3(tgt3 + sum(part) + ff2b)
  reduce_ln_kernel<<<dim3(MQ), dim3(256), 0, stream>>>(
      out, part, ff2b, tgt3, ln3g, ln3b, 4);
}

// Round 20
// 118.703 us; speedup vs baseline: 1.0715x; 1.0205x over previous
//
#include <hip/hip_runtime.h>
#include <hip/hip_bf16.h>
#include <hip/hip_fp16.h>
#include <math.h>

#define Bb 2
#define NQn 256
#define NSn 1024
#define Dn 256
#define Hn 8
#define DHn 32
#define FFNn 1024
#define RPEn 512
#define SCALEf 0.17677669529663687f
#define EPSf 1e-5f

#if defined(__has_builtin)
#if __has_builtin(__builtin_amdgcn_fdot2)
#define HAS_FDOT2 1
#endif
#endif
#ifndef HAS_FDOT2
#define HAS_FDOT2 0
#endif

typedef _Float16 h2f __attribute__((ext_vector_type(2)));

// async global->LDS, 16B per lane. LDS dest must be linear in lane order
// (wave-uniform base + lane*16); global src is per-lane (pre-swizzled).
#define GLDS16(g, l)                                                         \
  __builtin_amdgcn_global_load_lds(                                          \
      (const __attribute__((address_space(1))) void*)(const void*)(g),       \
      (__attribute__((address_space(3))) void*)(void*)(l), 16, 0, 0)

// ---------------------------------------------------------------------------
// gemm64 body: 64x64 tile, 512 threads, K-step 32, float4 loads, reg prefetch.
// trsh != 0: write transposed head-major FP16 Ch[((b*H+h)<<trsh)+kseq][32].
// ---------------------------------------------------------------------------
__device__ __forceinline__ void gemm64_body(
    float* __restrict__ C, __half* __restrict__ Ch, int ldc,
    const float* __restrict__ A, const float* __restrict__ A2, int ld,
    const float* __restrict__ W, const float* __restrict__ bias,
    int K, int bm, int bnC, int bnW, float scale, int do_relu, int trsh,
    float (*As)[33], float (*WsT)[68])
{
  const int tid = threadIdx.x;
  const int tx = tid & 15, ty = tid >> 4;       // ty 0..31
  const int lr = tid >> 3, lc = (tid & 7) * 4;  // staging coords
  float4 ra, rw;
  {
    ra = *(const float4*)(A + (size_t)(bm + lr) * ld + lc);
    if (A2) {
      float4 t = *(const float4*)(A2 + (size_t)(bm + lr) * ld + lc);
      ra.x += t.x; ra.y += t.y; ra.z += t.z; ra.w += t.w;
    }
    rw = *(const float4*)(W + (size_t)(bnW + lr) * ld + lc);
  }
  float acc[2][4] = {};
  for (int k0 = 0; k0 < K; k0 += 32) {
    As[lr][lc] = ra.x; As[lr][lc + 1] = ra.y;
    As[lr][lc + 2] = ra.z; As[lr][lc + 3] = ra.w;
    WsT[lc][lr] = rw.x; WsT[lc + 1][lr] = rw.y;
    WsT[lc + 2][lr] = rw.z; WsT[lc + 3][lr] = rw.w;
    __syncthreads();
    if (k0 + 32 < K) {
      ra = *(const float4*)(A + (size_t)(bm + lr) * ld + k0 + 32 + lc);
      if (A2) {
        float4 t = *(const float4*)(A2 + (size_t)(bm + lr) * ld + k0 + 32 + lc);
        ra.x += t.x; ra.y += t.y; ra.z += t.z; ra.w += t.w;
      }
      rw = *(const float4*)(W + (size_t)(bnW + lr) * ld + k0 + 32 + lc);
    }
#pragma unroll
    for (int k = 0; k < 32; ++k) {
      float a0 = As[ty][k], a1 = As[ty + 32][k];
      float4 w = *(const float4*)&WsT[k][tx * 4];
      acc[0][0] += a0 * w.x; acc[0][1] += a0 * w.y;
      acc[0][2] += a0 * w.z; acc[0][3] += a0 * w.w;
      acc[1][0] += a1 * w.x; acc[1][1] += a1 * w.y;
      acc[1][2] += a1 * w.z; acc[1][3] += a1 * w.w;
    }
    __syncthreads();
  }
#pragma unroll
  for (int i = 0; i < 2; ++i) {
    int m = bm + ty + i * 32;
#pragma unroll
    for (int j = 0; j < 4; ++j) {
      float v = acc[i][j];
      if (bias) v += bias[bnW + tx * 4 + j];
      v *= scale;
      if (do_relu) v = fmaxf(v, 0.f);
      if (trsh == 0) {
        C[(size_t)m * ldc + bnC + tx * 4 + j] = v;
      } else {
        const int nC = bnC + tx * 4 + j;
        const int bb = m >> trsh, kseq = m & ((1 << trsh) - 1);
        const int hh = nC >> 5, d = nC & 31;
        Ch[((((size_t)(bb * Hn + hh)) << trsh) + kseq) * 32 + d] =
            __float2half(v);
      }
    }
  }
}

// ---------------------------------------------------------------------------
// prep: fused build_cpb (1 block) + self QKV GEMM (96 blocks; K/V written
// head-major transposed fp16) + cross KV GEMM (256 blocks). 512 threads.
// ---------------------------------------------------------------------------
__global__ __launch_bounds__(512) void prep_kernel(
    float* __restrict__ qSb, __half* __restrict__ kSb, __half* __restrict__ vSb,
    __half* __restrict__ kCb, __half* __restrict__ vCb,
    const float* __restrict__ tgt, const float* __restrict__ qpos,
    const float* __restrict__ src, const float* __restrict__ spe,
    const float* __restrict__ ipw, const float* __restrict__ ipb,
    const float* __restrict__ kw, const float* __restrict__ kb,
    const float* __restrict__ vw, const float* __restrict__ vb,
    const float* __restrict__ w1p, const float* __restrict__ b1p,
    const float* __restrict__ w2p,
    float* __restrict__ tout, float* __restrict__ Stab, float* __restrict__ Btab)
{
  __shared__ float smem[4288];  // As 64*33=2112 + WsT 32*68=2176
  const int bx = blockIdx.x;
  const int tid = threadIdx.x;
  if (bx < 96) {
    float (*As)[33] = (float(*)[33])smem;
    float (*WsT)[68] = (float(*)[68])(smem + 2112);
    int my = bx & 7, nx = bx >> 3;
    int sec = nx >> 2;
    gemm64_body(qSb, sec == 1 ? kSb : vSb, Dn, tgt,
                sec < 2 ? qpos : nullptr, Dn, ipw, ipb,
                Dn, my * 64, (nx & 3) * 64, nx * 64,
                sec == 0 ? SCALEf : 1.f, 0, sec == 0 ? 0 : 8, As, WsT);
    return;
  }
  if (bx < 96 + 256) {
    float (*As)[33] = (float(*)[33])smem;
    float (*WsT)[68] = (float(*)[68])(smem + 2112);
    int idx = bx - 96;
    int my = idx & 31, nx = idx >> 5;
    int sec = nx >> 2;
    gemm64_body(nullptr, sec ? vCb : kCb, Dn, src, sec ? nullptr : spe, Dn,
                sec ? vw : kw, sec ? vb : kb,
                Dn, my * 64, (nx & 3) * 64, (nx & 3) * 64, 1.f, 0, 10, As, WsT);
    return;
  }
  // ---- cpb piecewise-linear table build (verified rounds 1-19) ----
  float* key = smem;
  int* pidx = (int*)(smem + 512);
  float* w1s = smem + 1024;
  float* b1s = smem + 1536;
  {
    float w = w1p[tid], bb = b1p[tid];
    key[tid] = (w != 0.f) ? (-bb / w) : 3.0e38f;
    pidx[tid] = tid;
  }
  __syncthreads();
  for (int k = 2; k <= RPEn; k <<= 1) {
    for (int j = k >> 1; j > 0; j >>= 1) {
      int ixj = tid ^ j;
      if (ixj > tid) {
        float a = key[tid], c = key[ixj];
        bool asc = ((tid & k) == 0);
        bool sw = asc ? (a > c) : (a < c);
        if (sw) {
          key[tid] = c; key[ixj] = a;
          int tmp = pidx[tid]; pidx[tid] = pidx[ixj]; pidx[ixj] = tmp;
        }
      }
      __syncthreads();
    }
  }
  w1s[tid] = w1p[pidx[tid]];
  b1s[tid] = b1p[pidx[tid]];
  tout[tid] = key[tid];
  __syncthreads();
  const int lane = tid & 63;
  const int h = tid >> 6;
  const int j0 = lane * 8;
  float sp[8], bp[8], sn[8], bn[8];
  float csp = 0.f, cbp = 0.f, csn = 0.f, cbn = 0.f, ccc = 0.f;
#pragma unroll
  for (int e = 0; e < 8; ++e) {
    int j = j0 + e;
    float w = w1s[j], b = b1s[j];
    float c = w2p[h * RPEn + pidx[j]];
    sp[e] = csp; bp[e] = cbp; sn[e] = csn; bn[e] = cbn;
    if (w > 0.f)      { csp += w * c; cbp += b * c; }
    else if (w < 0.f) { csn += w * c; cbn += b * c; }
    else              { ccc += fmaxf(b, 0.f) * c; }
  }
  float isp = csp, ibp = cbp, isn = csn, ibn = cbn, icc = ccc;
#pragma unroll
  for (int d = 1; d < 64; d <<= 1) {
    float t0 = __shfl_up(isp, d);
    float t1 = __shfl_up(ibp, d);
    float t2 = __shfl_up(isn, d);
    float t3 = __shfl_up(ibn, d);
    if (lane >= d) { isp += t0; ibp += t1; isn += t2; ibn += t3; }
    icc += __shfl_xor(icc, d);
  }
  const float tsn = __shfl(isn, 63);
  const float tbn = __shfl(ibn, 63);
  const float esp = isp - csp, ebp = ibp - cbp;
  const float esn = isn - csn, ebn = ibn - cbn;
#pragma unroll
  for (int e = 0; e < 8; ++e) {
    int j = j0 + e;
    Stab[j * Hn + h] = (esp + sp[e]) + (tsn - (esn + sn[e]));
    Btab[j * Hn + h] = (ebp + bp[e]) + (tbn - (ebn + bn[e])) + icc;
  }
  if (lane == 63) {
    Stab[RPEn * Hn + h] = isp;
    Btab[RPEn * Hn + h] = ibp + icc;
  }
}

// ---------------------------------------------------------------------------
// bias body: fp16 bias[b,h,q,k] = Sh[lo]*m + Bh[lo] - 100*pad. One block per
// (b,q); search once per (b,q,k), applied to 8 heads. LDS carved from smem.
// ---------------------------------------------------------------------------
__device__ __forceinline__ void bias_body(
    char* smemraw, int idx,
    __half* __restrict__ biasb, const float* __restrict__ rel,
    const float* __restrict__ pad, const float* __restrict__ tsg,
    const float* __restrict__ Stabg, const float* __restrict__ Btabg)
{
  float* ts = (float*)smemraw;                    // 512 f
  float* Sh = (float*)(smemraw + 2048);           // 4104 f
  float* Bh = (float*)(smemraw + 18464);          // 4104 f
  const int tid = threadIdx.x;
  const int b = idx >> 8, q = idx & 255;
  ts[tid] = tsg[tid];
  ts[tid + 256] = tsg[tid + 256];
  for (int i = tid; i < (RPEn + 1) * Hn; i += 256) {
    Sh[i] = Stabg[i];
    Bh[i] = Btabg[i];
  }
  __syncthreads();
#pragma unroll
  for (int j = 0; j < 4; ++j) {
    const int k = tid + j * 256;
    const float m = rel[((size_t)b * NQn + q) * NSn + k];
    const float padv = -100.f * pad[b * NSn + k];
    int lo = 0, hi = RPEn;
#pragma unroll
    for (int it = 0; it < 9; ++it) {
      int mid = (lo + hi) >> 1;
      if (ts[mid] < m) lo = mid + 1; else hi = mid;
    }
#pragma unroll
    for (int h = 0; h < Hn; ++h) {
      biasb[(((size_t)(b * Hn + h)) * NQn + q) * NSn + k] =
          __float2half(Sh[lo * Hn + h] * m + Bh[lo * Hn + h] + padv);
    }
  }
}

// ---------------------------------------------------------------------------
// Flash body, templated on CHUNK. R=2 rows/thread, HEAD-MAJOR FP16 K/V.
// Rotation swizzle o(k)=(k+(k>>2))&3 in ADDRESS arithmetic only.
// r19: QK via v_dot2_f32_f16 (packed fp16 q).
// r20: PV + rescale via packed fp16 math (v_pk_fma_f16 / v_pk_mul_f16) --
// O accumulated as h2f[2][16]; converted to f32 once before lane reduce.
// ---------------------------------------------------------------------------
template <int CHUNK>
__device__ __forceinline__ void flash_body(
    char* smemraw, int qb, int bh,
    float* __restrict__ O, const float* __restrict__ Q,
    const __half* __restrict__ kT, const __half* __restrict__ vT,
    const __half* __restrict__ biasb, int NK)
{
  constexpr int NJ = CHUNK / 64;        // keys per lane per chunk
  constexpr int NS = CHUNK / 64;        // stage iters
  float4 (*Ks)[CHUNK * 4] = (float4(*)[CHUNK * 4])smemraw;
  float4 (*Vs)[CHUNK * 4] = (float4(*)[CHUNK * 4])(smemraw + CHUNK * 128);
  float4* Qs = (float4*)(smemraw + CHUNK * 256);
  const int b = bh >> 3, h = bh & 7;
  const int q0 = qb * 8;
  const int tid = threadIdx.x;
  const int w = tid >> 6, kc = tid & 63;
  const float4* Ktp = (const float4*)kT + (size_t)bh * NK * 4;
  const float4* Vtp = (const float4*)vT + (size_t)bh * NK * 4;
  if (tid < 64)
    Qs[tid] = ((const float4*)Q)[(size_t)(b * NQn + q0 + (tid >> 3)) * 64 +
                                 h * 8 + (tid & 7)];

  const __half* brow0 =
      biasb ? biasb + ((size_t)bh * NQn + q0 + 2 * w) * NK : nullptr;
  const __half* brow1 = biasb ? brow0 + NK : nullptr;

  auto stage = [&](int buf, int kb0) {
#pragma unroll
    for (int u = 0; u < NS; ++u) {
      const int s = tid + u * 256;   // linear LDS slot (lane order)
      const int k = s >> 2, e = s & 3;
      const int ok = (k + (k >> 2)) & 3;
      const int g = (kb0 + k) * 4 + ((e - ok) & 3);
      GLDS16(Ktp + g, &Ks[buf][s]);
      GLDS16(Vtp + g, &Vs[buf][s]);
    }
  };

  stage(0, 0);
  float cb[2][NJ];
  if (biasb) {
#pragma unroll
    for (int j = 0; j < NJ; ++j) {
      cb[0][j] = __half2float(brow0[kc + j * 64]);
      cb[1][j] = __half2float(brow1[kc + j * 64]);
    }
  }
  __syncthreads();  // drains vmcnt: chunk 0 + Qs ready

  // q rows packed to fp16 pairs: qh[r][2*dd+p] covers elems {8dd+4p .. +3}/2
  h2f qh[2][16];
#pragma unroll
  for (int dd = 0; dd < 8; ++dd) {
    float4 v0 = Qs[(2 * w) * 8 + dd];
    float4 v1 = Qs[(2 * w + 1) * 8 + dd];
    h2f t;
    t.x = (_Float16)v0.x; t.y = (_Float16)v0.y; qh[0][2 * dd] = t;
    t.x = (_Float16)v0.z; t.y = (_Float16)v0.w; qh[0][2 * dd + 1] = t;
    t.x = (_Float16)v1.x; t.y = (_Float16)v1.y; qh[1][2 * dd] = t;
    t.x = (_Float16)v1.z; t.y = (_Float16)v1.w; qh[1][2 * dd + 1] = t;
  }
  // O accumulated in packed fp16 (r20): 16 h2f pairs per row = 32 elems
  h2f oh[2][16];
#pragma unroll
  for (int i = 0; i < 16; ++i) {
    oh[0][i] = (h2f)(_Float16)0;
    oh[1][i] = (h2f)(_Float16)0;
  }
  float m_run[2] = {-3.0e38f, -3.0e38f};
  float l_run[2] = {0.f, 0.f};
  const int nchunk = NK / CHUNK;
  const int ox = (kc + (kc >> 2)) & 3;  // row-rot key, invariant to j*64

  for (int c = 0; c < nchunk; ++c) {
    const int cur = c & 1;
    float nb[2][NJ];
    if (c + 1 < nchunk) {
      stage(cur ^ 1, (c + 1) * CHUNK);  // prefetch flies under compute
      if (biasb) {
#pragma unroll
        for (int j = 0; j < NJ; ++j) {
          nb[0][j] = __half2float(brow0[(c + 1) * CHUNK + kc + j * 64]);
          nb[1][j] = __half2float(brow1[(c + 1) * CHUNK + kc + j * 64]);
        }
      }
    }
    float s[2][NJ];
#pragma unroll
    for (int j = 0; j < NJ; ++j) {
      const int kbase = (kc + j * 64) * 4;
      float a0 = 0.f, a1 = 0.f;
#pragma unroll
      for (int u = 0; u < 4; ++u) {
        float4 raw = Ks[cur][kbase + ((u + ox) & 3)];  // = unit u of row k
        const h2f* kp = (const h2f*)&raw;
#if HAS_FDOT2
#pragma unroll
        for (int m2 = 0; m2 < 4; ++m2) {
          a0 = __builtin_amdgcn_fdot2(qh[0][4 * u + m2], kp[m2], a0, false);
          a1 = __builtin_amdgcn_fdot2(qh[1][4 * u + m2], kp[m2], a1, false);
        }
#else
#pragma unroll
        for (int m2 = 0; m2 < 4; ++m2) {
          const h2f kk = kp[m2];
          const h2f q0h = qh[0][4 * u + m2];
          const h2f q1h = qh[1][4 * u + m2];
          a0 += (float)q0h.x * (float)kk.x + (float)q0h.y * (float)kk.y;
          a1 += (float)q1h.x * (float)kk.x + (float)q1h.y * (float)kk.y;
        }
#endif
      }
      s[0][j] = a0;
      s[1][j] = a1;
      if (biasb) { s[0][j] += cb[0][j]; s[1][j] += cb[1][j]; }
    }
    float f[2];
#pragma unroll
    for (int r = 0; r < 2; ++r) {
      float cmax = s[r][0];
#pragma unroll
      for (int j = 1; j < NJ; ++j) cmax = fmaxf(cmax, s[r][j]);
#pragma unroll
      for (int off = 1; off < 64; off <<= 1)
        cmax = fmaxf(cmax, __shfl_xor(cmax, off));
      const float m_new = fmaxf(m_run[r], cmax);
      f[r] = __expf(m_run[r] - m_new);
      float ls = 0.f;
#pragma unroll
      for (int j = 0; j < NJ; ++j) {
        s[r][j] = __expf(s[r][j] - m_new);
        ls += s[r][j];
      }
#pragma unroll
      for (int off = 1; off < 64; off <<= 1) ls += __shfl_xor(ls, off);
      l_run[r] = l_run[r] * f[r] + ls;
      m_run[r] = m_new;
    }
    {
      h2f f0h, f1h;
      f0h.x = (_Float16)f[0]; f0h.y = f0h.x;
      f1h.x = (_Float16)f[1]; f1h.y = f1h.x;
#pragma unroll
      for (int i = 0; i < 16; ++i) {
        oh[0][i] *= f0h;   // v_pk_mul_f16
        oh[1][i] *= f1h;
      }
    }
#pragma unroll
    for (int j = 0; j < NJ; ++j) {
      const int kbase = (kc + j * 64) * 4;
      h2f p0h, p1h;
      p0h.x = (_Float16)s[0][j]; p0h.y = p0h.x;
      p1h.x = (_Float16)s[1][j]; p1h.y = p1h.x;
#pragma unroll
      for (int u = 0; u < 4; ++u) {
        float4 raw = Vs[cur][kbase + ((u + ox) & 3)];  // = unit u of row k
        const h2f* vp = (const h2f*)&raw;
#pragma unroll
        for (int m2 = 0; m2 < 4; ++m2) {
          oh[0][4 * u + m2] += p0h * vp[m2];   // v_pk_fma_f16
          oh[1][4 * u + m2] += p1h * vp[m2];
        }
      }
    }
    if (biasb && c + 1 < nchunk) {
#pragma unroll
      for (int j = 0; j < NJ; ++j) {
        cb[0][j] = nb[0][j];
        cb[1][j] = nb[1][j];
      }
    }
    __syncthreads();  // drains prefetch vmcnt + LDS reads before buffer reuse
  }
  // convert fp16 accumulators to f32 once, then cross-lane reduce
  float4 o[2][8];
#pragma unroll
  for (int dd = 0; dd < 8; ++dd) {
#pragma unroll
    for (int r = 0; r < 2; ++r) {
      o[r][dd].x = (float)oh[r][2 * dd].x;
      o[r][dd].y = (float)oh[r][2 * dd].y;
      o[r][dd].z = (float)oh[r][2 * dd + 1].x;
      o[r][dd].w = (float)oh[r][2 * dd + 1].y;
    }
  }
#pragma unroll
  for (int off = 1; off < 64; off <<= 1) {
#pragma unroll
    for (int dd = 0; dd < 8; ++dd) {
      o[0][dd].x += __shfl_xor(o[0][dd].x, off);
      o[0][dd].y += __shfl_xor(o[0][dd].y, off);
      o[0][dd].z += __shfl_xor(o[0][dd].z, off);
      o[0][dd].w += __shfl_xor(o[0][dd].w, off);
      o[1][dd].x += __shfl_xor(o[1][dd].x, off);
      o[1][dd].y += __shfl_xor(o[1][dd].y, off);
      o[1][dd].z += __shfl_xor(o[1][dd].z, off);
      o[1][dd].w += __shfl_xor(o[1][dd].w, off);
    }
  }
  if (kc == 0) {
    const float inv = 1.f / l_run[0];
#pragma unroll
    for (int dd = 0; dd < 8; ++dd) {
      float4 v = o[0][dd];
      v.x *= inv; v.y *= inv; v.z *= inv; v.w *= inv;
      ((float4*)O)[(size_t)(b * NQn + q0 + 2 * w) * 64 + h * 8 + dd] = v;
    }
  } else if (kc == 1) {
    const float inv = 1.f / l_run[1];
#pragma unroll
    for (int dd = 0; dd < 8; ++dd) {
      float4 v = o[1][dd];
      v.x *= inv; v.y *= inv; v.z *= inv; v.w *= inv;
      ((float4*)O)[(size_t)(b * NQn + q0 + 2 * w + 1) * 64 + h * 8 + dd] = v;
    }
  }
}

// ---------------------------------------------------------------------------
// fsb: fused flash-self (blocks 0..511, CHUNK=128) + bias materialization
// (512..1023). Independent work; bias's memory-bound work overlaps flash.
// ---------------------------------------------------------------------------
__global__ __launch_bounds__(256, 2) void fsb_kernel(
    float* __restrict__ O, const float* __restrict__ Q,
    const __half* __restrict__ kT, const __half* __restrict__ vT,
    __half* __restrict__ biasb, const float* __restrict__ rel,
    const float* __restrict__ pad, const float* __restrict__ tsg,
    const float* __restrict__ Stabg, const float* __restrict__ Btabg)
{
  __shared__ __align__(16) char smem[34880];
  const int bx = blockIdx.x;
  if (bx < 512) {
    flash_body<128>(smem, bx & 31, bx >> 5, O, Q, kT, vT, nullptr, NQn);
  } else {
    bias_body(smem, bx - 512, biasb, rel, pad, tsg, Stabg, Btabg);
  }
}

// ---------------------------------------------------------------------------
// flash standalone (cross, CHUNK=256): grid (NQ/8, B*H), 256 threads.
// 66.5 KB LDS -> 2 blocks/CU, 512 blocks in one round; 4 chunks of 256 keys.
// ---------------------------------------------------------------------------
__global__ __launch_bounds__(256, 2) void flash_kernel(
    float* __restrict__ O, const float* __restrict__ Q,
    const __half* __restrict__ kT, const __half* __restrict__ vT,
    const __half* __restrict__ biasb, int NK)
{
  __shared__ __align__(16) char smem[66560];
  flash_body<256>(smem, blockIdx.x, blockIdx.y, O, Q, kT, vT, biasb, NK);
}

// ---------------------------------------------------------------------------
// gemm32: 32x32 tile, 256 threads, 2x2/thread, K-step 32, float4 staging with
// register prefetch. Split-K via blockIdx.z (partials at kz*M*N). relu opt.
// ---------------------------------------------------------------------------
__global__ __launch_bounds__(256) void gemm32_kernel(
    float* __restrict__ C, const float* __restrict__ A, const float* __restrict__ A2,
    const float* __restrict__ W, const float* __restrict__ bias,
    int N, int Kchunk, int Ktot, float scale, int do_relu)
{
  __shared__ float As[32][33];
  __shared__ float Ws[32][33];
  const int bm = blockIdx.y * 32, bn = blockIdx.x * 32;
  const int kz = blockIdx.z;
  const int M = gridDim.y * 32;
  float* Cp = C + (size_t)kz * M * N;
  const int tid = threadIdx.x;
  const int tx = tid & 15, ty = tid >> 4;
  const int lr = tid >> 3, lc = (tid & 7) * 4;
  float acc[2][2] = {};
  const int k00 = kz * Kchunk;
  float4 av, wv;
  {
    av = *(const float4*)(A + (size_t)(bm + lr) * Ktot + k00 + lc);
    if (A2) {
      float4 bv = *(const float4*)(A2 + (size_t)(bm + lr) * Ktot + k00 + lc);
      av.x += bv.x; av.y += bv.y; av.z += bv.z; av.w += bv.w;
    }
    wv = *(const float4*)(W + (size_t)(bn + lr) * Ktot + k00 + lc);
  }
  for (int k0 = k00; k0 < k00 + Kchunk; k0 += 32) {
    As[lr][lc] = av.x; As[lr][lc + 1] = av.y; As[lr][lc + 2] = av.z; As[lr][lc + 3] = av.w;
    Ws[lr][lc] = wv.x; Ws[lr][lc + 1] = wv.y; Ws[lr][lc + 2] = wv.z; Ws[lr][lc + 3] = wv.w;
    __syncthreads();
    if (k0 + 32 < k00 + Kchunk) {
      av = *(const float4*)(A + (size_t)(bm + lr) * Ktot + k0 + 32 + lc);
      if (A2) {
        float4 bv = *(const float4*)(A2 + (size_t)(bm + lr) * Ktot + k0 + 32 + lc);
        av.x += bv.x; av.y += bv.y; av.z += bv.z; av.w += bv.w;
      }
      wv = *(const float4*)(W + (size_t)(bn + lr) * Ktot + k0 + 32 + lc);
    }
#pragma unroll
    for (int k = 0; k < 32; ++k) {
      float a0 = As[ty * 2][k], a1 = As[ty * 2 + 1][k];
      float w0 = Ws[tx * 2][k], w1 = Ws[tx * 2 + 1][k];
      acc[0][0] += a0 * w0; acc[0][1] += a0 * w1;
      acc[1][0] += a1 * w0; acc[1][1] += a1 * w1;
    }
    __syncthreads();
  }
#pragma unroll
  for (int i = 0; i < 2; ++i) {
    int m = bm + ty * 2 + i;
#pragma unroll
    for (int j = 0; j < 2; ++j) {
      int n = bn + tx * 2 + j;
      float v = acc[i][j];
      if (bias) v += bias[n];
      v *= scale;
      if (do_relu) v = fmaxf(v, 0.f);
      Cp[(size_t)m * N + n] = v;
    }
  }
}

// ---------------------------------------------------------------------------
// out = LayerNorm(resid + sum_{s<nsplit} part[s] + bias) * g + b.
// Generalized split-K reducer + residual + LN. grid: rows, block = 256 = D.
// ---------------------------------------------------------------------------
__global__ __launch_bounds__(256) void reduce_ln_kernel(
    float* __restrict__ out, const float* __restrict__ part,
    const float* __restrict__ bias, const float* __restrict__ resid,
    const float* __restrict__ g, const float* __restrict__ bt, int nsplit)
{
  const int row = blockIdx.x;
  const int t = threadIdx.x;
  const size_t idx = (size_t)row * Dn + t;
  const size_t STR = (size_t)Bb * NQn * Dn;
  float v = bias[t] + resid[idx];
  for (int s = 0; s < nsplit; ++s) v += part[idx + (size_t)s * STR];
  float sm = v, s2 = v * v;
#pragma unroll
  for (int off = 32; off > 0; off >>= 1) {
    sm += __shfl_down(sm, off);
    s2 += __shfl_down(s2, off);
  }
  __shared__ float rs[4], rs2[4], fin[2];
  const int lane = t & 63, wid = t >> 6;
  if (lane == 0) { rs[wid] = sm; rs2[wid] = s2; }
  __syncthreads();
  if (t == 0) {
    float a = rs[0] + rs[1] + rs[2] + rs[3];
    float a2 = rs2[0] + rs2[1] + rs2[2] + rs2[3];
    float mean = a * (1.f / Dn);
    float var = a2 * (1.f / Dn) - mean * mean;
    fin[0] = mean;
    fin[1] = rsqrtf(var + EPSf);
  }
  __syncthreads();
  out[idx] = (v - fin[0]) * fin[1] * g[t] + bt[t];
}

extern "C" void kernel_launch(void* const* d_in, const int* in_sizes, int n_in,
                              void* d_out, int out_size, void* d_ws, size_t ws_size,
                              hipStream_t stream)
{
  const float* tgt   = (const float*)d_in[0];
  const float* qpos  = (const float*)d_in[1];
  const float* src   = (const float*)d_in[2];
  const float* spe   = (const float*)d_in[3];
  const float* pad   = (const float*)d_in[4];
  const float* rel   = (const float*)d_in[5];
  const float* qw    = (const float*)d_in[6];
  const float* qb    = (const float*)d_in[7];
  const float* kw    = (const float*)d_in[8];
  const float* kb    = (const float*)d_in[9];
  const float* vw    = (const float*)d_in[10];
  const float* vb    = (const float*)d_in[11];
  const float* projw = (const float*)d_in[12];
  const float* projb = (const float*)d_in[13];
  const float* cpbw1 = (const float*)d_in[14];
  const float* cpbb1 = (const float*)d_in[15];
  const float* cpbw2 = (const float*)d_in[16];
  const float* ipw   = (const float*)d_in[17];
  const float* ipb   = (const float*)d_in[18];
  const float* outw  = (const float*)d_in[19];
  const float* outb  = (const float*)d_in[20];
  const float* ln1g  = (const float*)d_in[21];
  const float* ln1b  = (const float*)d_in[22];
  const float* ln2g  = (const float*)d_in[23];
  const float* ln2b  = (const float*)d_in[24];
  const float* ln3g  = (const float*)d_in[25];
  const float* ln3b  = (const float*)d_in[26];
  const float* ff1w  = (const float*)d_in[27];
  const float* ff1b  = (const float*)d_in[28];
  const float* ff2w  = (const float*)d_in[29];
  const float* ff2b  = (const float*)d_in[30];
  float* out = (float*)d_out;
  float* ws = (float*)d_ws;

  constexpr size_t SZ_Q   = (size_t)Bb * NQn * Dn;   // 131072
  constexpr size_t SZ_S   = (size_t)Bb * NSn * Dn;   // 524288
  constexpr size_t SZ_FFH = (size_t)Bb * NQn * FFNn; // 524288

  float* qSb  = ws;
  __half* kSb = (__half*)(qSb + SZ_Q);   // head-major fp16 kT (self)
  __half* vSb = (__half*)(qSb + 2 * SZ_Q);
  float* oSb  = ws + 3 * SZ_Q;
  float* soP  = oSb + SZ_Q;              // (layout stability)
  float* tgt2 = soP + SZ_Q;
  float* qCb  = tgt2 + SZ_Q;
  __half* kCb = (__half*)(qCb + SZ_Q);   // head-major fp16 kT (cross)
  __half* vCb = (__half*)(qCb + SZ_Q + SZ_S);
  float* oCb  = qCb + SZ_Q + 2 * SZ_S;
  float* coP  = oCb + SZ_Q;              // (layout stability)
  float* tgt3 = coP + SZ_Q;
  float* ffh  = tgt3 + SZ_Q;
  float* part = ffh + SZ_FFH;            // 4 * SZ_Q partials scratch
  float* tsb  = part + 4 * SZ_Q;
  float* Stab = tsb + RPEn;
  float* Btab = Stab + (RPEn + 1) * Hn;
  __half* biasb = (__half*)(Btab + (RPEn + 1) * Hn);

  const int MQ = Bb * NQn;  // 512

  // 1. prep: cpb tables + self QKV + cross KV (K/V transposed fp16 head-major)
  prep_kernel<<<dim3(96 + 256 + 1), dim3(512), 0, stream>>>(
      qSb, kSb, vSb, kCb, vCb, tgt, qpos, src, spe, ipw, ipb,
      kw, kb, vw, vb, cpbw1, cpbb1, cpbw2, tsb, Stab, Btab);

  // 2. fused: flash self (512 blocks) + fp16 bias materialization (512 blocks)
  fsb_kernel<<<dim3(1024), dim3(256), 0, stream>>>(
      oSb, qSb, kSb, vSb, biasb, rel, pad, tsb, Stab, Btab);

  // 3. self out-proj, split-K x2 -> partials (bias deferred to reducer)
  gemm32_kernel<<<dim3(Dn / 32, MQ / 32, 2), dim3(256), 0, stream>>>(
      part, oSb, nullptr, outw, nullptr, Dn, 128, Dn, 1.f, 0);

  // 4. tgt2 = LN2(tgt + sum(part) + outb)
  reduce_ln_kernel<<<dim3(MQ), dim3(256), 0, stream>>>(
      tgt2, part, outb, tgt, ln2g, ln2b, 2);

  // 5. cross q
  gemm32_kernel<<<dim3(Dn / 32, MQ / 32, 1), dim3(256), 0, stream>>>(
      qCb, tgt2, qpos, qw, qb, Dn, Dn, Dn, SCALEf, 0);

  // 6. cross attention (CHUNK=256 flash, fp16 K/V + fp16 staged bias)
  flash_kernel<<<dim3(NQn / 8, Bb * Hn), dim3(256), 0, stream>>>(
      oCb, qCb, kCb, vCb, biasb, NSn);

  // 7. cross out-proj, split-K x2 -> partials
  gemm32_kernel<<<dim3(Dn / 32, MQ / 32, 2), dim3(256), 0, stream>>>(
      part, oCb, nullptr, projw, nullptr, Dn, 128, Dn, 1.f, 0);

  // 8. tgt3 = LN1(tgt2 + sum(part) + projb)
  reduce_ln_kernel<<<dim3(MQ), dim3(256), 0, stream>>>(
      tgt3, part, projb, tgt2, ln1g, ln1b, 2);

  // 9. FFN1 (relu) as gemm32: 512 blocks (full GPU)
  gemm32_kernel<<<dim3(FFNn / 32, MQ / 32, 1), dim3(256), 0, stream>>>(
      ffh, tgt3, nullptr, ff1w, ff1b, FFNn, Dn, Dn, 1.f, 1);

  // 10. FFN2 split-K x4 -> partials
  gemm32_kernel<<<dim3(Dn / 32, MQ / 32, 4), dim3(256), 0, stream>>>(
      part, ffh, nullptr, ff2w, nullptr, Dn, 256, FFNn, 1.f, 0);

  // 11. out = LN3(tgt3 + sum(part) + ff2b)
  reduce_ln_kernel<<<dim3(MQ), dim3(256), 0, stream>>>(
      out, part, ff2b, tgt3, ln3g, ln3b, 4);
}

// Round 21
// 115.594 us; speedup vs baseline: 1.1003x; 1.0269x over previous
//
#include <hip/hip_runtime.h>
#include <hip/hip_bf16.h>
#include <hip/hip_fp16.h>
#include <math.h>

#define Bb 2
#define NQn 256
#define NSn 1024
#define Dn 256
#define Hn 8
#define DHn 32
#define FFNn 1024
#define RPEn 512
#define SCALEf 0.17677669529663687f
#define EPSf 1e-5f

#if defined(__has_builtin)
#if __has_builtin(__builtin_amdgcn_fdot2)
#define HAS_FDOT2 1
#endif
#endif
#ifndef HAS_FDOT2
#define HAS_FDOT2 0
#endif

typedef _Float16 h2f __attribute__((ext_vector_type(2)));

// async global->LDS, 16B per lane. LDS dest must be linear in lane order
// (wave-uniform base + lane*16); global src is per-lane (pre-swizzled).
#define GLDS16(g, l)                                                         \
  __builtin_amdgcn_global_load_lds(                                          \
      (const __attribute__((address_space(1))) void*)(const void*)(g),       \
      (__attribute__((address_space(3))) void*)(void*)(l), 16, 0, 0)

__device__ __forceinline__ float fdot2e(h2f a, h2f b, float c) {
#if HAS_FDOT2
  return __builtin_amdgcn_fdot2(a, b, c, false);
#else
  return c + (float)a.x * (float)b.x + (float)a.y * (float)b.y;
#endif
}

// ---------------------------------------------------------------------------
// gemm64h body (r21): 64x64 tile, 512 threads, K-step 32, float4 loads with
// reg prefetch; A and W staged as PACKED FP16 (h2f) via cvt_pkrtz; inner
// loop = 16 k-pairs x 8 v_dot2_f32_f16 with f32 accumulation. Halves VALU
// and LDS traffic vs the f32 body. Epilogue identical (f32 acc + bias +
// scale + relu; trsh != 0 writes transposed head-major FP16).
// LDS: Ah[64][17] h2f (4352B) + WhT[16][68] h2f (4352B) carved from smem.
// ---------------------------------------------------------------------------
__device__ __forceinline__ void gemm64h_body(
    float* __restrict__ C, __half* __restrict__ Ch, int ldc,
    const float* __restrict__ A, const float* __restrict__ A2, int ld,
    const float* __restrict__ W, const float* __restrict__ bias,
    int K, int bm, int bnC, int bnW, float scale, int do_relu, int trsh,
    float* smem)
{
  h2f (*Ah)[17] = (h2f(*)[17])smem;            // [row][kpair]
  h2f (*WhT)[68] = (h2f(*)[68])(smem + 1088);  // [kpair][col]
  const int tid = threadIdx.x;
  const int tx = tid & 15, ty = tid >> 4;       // ty 0..31
  const int lr = tid >> 3, lc = (tid & 7) * 4;  // staging: row, k-offset
  const int lp = lc >> 1;                       // k-pair index
  float4 ra, rw;
  {
    ra = *(const float4*)(A + (size_t)(bm + lr) * ld + lc);
    if (A2) {
      float4 t = *(const float4*)(A2 + (size_t)(bm + lr) * ld + lc);
      ra.x += t.x; ra.y += t.y; ra.z += t.z; ra.w += t.w;
    }
    rw = *(const float4*)(W + (size_t)(bnW + lr) * ld + lc);
  }
  float acc[2][4] = {};
  for (int k0 = 0; k0 < K; k0 += 32) {
    {
      h2f a01, a23, w01, w23;
      a01.x = (_Float16)ra.x; a01.y = (_Float16)ra.y;
      a23.x = (_Float16)ra.z; a23.y = (_Float16)ra.w;
      w01.x = (_Float16)rw.x; w01.y = (_Float16)rw.y;
      w23.x = (_Float16)rw.z; w23.y = (_Float16)rw.w;
      Ah[lr][lp] = a01; Ah[lr][lp + 1] = a23;
      WhT[lp][lr] = w01; WhT[lp + 1][lr] = w23;
    }
    __syncthreads();
    if (k0 + 32 < K) {
      ra = *(const float4*)(A + (size_t)(bm + lr) * ld + k0 + 32 + lc);
      if (A2) {
        float4 t = *(const float4*)(A2 + (size_t)(bm + lr) * ld + k0 + 32 + lc);
        ra.x += t.x; ra.y += t.y; ra.z += t.z; ra.w += t.w;
      }
      rw = *(const float4*)(W + (size_t)(bnW + lr) * ld + k0 + 32 + lc);
    }
#pragma unroll
    for (int kp = 0; kp < 16; ++kp) {
      h2f a0 = Ah[ty][kp], a1 = Ah[ty + 32][kp];
      float4 wr = *(const float4*)&WhT[kp][tx * 4];
      const h2f* wp = (const h2f*)&wr;
      acc[0][0] = fdot2e(a0, wp[0], acc[0][0]);
      acc[0][1] = fdot2e(a0, wp[1], acc[0][1]);
      acc[0][2] = fdot2e(a0, wp[2], acc[0][2]);
      acc[0][3] = fdot2e(a0, wp[3], acc[0][3]);
      acc[1][0] = fdot2e(a1, wp[0], acc[1][0]);
      acc[1][1] = fdot2e(a1, wp[1], acc[1][1]);
      acc[1][2] = fdot2e(a1, wp[2], acc[1][2]);
      acc[1][3] = fdot2e(a1, wp[3], acc[1][3]);
    }
    __syncthreads();
  }
#pragma unroll
  for (int i = 0; i < 2; ++i) {
    int m = bm + ty + i * 32;
#pragma unroll
    for (int j = 0; j < 4; ++j) {
      float v = acc[i][j];
      if (bias) v += bias[bnW + tx * 4 + j];
      v *= scale;
      if (do_relu) v = fmaxf(v, 0.f);
      if (trsh == 0) {
        C[(size_t)m * ldc + bnC + tx * 4 + j] = v;
      } else {
        const int nC = bnC + tx * 4 + j;
        const int bb = m >> trsh, kseq = m & ((1 << trsh) - 1);
        const int hh = nC >> 5, d = nC & 31;
        Ch[((((size_t)(bb * Hn + hh)) << trsh) + kseq) * 32 + d] =
            __float2half(v);
      }
    }
  }
}

// ---------------------------------------------------------------------------
// prep: fused build_cpb (1 block) + self QKV GEMM (96 blocks; K/V written
// head-major transposed fp16) + cross KV GEMM (256 blocks). 512 threads.
// GEMMs use the fp16/fdot2 body (r21).
// ---------------------------------------------------------------------------
__global__ __launch_bounds__(512) void prep_kernel(
    float* __restrict__ qSb, __half* __restrict__ kSb, __half* __restrict__ vSb,
    __half* __restrict__ kCb, __half* __restrict__ vCb,
    const float* __restrict__ tgt, const float* __restrict__ qpos,
    const float* __restrict__ src, const float* __restrict__ spe,
    const float* __restrict__ ipw, const float* __restrict__ ipb,
    const float* __restrict__ kw, const float* __restrict__ kb,
    const float* __restrict__ vw, const float* __restrict__ vb,
    const float* __restrict__ w1p, const float* __restrict__ b1p,
    const float* __restrict__ w2p,
    float* __restrict__ tout, float* __restrict__ Stab, float* __restrict__ Btab)
{
  __shared__ float smem[4288];
  const int bx = blockIdx.x;
  const int tid = threadIdx.x;
  if (bx < 96) {
    int my = bx & 7, nx = bx >> 3;
    int sec = nx >> 2;
    gemm64h_body(qSb, sec == 1 ? kSb : vSb, Dn, tgt,
                 sec < 2 ? qpos : nullptr, Dn, ipw, ipb,
                 Dn, my * 64, (nx & 3) * 64, nx * 64,
                 sec == 0 ? SCALEf : 1.f, 0, sec == 0 ? 0 : 8, smem);
    return;
  }
  if (bx < 96 + 256) {
    int idx = bx - 96;
    int my = idx & 31, nx = idx >> 5;
    int sec = nx >> 2;
    gemm64h_body(nullptr, sec ? vCb : kCb, Dn, src, sec ? nullptr : spe, Dn,
                 sec ? vw : kw, sec ? vb : kb,
                 Dn, my * 64, (nx & 3) * 64, (nx & 3) * 64, 1.f, 0, 10, smem);
    return;
  }
  // ---- cpb piecewise-linear table build (verified rounds 1-20) ----
  float* key = smem;
  int* pidx = (int*)(smem + 512);
  float* w1s = smem + 1024;
  float* b1s = smem + 1536;
  {
    float w = w1p[tid], bb = b1p[tid];
    key[tid] = (w != 0.f) ? (-bb / w) : 3.0e38f;
    pidx[tid] = tid;
  }
  __syncthreads();
  for (int k = 2; k <= RPEn; k <<= 1) {
    for (int j = k >> 1; j > 0; j >>= 1) {
      int ixj = tid ^ j;
      if (ixj > tid) {
        float a = key[tid], c = key[ixj];
        bool asc = ((tid & k) == 0);
        bool sw = asc ? (a > c) : (a < c);
        if (sw) {
          key[tid] = c; key[ixj] = a;
          int tmp = pidx[tid]; pidx[tid] = pidx[ixj]; pidx[ixj] = tmp;
        }
      }
      __syncthreads();
    }
  }
  w1s[tid] = w1p[pidx[tid]];
  b1s[tid] = b1p[pidx[tid]];
  tout[tid] = key[tid];
  __syncthreads();
  const int lane = tid & 63;
  const int h = tid >> 6;
  const int j0 = lane * 8;
  float sp[8], bp[8], sn[8], bn[8];
  float csp = 0.f, cbp = 0.f, csn = 0.f, cbn = 0.f, ccc = 0.f;
#pragma unroll
  for (int e = 0; e < 8; ++e) {
    int j = j0 + e;
    float w = w1s[j], b = b1s[j];
    float c = w2p[h * RPEn + pidx[j]];
    sp[e] = csp; bp[e] = cbp; sn[e] = csn; bn[e] = cbn;
    if (w > 0.f)      { csp += w * c; cbp += b * c; }
    else if (w < 0.f) { csn += w * c; cbn += b * c; }
    else              { ccc += fmaxf(b, 0.f) * c; }
  }
  float isp = csp, ibp = cbp, isn = csn, ibn = cbn, icc = ccc;
#pragma unroll
  for (int d = 1; d < 64; d <<= 1) {
    float t0 = __shfl_up(isp, d);
    float t1 = __shfl_up(ibp, d);
    float t2 = __shfl_up(isn, d);
    float t3 = __shfl_up(ibn, d);
    if (lane >= d) { isp += t0; ibp += t1; isn += t2; ibn += t3; }
    icc += __shfl_xor(icc, d);
  }
  const float tsn = __shfl(isn, 63);
  const float tbn = __shfl(ibn, 63);
  const float esp = isp - csp, ebp = ibp - cbp;
  const float esn = isn - csn, ebn = ibn - cbn;
#pragma unroll
  for (int e = 0; e < 8; ++e) {
    int j = j0 + e;
    Stab[j * Hn + h] = (esp + sp[e]) + (tsn - (esn + sn[e]));
    Btab[j * Hn + h] = (ebp + bp[e]) + (tbn - (ebn + bn[e])) + icc;
  }
  if (lane == 63) {
    Stab[RPEn * Hn + h] = isp;
    Btab[RPEn * Hn + h] = ibp + icc;
  }
}

// ---------------------------------------------------------------------------
// bias body: fp16 bias[b,h,q,k] = Sh[lo]*m + Bh[lo] - 100*pad. One block per
// (b,q); search once per (b,q,k), applied to 8 heads. LDS carved from smem.
// ---------------------------------------------------------------------------
__device__ __forceinline__ void bias_body(
    char* smemraw, int idx,
    __half* __restrict__ biasb, const float* __restrict__ rel,
    const float* __restrict__ pad, const float* __restrict__ tsg,
    const float* __restrict__ Stabg, const float* __restrict__ Btabg)
{
  float* ts = (float*)smemraw;                    // 512 f
  float* Sh = (float*)(smemraw + 2048);           // 4104 f
  float* Bh = (float*)(smemraw + 18464);          // 4104 f
  const int tid = threadIdx.x;
  const int b = idx >> 8, q = idx & 255;
  ts[tid] = tsg[tid];
  ts[tid + 256] = tsg[tid + 256];
  for (int i = tid; i < (RPEn + 1) * Hn; i += 256) {
    Sh[i] = Stabg[i];
    Bh[i] = Btabg[i];
  }
  __syncthreads();
#pragma unroll
  for (int j = 0; j < 4; ++j) {
    const int k = tid + j * 256;
    const float m = rel[((size_t)b * NQn + q) * NSn + k];
    const float padv = -100.f * pad[b * NSn + k];
    int lo = 0, hi = RPEn;
#pragma unroll
    for (int it = 0; it < 9; ++it) {
      int mid = (lo + hi) >> 1;
      if (ts[mid] < m) lo = mid + 1; else hi = mid;
    }
#pragma unroll
    for (int h = 0; h < Hn; ++h) {
      biasb[(((size_t)(b * Hn + h)) * NQn + q) * NSn + k] =
          __float2half(Sh[lo * Hn + h] * m + Bh[lo * Hn + h] + padv);
    }
  }
}

// ---------------------------------------------------------------------------
// Flash body, templated on CHUNK. R=2 rows/thread, HEAD-MAJOR FP16 K/V.
// Rotation swizzle o(k)=(k+(k>>2))&3 in ADDRESS arithmetic only.
// r19: QK via v_dot2_f32_f16 (packed fp16 q).
// r20: PV + rescale via packed fp16 math (v_pk_fma_f16 / v_pk_mul_f16).
// ---------------------------------------------------------------------------
template <int CHUNK>
__device__ __forceinline__ void flash_body(
    char* smemraw, int qb, int bh,
    float* __restrict__ O, const float* __restrict__ Q,
    const __half* __restrict__ kT, const __half* __restrict__ vT,
    const __half* __restrict__ biasb, int NK)
{
  constexpr int NJ = CHUNK / 64;        // keys per lane per chunk
  constexpr int NS = CHUNK / 64;        // stage iters
  float4 (*Ks)[CHUNK * 4] = (float4(*)[CHUNK * 4])smemraw;
  float4 (*Vs)[CHUNK * 4] = (float4(*)[CHUNK * 4])(smemraw + CHUNK * 128);
  float4* Qs = (float4*)(smemraw + CHUNK * 256);
  const int b = bh >> 3, h = bh & 7;
  const int q0 = qb * 8;
  const int tid = threadIdx.x;
  const int w = tid >> 6, kc = tid & 63;
  const float4* Ktp = (const float4*)kT + (size_t)bh * NK * 4;
  const float4* Vtp = (const float4*)vT + (size_t)bh * NK * 4;
  if (tid < 64)
    Qs[tid] = ((const float4*)Q)[(size_t)(b * NQn + q0 + (tid >> 3)) * 64 +
                                 h * 8 + (tid & 7)];

  const __half* brow0 =
      biasb ? biasb + ((size_t)bh * NQn + q0 + 2 * w) * NK : nullptr;
  const __half* brow1 = biasb ? brow0 + NK : nullptr;

  auto stage = [&](int buf, int kb0) {
#pragma unroll
    for (int u = 0; u < NS; ++u) {
      const int s = tid + u * 256;   // linear LDS slot (lane order)
      const int k = s >> 2, e = s & 3;
      const int ok = (k + (k >> 2)) & 3;
      const int g = (kb0 + k) * 4 + ((e - ok) & 3);
      GLDS16(Ktp + g, &Ks[buf][s]);
      GLDS16(Vtp + g, &Vs[buf][s]);
    }
  };

  stage(0, 0);
  float cb[2][NJ];
  if (biasb) {
#pragma unroll
    for (int j = 0; j < NJ; ++j) {
      cb[0][j] = __half2float(brow0[kc + j * 64]);
      cb[1][j] = __half2float(brow1[kc + j * 64]);
    }
  }
  __syncthreads();  // drains vmcnt: chunk 0 + Qs ready

  // q rows packed to fp16 pairs
  h2f qh[2][16];
#pragma unroll
  for (int dd = 0; dd < 8; ++dd) {
    float4 v0 = Qs[(2 * w) * 8 + dd];
    float4 v1 = Qs[(2 * w + 1) * 8 + dd];
    h2f t;
    t.x = (_Float16)v0.x; t.y = (_Float16)v0.y; qh[0][2 * dd] = t;
    t.x = (_Float16)v0.z; t.y = (_Float16)v0.w; qh[0][2 * dd + 1] = t;
    t.x = (_Float16)v1.x; t.y = (_Float16)v1.y; qh[1][2 * dd] = t;
    t.x = (_Float16)v1.z; t.y = (_Float16)v1.w; qh[1][2 * dd + 1] = t;
  }
  // O accumulated in packed fp16: 16 h2f pairs per row = 32 elems
  h2f oh[2][16];
#pragma unroll
  for (int i = 0; i < 16; ++i) {
    oh[0][i] = (h2f)(_Float16)0;
    oh[1][i] = (h2f)(_Float16)0;
  }
  float m_run[2] = {-3.0e38f, -3.0e38f};
  float l_run[2] = {0.f, 0.f};
  const int nchunk = NK / CHUNK;
  const int ox = (kc + (kc >> 2)) & 3;  // row-rot key, invariant to j*64

  for (int c = 0; c < nchunk; ++c) {
    const int cur = c & 1;
    float nb[2][NJ];
    if (c + 1 < nchunk) {
      stage(cur ^ 1, (c + 1) * CHUNK);  // prefetch flies under compute
      if (biasb) {
#pragma unroll
        for (int j = 0; j < NJ; ++j) {
          nb[0][j] = __half2float(brow0[(c + 1) * CHUNK + kc + j * 64]);
          nb[1][j] = __half2float(brow1[(c + 1) * CHUNK + kc + j * 64]);
        }
      }
    }
    float s[2][NJ];
#pragma unroll
    for (int j = 0; j < NJ; ++j) {
      const int kbase = (kc + j * 64) * 4;
      float a0 = 0.f, a1 = 0.f;
#pragma unroll
      for (int u = 0; u < 4; ++u) {
        float4 raw = Ks[cur][kbase + ((u + ox) & 3)];  // = unit u of row k
        const h2f* kp = (const h2f*)&raw;
#pragma unroll
        for (int m2 = 0; m2 < 4; ++m2) {
          a0 = fdot2e(qh[0][4 * u + m2], kp[m2], a0);
          a1 = fdot2e(qh[1][4 * u + m2], kp[m2], a1);
        }
      }
      s[0][j] = a0;
      s[1][j] = a1;
      if (biasb) { s[0][j] += cb[0][j]; s[1][j] += cb[1][j]; }
    }
    float f[2];
#pragma unroll
    for (int r = 0; r < 2; ++r) {
      float cmax = s[r][0];
#pragma unroll
      for (int j = 1; j < NJ; ++j) cmax = fmaxf(cmax, s[r][j]);
#pragma unroll
      for (int off = 1; off < 64; off <<= 1)
        cmax = fmaxf(cmax, __shfl_xor(cmax, off));
      const float m_new = fmaxf(m_run[r], cmax);
      f[r] = __expf(m_run[r] - m_new);
      float ls = 0.f;
#pragma unroll
      for (int j = 0; j < NJ; ++j) {
        s[r][j] = __expf(s[r][j] - m_new);
        ls += s[r][j];
      }
#pragma unroll
      for (int off = 1; off < 64; off <<= 1) ls += __shfl_xor(ls, off);
      l_run[r] = l_run[r] * f[r] + ls;
      m_run[r] = m_new;
    }
    {
      h2f f0h, f1h;
      f0h.x = (_Float16)f[0]; f0h.y = f0h.x;
      f1h.x = (_Float16)f[1]; f1h.y = f1h.x;
#pragma unroll
      for (int i = 0; i < 16; ++i) {
        oh[0][i] *= f0h;   // v_pk_mul_f16
        oh[1][i] *= f1h;
      }
    }
#pragma unroll
    for (int j = 0; j < NJ; ++j) {
      const int kbase = (kc + j * 64) * 4;
      h2f p0h, p1h;
      p0h.x = (_Float16)s[0][j]; p0h.y = p0h.x;
      p1h.x = (_Float16)s[1][j]; p1h.y = p1h.x;
#pragma unroll
      for (int u = 0; u < 4; ++u) {
        float4 raw = Vs[cur][kbase + ((u + ox) & 3)];  // = unit u of row k
        const h2f* vp = (const h2f*)&raw;
#pragma unroll
        for (int m2 = 0; m2 < 4; ++m2) {
          oh[0][4 * u + m2] += p0h * vp[m2];   // v_pk_fma_f16
          oh[1][4 * u + m2] += p1h * vp[m2];
        }
      }
    }
    if (biasb && c + 1 < nchunk) {
#pragma unroll
      for (int j = 0; j < NJ; ++j) {
        cb[0][j] = nb[0][j];
        cb[1][j] = nb[1][j];
      }
    }
    __syncthreads();  // drains prefetch vmcnt + LDS reads before buffer reuse
  }
  // convert fp16 accumulators to f32 once, then cross-lane reduce
  float4 o[2][8];
#pragma unroll
  for (int dd = 0; dd < 8; ++dd) {
#pragma unroll
    for (int r = 0; r < 2; ++r) {
      o[r][dd].x = (float)oh[r][2 * dd].x;
      o[r][dd].y = (float)oh[r][2 * dd].y;
      o[r][dd].z = (float)oh[r][2 * dd + 1].x;
      o[r][dd].w = (float)oh[r][2 * dd + 1].y;
    }
  }
#pragma unroll
  for (int off = 1; off < 64; off <<= 1) {
#pragma unroll
    for (int dd = 0; dd < 8; ++dd) {
      o[0][dd].x += __shfl_xor(o[0][dd].x, off);
      o[0][dd].y += __shfl_xor(o[0][dd].y, off);
      o[0][dd].z += __shfl_xor(o[0][dd].z, off);
      o[0][dd].w += __shfl_xor(o[0][dd].w, off);
      o[1][dd].x += __shfl_xor(o[1][dd].x, off);
      o[1][dd].y += __shfl_xor(o[1][dd].y, off);
      o[1][dd].z += __shfl_xor(o[1][dd].z, off);
      o[1][dd].w += __shfl_xor(o[1][dd].w, off);
    }
  }
  if (kc == 0) {
    const float inv = 1.f / l_run[0];
#pragma unroll
    for (int dd = 0; dd < 8; ++dd) {
      float4 v = o[0][dd];
      v.x *= inv; v.y *= inv; v.z *= inv; v.w *= inv;
      ((float4*)O)[(size_t)(b * NQn + q0 + 2 * w) * 64 + h * 8 + dd] = v;
    }
  } else if (kc == 1) {
    const float inv = 1.f / l_run[1];
#pragma unroll
    for (int dd = 0; dd < 8; ++dd) {
      float4 v = o[1][dd];
      v.x *= inv; v.y *= inv; v.z *= inv; v.w *= inv;
      ((float4*)O)[(size_t)(b * NQn + q0 + 2 * w + 1) * 64 + h * 8 + dd] = v;
    }
  }
}

// ---------------------------------------------------------------------------
// fsb: fused flash-self (blocks 0..511, CHUNK=128) + bias materialization
// (512..1023). Independent work; bias's memory-bound work overlaps flash.
// ---------------------------------------------------------------------------
__global__ __launch_bounds__(256, 2) void fsb_kernel(
    float* __restrict__ O, const float* __restrict__ Q,
    const __half* __restrict__ kT, const __half* __restrict__ vT,
    __half* __restrict__ biasb, const float* __restrict__ rel,
    const float* __restrict__ pad, const float* __restrict__ tsg,
    const float* __restrict__ Stabg, const float* __restrict__ Btabg)
{
  __shared__ __align__(16) char smem[34880];
  const int bx = blockIdx.x;
  if (bx < 512) {
    flash_body<128>(smem, bx & 31, bx >> 5, O, Q, kT, vT, nullptr, NQn);
  } else {
    bias_body(smem, bx - 512, biasb, rel, pad, tsg, Stabg, Btabg);
  }
}

// ---------------------------------------------------------------------------
// flash standalone (cross, CHUNK=256): grid (NQ/8, B*H), 256 threads.
// 66.5 KB LDS -> 2 blocks/CU, 512 blocks in one round; 4 chunks of 256 keys.
// ---------------------------------------------------------------------------
__global__ __launch_bounds__(256, 2) void flash_kernel(
    float* __restrict__ O, const float* __restrict__ Q,
    const __half* __restrict__ kT, const __half* __restrict__ vT,
    const __half* __restrict__ biasb, int NK)
{
  __shared__ __align__(16) char smem[66560];
  flash_body<256>(smem, blockIdx.x, blockIdx.y, O, Q, kT, vT, biasb, NK);
}

// ---------------------------------------------------------------------------
// gemm32: 32x32 tile, 256 threads, 2x2/thread, K-step 32, float4 staging with
// register prefetch. Split-K via blockIdx.z (partials at kz*M*N). relu opt.
// ---------------------------------------------------------------------------
__global__ __launch_bounds__(256) void gemm32_kernel(
    float* __restrict__ C, const float* __restrict__ A, const float* __restrict__ A2,
    const float* __restrict__ W, const float* __restrict__ bias,
    int N, int Kchunk, int Ktot, float scale, int do_relu)
{
  __shared__ float As[32][33];
  __shared__ float Ws[32][33];
  const int bm = blockIdx.y * 32, bn = blockIdx.x * 32;
  const int kz = blockIdx.z;
  const int M = gridDim.y * 32;
  float* Cp = C + (size_t)kz * M * N;
  const int tid = threadIdx.x;
  const int tx = tid & 15, ty = tid >> 4;
  const int lr = tid >> 3, lc = (tid & 7) * 4;
  float acc[2][2] = {};
  const int k00 = kz * Kchunk;
  float4 av, wv;
  {
    av = *(const float4*)(A + (size_t)(bm + lr) * Ktot + k00 + lc);
    if (A2) {
      float4 bv = *(const float4*)(A2 + (size_t)(bm + lr) * Ktot + k00 + lc);
      av.x += bv.x; av.y += bv.y; av.z += bv.z; av.w += bv.w;
    }
    wv = *(const float4*)(W + (size_t)(bn + lr) * Ktot + k00 + lc);
  }
  for (int k0 = k00; k0 < k00 + Kchunk; k0 += 32) {
    As[lr][lc] = av.x; As[lr][lc + 1] = av.y; As[lr][lc + 2] = av.z; As[lr][lc + 3] = av.w;
    Ws[lr][lc] = wv.x; Ws[lr][lc + 1] = wv.y; Ws[lr][lc + 2] = wv.z; Ws[lr][lc + 3] = wv.w;
    __syncthreads();
    if (k0 + 32 < k00 + Kchunk) {
      av = *(const float4*)(A + (size_t)(bm + lr) * Ktot + k0 + 32 + lc);
      if (A2) {
        float4 bv = *(const float4*)(A2 + (size_t)(bm + lr) * Ktot + k0 + 32 + lc);
        av.x += bv.x; av.y += bv.y; av.z += bv.z; av.w += bv.w;
      }
      wv = *(const float4*)(W + (size_t)(bn + lr) * Ktot + k0 + 32 + lc);
    }
#pragma unroll
    for (int k = 0; k < 32; ++k) {
      float a0 = As[ty * 2][k], a1 = As[ty * 2 + 1][k];
      float w0 = Ws[tx * 2][k], w1 = Ws[tx * 2 + 1][k];
      acc[0][0] += a0 * w0; acc[0][1] += a0 * w1;
      acc[1][0] += a1 * w0; acc[1][1] += a1 * w1;
    }
    __syncthreads();
  }
#pragma unroll
  for (int i = 0; i < 2; ++i) {
    int m = bm + ty * 2 + i;
#pragma unroll
    for (int j = 0; j < 2; ++j) {
      int n = bn + tx * 2 + j;
      float v = acc[i][j];
      if (bias) v += bias[n];
      v *= scale;
      if (do_relu) v = fmaxf(v, 0.f);
      Cp[(size_t)m * N + n] = v;
    }
  }
}

// ---------------------------------------------------------------------------
// out = LayerNorm(resid + sum_{s<nsplit} part[s] + bias) * g + b.
// Generalized split-K reducer + residual + LN. grid: rows, block = 256 = D.
// ---------------------------------------------------------------------------
__global__ __launch_bounds__(256) void reduce_ln_kernel(
    float* __restrict__ out, const float* __restrict__ part,
    const float* __restrict__ bias, const float* __restrict__ resid,
    const float* __restrict__ g, const float* __restrict__ bt, int nsplit)
{
  const int row = blockIdx.x;
  const int t = threadIdx.x;
  const size_t idx = (size_t)row * Dn + t;
  const size_t STR = (size_t)Bb * NQn * Dn;
  float v = bias[t] + resid[idx];
  for (int s = 0; s < nsplit; ++s) v += part[idx + (size_t)s * STR];
  float sm = v, s2 = v * v;
#pragma unroll
  for (int off = 32; off > 0; off >>= 1) {
    sm += __shfl_down(sm, off);
    s2 += __shfl_down(s2, off);
  }
  __shared__ float rs[4], rs2[4], fin[2];
  const int lane = t & 63, wid = t >> 6;
  if (lane == 0) { rs[wid] = sm; rs2[wid] = s2; }
  __syncthreads();
  if (t == 0) {
    float a = rs[0] + rs[1] + rs[2] + rs[3];
    float a2 = rs2[0] + rs2[1] + rs2[2] + rs2[3];
    float mean = a * (1.f / Dn);
    float var = a2 * (1.f / Dn) - mean * mean;
    fin[0] = mean;
    fin[1] = rsqrtf(var + EPSf);
  }
  __syncthreads();
  out[idx] = (v - fin[0]) * fin[1] * g[t] + bt[t];
}

extern "C" void kernel_launch(void* const* d_in, const int* in_sizes, int n_in,
                              void* d_out, int out_size, void* d_ws, size_t ws_size,
                              hipStream_t stream)
{
  const float* tgt   = (const float*)d_in[0];
  const float* qpos  = (const float*)d_in[1];
  const float* src   = (const float*)d_in[2];
  const float* spe   = (const float*)d_in[3];
  const float* pad   = (const float*)d_in[4];
  const float* rel   = (const float*)d_in[5];
  const float* qw    = (const float*)d_in[6];
  const float* qb    = (const float*)d_in[7];
  const float* kw    = (const float*)d_in[8];
  const float* kb    = (const float*)d_in[9];
  const float* vw    = (const float*)d_in[10];
  const float* vb    = (const float*)d_in[11];
  const float* projw = (const float*)d_in[12];
  const float* projb = (const float*)d_in[13];
  const float* cpbw1 = (const float*)d_in[14];
  const float* cpbb1 = (const float*)d_in[15];
  const float* cpbw2 = (const float*)d_in[16];
  const float* ipw   = (const float*)d_in[17];
  const float* ipb   = (const float*)d_in[18];
  const float* outw  = (const float*)d_in[19];
  const float* outb  = (const float*)d_in[20];
  const float* ln1g  = (const float*)d_in[21];
  const float* ln1b  = (const float*)d_in[22];
  const float* ln2g  = (const float*)d_in[23];
  const float* ln2b  = (const float*)d_in[24];
  const float* ln3g  = (const float*)d_in[25];
  const float* ln3b  = (const float*)d_in[26];
  const float* ff1w  = (const float*)d_in[27];
  const float* ff1b  = (const float*)d_in[28];
  const float* ff2w  = (const float*)d_in[29];
  const float* ff2b  = (const float*)d_in[30];
  float* out = (float*)d_out;
  float* ws = (float*)d_ws;

  constexpr size_t SZ_Q   = (size_t)Bb * NQn * Dn;   // 131072
  constexpr size_t SZ_S   = (size_t)Bb * NSn * Dn;   // 524288
  constexpr size_t SZ_FFH = (size_t)Bb * NQn * FFNn; // 524288

  float* qSb  = ws;
  __half* kSb = (__half*)(qSb + SZ_Q);   // head-major fp16 kT (self)
  __half* vSb = (__half*)(qSb + 2 * SZ_Q);
  float* oSb  = ws + 3 * SZ_Q;
  float* soP  = oSb + SZ_Q;              // (layout stability)
  float* tgt2 = soP + SZ_Q;
  float* qCb  = tgt2 + SZ_Q;
  __half* kCb = (__half*)(qCb + SZ_Q);   // head-major fp16 kT (cross)
  __half* vCb = (__half*)(qCb + SZ_Q + SZ_S);
  float* oCb  = qCb + SZ_Q + 2 * SZ_S;
  float* coP  = oCb + SZ_Q;              // (layout stability)
  float* tgt3 = coP + SZ_Q;
  float* ffh  = tgt3 + SZ_Q;
  float* part = ffh + SZ_FFH;            // 4 * SZ_Q partials scratch
  float* tsb  = part + 4 * SZ_Q;
  float* Stab = tsb + RPEn;
  float* Btab = Stab + (RPEn + 1) * Hn;
  __half* biasb = (__half*)(Btab + (RPEn + 1) * Hn);

  const int MQ = Bb * NQn;  // 512

  // 1. prep: cpb tables + self QKV + cross KV (fp16/fdot2 GEMM bodies)
  prep_kernel<<<dim3(96 + 256 + 1), dim3(512), 0, stream>>>(
      qSb, kSb, vSb, kCb, vCb, tgt, qpos, src, spe, ipw, ipb,
      kw, kb, vw, vb, cpbw1, cpbb1, cpbw2, tsb, Stab, Btab);

  // 2. fused: flash self (512 blocks) + fp16 bias materialization (512 blocks)
  fsb_kernel<<<dim3(1024), dim3(256), 0, stream>>>(
      oSb, qSb, kSb, vSb, biasb, rel, pad, tsb, Stab, Btab);

  // 3. self out-proj, split-K x2 -> partials (bias deferred to reducer)
  gemm32_kernel<<<dim3(Dn / 32, MQ / 32, 2), dim3(256), 0, stream>>>(
      part, oSb, nullptr, outw, nullptr, Dn, 128, Dn, 1.f, 0);

  // 4. tgt2 = LN2(tgt + sum(part) + outb)
  reduce_ln_kernel<<<dim3(MQ), dim3(256), 0, stream>>>(
      tgt2, part, outb, tgt, ln2g, ln2b, 2);

  // 5. cross q
  gemm32_kernel<<<dim3(Dn / 32, MQ / 32, 1), dim3(256), 0, stream>>>(
      qCb, tgt2, qpos, qw, qb, Dn, Dn, Dn, SCALEf, 0);

  // 6. cross attention (CHUNK=256 flash, fp16 K/V + fp16 staged bias)
  flash_kernel<<<dim3(NQn / 8, Bb * Hn), dim3(256), 0, stream>>>(
      oCb, qCb, kCb, vCb, biasb, NSn);

  // 7. cross out-proj, split-K x2 -> partials
  gemm32_kernel<<<dim3(Dn / 32, MQ / 32, 2), dim3(256), 0, stream>>>(
      part, oCb, nullptr, projw, nullptr, Dn, 128, Dn, 1.f, 0);

  // 8. tgt3 = LN1(tgt2 + sum(part) + projb)
  reduce_ln_kernel<<<dim3(MQ), dim3(256), 0, stream>>>(
      tgt3, part, projb, tgt2, ln1g, ln1b, 2);

  // 9. FFN1 (relu) as gemm32: 512 blocks (full GPU)
  gemm32_kernel<<<dim3(FFNn / 32, MQ / 32, 1), dim3(256), 0, stream>>>(
      ffh, tgt3, nullptr, ff1w, ff1b, FFNn, Dn, Dn, 1.f, 1);

  // 10. FFN2 split-K x4 -> partials
  gemm32_kernel<<<dim3(Dn / 32, MQ / 32, 4), dim3(256), 0, stream>>>(
      part, ffh, nullptr, ff2w, nullptr, Dn, 256, FFNn, 1.f, 0);

  // 11. out = LN3(tgt3 + sum(part) + ff2b)
  reduce_ln_kernel<<<dim3(MQ), dim3(256), 0, stream>>>(
      out, part, ff2b, tgt3, ln3g, ln3b, 4);
}

// Round 22
// 103.713 us; speedup vs baseline: 1.2264x; 1.1146x over previous
//
#include <hip/hip_runtime.h>
#include <hip/hip_bf16.h>
#include <hip/hip_fp16.h>
#include <math.h>

#define Bb 2
#define NQn 256
#define NSn 1024
#define Dn 256
#define Hn 8
#define DHn 32
#define FFNn 1024
#define RPEn 512
#define SCALEf 0.17677669529663687f
#define EPSf 1e-5f

#if defined(__has_builtin)
#if __has_builtin(__builtin_amdgcn_fdot2)
#define HAS_FDOT2 1
#endif
#endif
#ifndef HAS_FDOT2
#define HAS_FDOT2 0
#endif

typedef _Float16 h2f __attribute__((ext_vector_type(2)));

// async global->LDS, 16B per lane. LDS dest must be linear in lane order
// (wave-uniform base + lane*16); global src is per-lane (pre-swizzled).
#define GLDS16(g, l)                                                         \
  __builtin_amdgcn_global_load_lds(                                          \
      (const __attribute__((address_space(1))) void*)(const void*)(g),       \
      (__attribute__((address_space(3))) void*)(void*)(l), 16, 0, 0)

__device__ __forceinline__ float fdot2e(h2f a, h2f b, float c) {
#if HAS_FDOT2
  return __builtin_amdgcn_fdot2(a, b, c, false);
#else
  return c + (float)a.x * (float)b.x + (float)a.y * (float)b.y;
#endif
}

// ---------------------------------------------------------------------------
// gemm64h body (r21): 64x64 tile, 512 threads, K-step 32, float4 loads with
// reg prefetch; A and W staged as PACKED FP16 (h2f); inner loop = 16 k-pairs
// x 8 v_dot2_f32_f16 with f32 accumulation. Epilogue: f32 acc + bias + scale
// + relu; trsh != 0 writes transposed head-major FP16.
// ---------------------------------------------------------------------------
__device__ __forceinline__ void gemm64h_body(
    float* __restrict__ C, __half* __restrict__ Ch, int ldc,
    const float* __restrict__ A, const float* __restrict__ A2, int ld,
    const float* __restrict__ W, const float* __restrict__ bias,
    int K, int bm, int bnC, int bnW, float scale, int do_relu, int trsh,
    float* smem)
{
  h2f (*Ah)[17] = (h2f(*)[17])smem;            // [row][kpair]
  h2f (*WhT)[68] = (h2f(*)[68])(smem + 1088);  // [kpair][col]
  const int tid = threadIdx.x;
  const int tx = tid & 15, ty = tid >> 4;       // ty 0..31
  const int lr = tid >> 3, lc = (tid & 7) * 4;  // staging: row, k-offset
  const int lp = lc >> 1;                       // k-pair index
  float4 ra, rw;
  {
    ra = *(const float4*)(A + (size_t)(bm + lr) * ld + lc);
    if (A2) {
      float4 t = *(const float4*)(A2 + (size_t)(bm + lr) * ld + lc);
      ra.x += t.x; ra.y += t.y; ra.z += t.z; ra.w += t.w;
    }
    rw = *(const float4*)(W + (size_t)(bnW + lr) * ld + lc);
  }
  float acc[2][4] = {};
  for (int k0 = 0; k0 < K; k0 += 32) {
    {
      h2f a01, a23, w01, w23;
      a01.x = (_Float16)ra.x; a01.y = (_Float16)ra.y;
      a23.x = (_Float16)ra.z; a23.y = (_Float16)ra.w;
      w01.x = (_Float16)rw.x; w01.y = (_Float16)rw.y;
      w23.x = (_Float16)rw.z; w23.y = (_Float16)rw.w;
      Ah[lr][lp] = a01; Ah[lr][lp + 1] = a23;
      WhT[lp][lr] = w01; WhT[lp + 1][lr] = w23;
    }
    __syncthreads();
    if (k0 + 32 < K) {
      ra = *(const float4*)(A + (size_t)(bm + lr) * ld + k0 + 32 + lc);
      if (A2) {
        float4 t = *(const float4*)(A2 + (size_t)(bm + lr) * ld + k0 + 32 + lc);
        ra.x += t.x; ra.y += t.y; ra.z += t.z; ra.w += t.w;
      }
      rw = *(const float4*)(W + (size_t)(bnW + lr) * ld + k0 + 32 + lc);
    }
#pragma unroll
    for (int kp = 0; kp < 16; ++kp) {
      h2f a0 = Ah[ty][kp], a1 = Ah[ty + 32][kp];
      float4 wr = *(const float4*)&WhT[kp][tx * 4];
      const h2f* wp = (const h2f*)&wr;
      acc[0][0] = fdot2e(a0, wp[0], acc[0][0]);
      acc[0][1] = fdot2e(a0, wp[1], acc[0][1]);
      acc[0][2] = fdot2e(a0, wp[2], acc[0][2]);
      acc[0][3] = fdot2e(a0, wp[3], acc[0][3]);
      acc[1][0] = fdot2e(a1, wp[0], acc[1][0]);
      acc[1][1] = fdot2e(a1, wp[1], acc[1][1]);
      acc[1][2] = fdot2e(a1, wp[2], acc[1][2]);
      acc[1][3] = fdot2e(a1, wp[3], acc[1][3]);
    }
    __syncthreads();
  }
#pragma unroll
  for (int i = 0; i < 2; ++i) {
    int m = bm + ty + i * 32;
#pragma unroll
    for (int j = 0; j < 4; ++j) {
      float v = acc[i][j];
      if (bias) v += bias[bnW + tx * 4 + j];
      v *= scale;
      if (do_relu) v = fmaxf(v, 0.f);
      if (trsh == 0) {
        C[(size_t)m * ldc + bnC + tx * 4 + j] = v;
      } else {
        const int nC = bnC + tx * 4 + j;
        const int bb = m >> trsh, kseq = m & ((1 << trsh) - 1);
        const int hh = nC >> 5, d = nC & 31;
        Ch[((((size_t)(bb * Hn + hh)) << trsh) + kseq) * 32 + d] =
            __float2half(v);
      }
    }
  }
}

// ---------------------------------------------------------------------------
// prep: fused build_cpb (1 block) + self QKV GEMM (96 blocks; K/V written
// head-major transposed fp16) + cross KV GEMM (256 blocks). 512 threads.
// ---------------------------------------------------------------------------
__global__ __launch_bounds__(512) void prep_kernel(
    float* __restrict__ qSb, __half* __restrict__ kSb, __half* __restrict__ vSb,
    __half* __restrict__ kCb, __half* __restrict__ vCb,
    const float* __restrict__ tgt, const float* __restrict__ qpos,
    const float* __restrict__ src, const float* __restrict__ spe,
    const float* __restrict__ ipw, const float* __restrict__ ipb,
    const float* __restrict__ kw, const float* __restrict__ kb,
    const float* __restrict__ vw, const float* __restrict__ vb,
    const float* __restrict__ w1p, const float* __restrict__ b1p,
    const float* __restrict__ w2p,
    float* __restrict__ tout, float* __restrict__ Stab, float* __restrict__ Btab)
{
  __shared__ float smem[4288];
  const int bx = blockIdx.x;
  const int tid = threadIdx.x;
  if (bx < 96) {
    int my = bx & 7, nx = bx >> 3;
    int sec = nx >> 2;
    gemm64h_body(qSb, sec == 1 ? kSb : vSb, Dn, tgt,
                 sec < 2 ? qpos : nullptr, Dn, ipw, ipb,
                 Dn, my * 64, (nx & 3) * 64, nx * 64,
                 sec == 0 ? SCALEf : 1.f, 0, sec == 0 ? 0 : 8, smem);
    return;
  }
  if (bx < 96 + 256) {
    int idx = bx - 96;
    int my = idx & 31, nx = idx >> 5;
    int sec = nx >> 2;
    gemm64h_body(nullptr, sec ? vCb : kCb, Dn, src, sec ? nullptr : spe, Dn,
                 sec ? vw : kw, sec ? vb : kb,
                 Dn, my * 64, (nx & 3) * 64, (nx & 3) * 64, 1.f, 0, 10, smem);
    return;
  }
  // ---- cpb piecewise-linear table build (verified rounds 1-21) ----
  float* key = smem;
  int* pidx = (int*)(smem + 512);
  float* w1s = smem + 1024;
  float* b1s = smem + 1536;
  {
    float w = w1p[tid], bb = b1p[tid];
    key[tid] = (w != 0.f) ? (-bb / w) : 3.0e38f;
    pidx[tid] = tid;
  }
  __syncthreads();
  for (int k = 2; k <= RPEn; k <<= 1) {
    for (int j = k >> 1; j > 0; j >>= 1) {
      int ixj = tid ^ j;
      if (ixj > tid) {
        float a = key[tid], c = key[ixj];
        bool asc = ((tid & k) == 0);
        bool sw = asc ? (a > c) : (a < c);
        if (sw) {
          key[tid] = c; key[ixj] = a;
          int tmp = pidx[tid]; pidx[tid] = pidx[ixj]; pidx[ixj] = tmp;
        }
      }
      __syncthreads();
    }
  }
  w1s[tid] = w1p[pidx[tid]];
  b1s[tid] = b1p[pidx[tid]];
  tout[tid] = key[tid];
  __syncthreads();
  const int lane = tid & 63;
  const int h = tid >> 6;
  const int j0 = lane * 8;
  float sp[8], bp[8], sn[8], bn[8];
  float csp = 0.f, cbp = 0.f, csn = 0.f, cbn = 0.f, ccc = 0.f;
#pragma unroll
  for (int e = 0; e < 8; ++e) {
    int j = j0 + e;
    float w = w1s[j], b = b1s[j];
    float c = w2p[h * RPEn + pidx[j]];
    sp[e] = csp; bp[e] = cbp; sn[e] = csn; bn[e] = cbn;
    if (w > 0.f)      { csp += w * c; cbp += b * c; }
    else if (w < 0.f) { csn += w * c; cbn += b * c; }
    else              { ccc += fmaxf(b, 0.f) * c; }
  }
  float isp = csp, ibp = cbp, isn = csn, ibn = cbn, icc = ccc;
#pragma unroll
  for (int d = 1; d < 64; d <<= 1) {
    float t0 = __shfl_up(isp, d);
    float t1 = __shfl_up(ibp, d);
    float t2 = __shfl_up(isn, d);
    float t3 = __shfl_up(ibn, d);
    if (lane >= d) { isp += t0; ibp += t1; isn += t2; ibn += t3; }
    icc += __shfl_xor(icc, d);
  }
  const float tsn = __shfl(isn, 63);
  const float tbn = __shfl(ibn, 63);
  const float esp = isp - csp, ebp = ibp - cbp;
  const float esn = isn - csn, ebn = ibn - cbn;
#pragma unroll
  for (int e = 0; e < 8; ++e) {
    int j = j0 + e;
    Stab[j * Hn + h] = (esp + sp[e]) + (tsn - (esn + sn[e]));
    Btab[j * Hn + h] = (ebp + bp[e]) + (tbn - (ebn + bn[e])) + icc;
  }
  if (lane == 63) {
    Stab[RPEn * Hn + h] = isp;
    Btab[RPEn * Hn + h] = ibp + icc;
  }
}

// ---------------------------------------------------------------------------
// bias body: fp16 bias[b,h,q,k] = Sh[lo]*m + Bh[lo] - 100*pad. One block per
// (b,q); search once per (b,q,k), applied to 8 heads. LDS carved from smem.
// ---------------------------------------------------------------------------
__device__ __forceinline__ void bias_body(
    char* smemraw, int idx,
    __half* __restrict__ biasb, const float* __restrict__ rel,
    const float* __restrict__ pad, const float* __restrict__ tsg,
    const float* __restrict__ Stabg, const float* __restrict__ Btabg)
{
  float* ts = (float*)smemraw;                    // 512 f
  float* Sh = (float*)(smemraw + 2048);           // 4104 f
  float* Bh = (float*)(smemraw + 18464);          // 4104 f
  const int tid = threadIdx.x;
  const int b = idx >> 8, q = idx & 255;
  ts[tid] = tsg[tid];
  ts[tid + 256] = tsg[tid + 256];
  for (int i = tid; i < (RPEn + 1) * Hn; i += 256) {
    Sh[i] = Stabg[i];
    Bh[i] = Btabg[i];
  }
  __syncthreads();
#pragma unroll
  for (int j = 0; j < 4; ++j) {
    const int k = tid + j * 256;
    const float m = rel[((size_t)b * NQn + q) * NSn + k];
    const float padv = -100.f * pad[b * NSn + k];
    int lo = 0, hi = RPEn;
#pragma unroll
    for (int it = 0; it < 9; ++it) {
      int mid = (lo + hi) >> 1;
      if (ts[mid] < m) lo = mid + 1; else hi = mid;
    }
#pragma unroll
    for (int h = 0; h < Hn; ++h) {
      biasb[(((size_t)(b * Hn + h)) * NQn + q) * NSn + k] =
          __float2half(Sh[lo * Hn + h] * m + Bh[lo * Hn + h] + padv);
    }
  }
}

// ---------------------------------------------------------------------------
// Flash body, templated on CHUNK. R=2 rows/thread, HEAD-MAJOR FP16 K/V.
// Rotation swizzle o(k)=(k+(k>>2))&3 in ADDRESS arithmetic only.
// r19: QK via v_dot2_f32_f16. r20: PV + rescale via packed fp16 math.
// ---------------------------------------------------------------------------
template <int CHUNK>
__device__ __forceinline__ void flash_body(
    char* smemraw, int qb, int bh,
    float* __restrict__ O, const float* __restrict__ Q,
    const __half* __restrict__ kT, const __half* __restrict__ vT,
    const __half* __restrict__ biasb, int NK)
{
  constexpr int NJ = CHUNK / 64;        // keys per lane per chunk
  constexpr int NS = CHUNK / 64;        // stage iters
  float4 (*Ks)[CHUNK * 4] = (float4(*)[CHUNK * 4])smemraw;
  float4 (*Vs)[CHUNK * 4] = (float4(*)[CHUNK * 4])(smemraw + CHUNK * 128);
  float4* Qs = (float4*)(smemraw + CHUNK * 256);
  const int b = bh >> 3, h = bh & 7;
  const int q0 = qb * 8;
  const int tid = threadIdx.x;
  const int w = tid >> 6, kc = tid & 63;
  const float4* Ktp = (const float4*)kT + (size_t)bh * NK * 4;
  const float4* Vtp = (const float4*)vT + (size_t)bh * NK * 4;
  if (tid < 64)
    Qs[tid] = ((const float4*)Q)[(size_t)(b * NQn + q0 + (tid >> 3)) * 64 +
                                 h * 8 + (tid & 7)];

  const __half* brow0 =
      biasb ? biasb + ((size_t)bh * NQn + q0 + 2 * w) * NK : nullptr;
  const __half* brow1 = biasb ? brow0 + NK : nullptr;

  auto stage = [&](int buf, int kb0) {
#pragma unroll
    for (int u = 0; u < NS; ++u) {
      const int s = tid + u * 256;   // linear LDS slot (lane order)
      const int k = s >> 2, e = s & 3;
      const int ok = (k + (k >> 2)) & 3;
      const int g = (kb0 + k) * 4 + ((e - ok) & 3);
      GLDS16(Ktp + g, &Ks[buf][s]);
      GLDS16(Vtp + g, &Vs[buf][s]);
    }
  };

  stage(0, 0);
  float cb[2][NJ];
  if (biasb) {
#pragma unroll
    for (int j = 0; j < NJ; ++j) {
      cb[0][j] = __half2float(brow0[kc + j * 64]);
      cb[1][j] = __half2float(brow1[kc + j * 64]);
    }
  }
  __syncthreads();  // drains vmcnt: chunk 0 + Qs ready

  // q rows packed to fp16 pairs
  h2f qh[2][16];
#pragma unroll
  for (int dd = 0; dd < 8; ++dd) {
    float4 v0 = Qs[(2 * w) * 8 + dd];
    float4 v1 = Qs[(2 * w + 1) * 8 + dd];
    h2f t;
    t.x = (_Float16)v0.x; t.y = (_Float16)v0.y; qh[0][2 * dd] = t;
    t.x = (_Float16)v0.z; t.y = (_Float16)v0.w; qh[0][2 * dd + 1] = t;
    t.x = (_Float16)v1.x; t.y = (_Float16)v1.y; qh[1][2 * dd] = t;
    t.x = (_Float16)v1.z; t.y = (_Float16)v1.w; qh[1][2 * dd + 1] = t;
  }
  // O accumulated in packed fp16: 16 h2f pairs per row = 32 elems
  h2f oh[2][16];
#pragma unroll
  for (int i = 0; i < 16; ++i) {
    oh[0][i] = (h2f)(_Float16)0;
    oh[1][i] = (h2f)(_Float16)0;
  }
  float m_run[2] = {-3.0e38f, -3.0e38f};
  float l_run[2] = {0.f, 0.f};
  const int nchunk = NK / CHUNK;
  const int ox = (kc + (kc >> 2)) & 3;  // row-rot key, invariant to j*64

  for (int c = 0; c < nchunk; ++c) {
    const int cur = c & 1;
    float nb[2][NJ];
    if (c + 1 < nchunk) {
      stage(cur ^ 1, (c + 1) * CHUNK);  // prefetch flies under compute
      if (biasb) {
#pragma unroll
        for (int j = 0; j < NJ; ++j) {
          nb[0][j] = __half2float(brow0[(c + 1) * CHUNK + kc + j * 64]);
          nb[1][j] = __half2float(brow1[(c + 1) * CHUNK + kc + j * 64]);
        }
      }
    }
    float s[2][NJ];
#pragma unroll
    for (int j = 0; j < NJ; ++j) {
      const int kbase = (kc + j * 64) * 4;
      float a0 = 0.f, a1 = 0.f;
#pragma unroll
      for (int u = 0; u < 4; ++u) {
        float4 raw = Ks[cur][kbase + ((u + ox) & 3)];  // = unit u of row k
        const h2f* kp = (const h2f*)&raw;
#pragma unroll
        for (int m2 = 0; m2 < 4; ++m2) {
          a0 = fdot2e(qh[0][4 * u + m2], kp[m2], a0);
          a1 = fdot2e(qh[1][4 * u + m2], kp[m2], a1);
        }
      }
      s[0][j] = a0;
      s[1][j] = a1;
      if (biasb) { s[0][j] += cb[0][j]; s[1][j] += cb[1][j]; }
    }
    float f[2];
#pragma unroll
    for (int r = 0; r < 2; ++r) {
      float cmax = s[r][0];
#pragma unroll
      for (int j = 1; j < NJ; ++j) cmax = fmaxf(cmax, s[r][j]);
#pragma unroll
      for (int off = 1; off < 64; off <<= 1)
        cmax = fmaxf(cmax, __shfl_xor(cmax, off));
      const float m_new = fmaxf(m_run[r], cmax);
      f[r] = __expf(m_run[r] - m_new);
      float ls = 0.f;
#pragma unroll
      for (int j = 0; j < NJ; ++j) {
        s[r][j] = __expf(s[r][j] - m_new);
        ls += s[r][j];
      }
#pragma unroll
      for (int off = 1; off < 64; off <<= 1) ls += __shfl_xor(ls, off);
      l_run[r] = l_run[r] * f[r] + ls;
      m_run[r] = m_new;
    }
    {
      h2f f0h, f1h;
      f0h.x = (_Float16)f[0]; f0h.y = f0h.x;
      f1h.x = (_Float16)f[1]; f1h.y = f1h.x;
#pragma unroll
      for (int i = 0; i < 16; ++i) {
        oh[0][i] *= f0h;   // v_pk_mul_f16
        oh[1][i] *= f1h;
      }
    }
#pragma unroll
    for (int j = 0; j < NJ; ++j) {
      const int kbase = (kc + j * 64) * 4;
      h2f p0h, p1h;
      p0h.x = (_Float16)s[0][j]; p0h.y = p0h.x;
      p1h.x = (_Float16)s[1][j]; p1h.y = p1h.x;
#pragma unroll
      for (int u = 0; u < 4; ++u) {
        float4 raw = Vs[cur][kbase + ((u + ox) & 3)];  // = unit u of row k
        const h2f* vp = (const h2f*)&raw;
#pragma unroll
        for (int m2 = 0; m2 < 4; ++m2) {
          oh[0][4 * u + m2] += p0h * vp[m2];   // v_pk_fma_f16
          oh[1][4 * u + m2] += p1h * vp[m2];
        }
      }
    }
    if (biasb && c + 1 < nchunk) {
#pragma unroll
      for (int j = 0; j < NJ; ++j) {
        cb[0][j] = nb[0][j];
        cb[1][j] = nb[1][j];
      }
    }
    __syncthreads();  // drains prefetch vmcnt + LDS reads before buffer reuse
  }
  // convert fp16 accumulators to f32 once, then cross-lane reduce
  float4 o[2][8];
#pragma unroll
  for (int dd = 0; dd < 8; ++dd) {
#pragma unroll
    for (int r = 0; r < 2; ++r) {
      o[r][dd].x = (float)oh[r][2 * dd].x;
      o[r][dd].y = (float)oh[r][2 * dd].y;
      o[r][dd].z = (float)oh[r][2 * dd + 1].x;
      o[r][dd].w = (float)oh[r][2 * dd + 1].y;
    }
  }
#pragma unroll
  for (int off = 1; off < 64; off <<= 1) {
#pragma unroll
    for (int dd = 0; dd < 8; ++dd) {
      o[0][dd].x += __shfl_xor(o[0][dd].x, off);
      o[0][dd].y += __shfl_xor(o[0][dd].y, off);
      o[0][dd].z += __shfl_xor(o[0][dd].z, off);
      o[0][dd].w += __shfl_xor(o[0][dd].w, off);
      o[1][dd].x += __shfl_xor(o[1][dd].x, off);
      o[1][dd].y += __shfl_xor(o[1][dd].y, off);
      o[1][dd].z += __shfl_xor(o[1][dd].z, off);
      o[1][dd].w += __shfl_xor(o[1][dd].w, off);
    }
  }
  if (kc == 0) {
    const float inv = 1.f / l_run[0];
#pragma unroll
    for (int dd = 0; dd < 8; ++dd) {
      float4 v = o[0][dd];
      v.x *= inv; v.y *= inv; v.z *= inv; v.w *= inv;
      ((float4*)O)[(size_t)(b * NQn + q0 + 2 * w) * 64 + h * 8 + dd] = v;
    }
  } else if (kc == 1) {
    const float inv = 1.f / l_run[1];
#pragma unroll
    for (int dd = 0; dd < 8; ++dd) {
      float4 v = o[1][dd];
      v.x *= inv; v.y *= inv; v.z *= inv; v.w *= inv;
      ((float4*)O)[(size_t)(b * NQn + q0 + 2 * w + 1) * 64 + h * 8 + dd] = v;
    }
  }
}

// ---------------------------------------------------------------------------
// fsb: fused flash-self (blocks 0..511, CHUNK=128) + bias materialization
// (512..1023). Independent work; bias's memory-bound work overlaps flash.
// ---------------------------------------------------------------------------
__global__ __launch_bounds__(256, 2) void fsb_kernel(
    float* __restrict__ O, const float* __restrict__ Q,
    const __half* __restrict__ kT, const __half* __restrict__ vT,
    __half* __restrict__ biasb, const float* __restrict__ rel,
    const float* __restrict__ pad, const float* __restrict__ tsg,
    const float* __restrict__ Stabg, const float* __restrict__ Btabg)
{
  __shared__ __align__(16) char smem[34880];
  const int bx = blockIdx.x;
  if (bx < 512) {
    flash_body<128>(smem, bx & 31, bx >> 5, O, Q, kT, vT, nullptr, NQn);
  } else {
    bias_body(smem, bx - 512, biasb, rel, pad, tsg, Stabg, Btabg);
  }
}

// ---------------------------------------------------------------------------
// flash standalone (cross, CHUNK=256): grid (NQ/8, B*H), 256 threads.
// 66.5 KB LDS -> 2 blocks/CU, 512 blocks in one round; 4 chunks of 256 keys.
// ---------------------------------------------------------------------------
__global__ __launch_bounds__(256, 2) void flash_kernel(
    float* __restrict__ O, const float* __restrict__ Q,
    const __half* __restrict__ kT, const __half* __restrict__ vT,
    const __half* __restrict__ biasb, int NK)
{
  __shared__ __align__(16) char smem[66560];
  flash_body<256>(smem, blockIdx.x, blockIdx.y, O, Q, kT, vT, biasb, NK);
}

// ---------------------------------------------------------------------------
// gemm32h (r22): 32x32 tile, 256 threads, K-step 32, float4 loads with reg
// prefetch; A and W staged as PACKED FP16 (h2f); inner loop = 16 k-pairs x 4
// v_dot2_f32_f16 with f32 accumulation -- VALU and LDS-read streams halve vs
// the f32 body. Split-K via blockIdx.z (partials at kz*M*N). relu opt.
// Banks: W-read rows stride 17 h2f -> banks 2*tx mod 32 distinct; A broadcast.
// ---------------------------------------------------------------------------
__global__ __launch_bounds__(256) void gemm32_kernel(
    float* __restrict__ C, const float* __restrict__ A, const float* __restrict__ A2,
    const float* __restrict__ W, const float* __restrict__ bias,
    int N, int Kchunk, int Ktot, float scale, int do_relu)
{
  __shared__ h2f Ah[32][17];
  __shared__ h2f Wh[32][17];
  const int bm = blockIdx.y * 32, bn = blockIdx.x * 32;
  const int kz = blockIdx.z;
  const int M = gridDim.y * 32;
  float* Cp = C + (size_t)kz * M * N;
  const int tid = threadIdx.x;
  const int tx = tid & 15, ty = tid >> 4;
  const int lr = tid >> 3, lc = (tid & 7) * 4;
  const int lp = lc >> 1;  // k-pair index
  float acc[2][2] = {};
  const int k00 = kz * Kchunk;
  float4 av, wv;
  {
    av = *(const float4*)(A + (size_t)(bm + lr) * Ktot + k00 + lc);
    if (A2) {
      float4 bv = *(const float4*)(A2 + (size_t)(bm + lr) * Ktot + k00 + lc);
      av.x += bv.x; av.y += bv.y; av.z += bv.z; av.w += bv.w;
    }
    wv = *(const float4*)(W + (size_t)(bn + lr) * Ktot + k00 + lc);
  }
  for (int k0 = k00; k0 < k00 + Kchunk; k0 += 32) {
    {
      h2f a01, a23, w01, w23;
      a01.x = (_Float16)av.x; a01.y = (_Float16)av.y;
      a23.x = (_Float16)av.z; a23.y = (_Float16)av.w;
      w01.x = (_Float16)wv.x; w01.y = (_Float16)wv.y;
      w23.x = (_Float16)wv.z; w23.y = (_Float16)wv.w;
      Ah[lr][lp] = a01; Ah[lr][lp + 1] = a23;
      Wh[lr][lp] = w01; Wh[lr][lp + 1] = w23;
    }
    __syncthreads();
    if (k0 + 32 < k00 + Kchunk) {
      av = *(const float4*)(A + (size_t)(bm + lr) * Ktot + k0 + 32 + lc);
      if (A2) {
        float4 bv = *(const float4*)(A2 + (size_t)(bm + lr) * Ktot + k0 + 32 + lc);
        av.x += bv.x; av.y += bv.y; av.z += bv.z; av.w += bv.w;
      }
      wv = *(const float4*)(W + (size_t)(bn + lr) * Ktot + k0 + 32 + lc);
    }
#pragma unroll
    for (int kp = 0; kp < 16; ++kp) {
      h2f a0 = Ah[ty * 2][kp], a1 = Ah[ty * 2 + 1][kp];
      h2f w0 = Wh[tx * 2][kp], w1 = Wh[tx * 2 + 1][kp];
      acc[0][0] = fdot2e(a0, w0, acc[0][0]);
      acc[0][1] = fdot2e(a0, w1, acc[0][1]);
      acc[1][0] = fdot2e(a1, w0, acc[1][0]);
      acc[1][1] = fdot2e(a1, w1, acc[1][1]);
    }
    __syncthreads();
  }
#pragma unroll
  for (int i = 0; i < 2; ++i) {
    int m = bm + ty * 2 + i;
#pragma unroll
    for (int j = 0; j < 2; ++j) {
      int n = bn + tx * 2 + j;
      float v = acc[i][j];
      if (bias) v += bias[n];
      v *= scale;
      if (do_relu) v = fmaxf(v, 0.f);
      Cp[(size_t)m * N + n] = v;
    }
  }
}

// ---------------------------------------------------------------------------
// out = LayerNorm(resid + sum_{s<nsplit} part[s] + bias) * g + b.
// Generalized split-K reducer + residual + LN. grid: rows, block = 256 = D.
// ---------------------------------------------------------------------------
__global__ __launch_bounds__(256) void reduce_ln_kernel(
    float* __restrict__ out, const float* __restrict__ part,
    const float* __restrict__ bias, const float* __restrict__ resid,
    const float* __restrict__ g, const float* __restrict__ bt, int nsplit)
{
  const int row = blockIdx.x;
  const int t = threadIdx.x;
  const size_t idx = (size_t)row * Dn + t;
  const size_t STR = (size_t)Bb * NQn * Dn;
  float v = bias[t] + resid[idx];
  for (int s = 0; s < nsplit; ++s) v += part[idx + (size_t)s * STR];
  float sm = v, s2 = v * v;
#pragma unroll
  for (int off = 32; off > 0; off >>= 1) {
    sm += __shfl_down(sm, off);
    s2 += __shfl_down(s2, off);
  }
  __shared__ float rs[4], rs2[4], fin[2];
  const int lane = t & 63, wid = t >> 6;
  if (lane == 0) { rs[wid] = sm; rs2[wid] = s2; }
  __syncthreads();
  if (t == 0) {
    float a = rs[0] + rs[1] + rs[2] + rs[3];
    float a2 = rs2[0] + rs2[1] + rs2[2] + rs2[3];
    float mean = a * (1.f / Dn);
    float var = a2 * (1.f / Dn) - mean * mean;
    fin[0] = mean;
    fin[1] = rsqrtf(var + EPSf);
  }
  __syncthreads();
  out[idx] = (v - fin[0]) * fin[1] * g[t] + bt[t];
}

extern "C" void kernel_launch(void* const* d_in, const int* in_sizes, int n_in,
                              void* d_out, int out_size, void* d_ws, size_t ws_size,
                              hipStream_t stream)
{
  const float* tgt   = (const float*)d_in[0];
  const float* qpos  = (const float*)d_in[1];
  const float* src   = (const float*)d_in[2];
  const float* spe   = (const float*)d_in[3];
  const float* pad   = (const float*)d_in[4];
  const float* rel   = (const float*)d_in[5];
  const float* qw    = (const float*)d_in[6];
  const float* qb    = (const float*)d_in[7];
  const float* kw    = (const float*)d_in[8];
  const float* kb    = (const float*)d_in[9];
  const float* vw    = (const float*)d_in[10];
  const float* vb    = (const float*)d_in[11];
  const float* projw = (const float*)d_in[12];
  const float* projb = (const float*)d_in[13];
  const float* cpbw1 = (const float*)d_in[14];
  const float* cpbb1 = (const float*)d_in[15];
  const float* cpbw2 = (const float*)d_in[16];
  const float* ipw   = (const float*)d_in[17];
  const float* ipb   = (const float*)d_in[18];
  const float* outw  = (const float*)d_in[19];
  const float* outb  = (const float*)d_in[20];
  const float* ln1g  = (const float*)d_in[21];
  const float* ln1b  = (const float*)d_in[22];
  const float* ln2g  = (const float*)d_in[23];
  const float* ln2b  = (const float*)d_in[24];
  const float* ln3g  = (const float*)d_in[25];
  const float* ln3b  = (const float*)d_in[26];
  const float* ff1w  = (const float*)d_in[27];
  const float* ff1b  = (const float*)d_in[28];
  const float* ff2w  = (const float*)d_in[29];
  const float* ff2b  = (const float*)d_in[30];
  float* out = (float*)d_out;
  float* ws = (float*)d_ws;

  constexpr size_t SZ_Q   = (size_t)Bb * NQn * Dn;   // 131072
  constexpr size_t SZ_S   = (size_t)Bb * NSn * Dn;   // 524288
  constexpr size_t SZ_FFH = (size_t)Bb * NQn * FFNn; // 524288

  float* qSb  = ws;
  __half* kSb = (__half*)(qSb + SZ_Q);   // head-major fp16 kT (self)
  __half* vSb = (__half*)(qSb + 2 * SZ_Q);
  float* oSb  = ws + 3 * SZ_Q;
  float* soP  = oSb + SZ_Q;              // (layout stability)
  float* tgt2 = soP + SZ_Q;
  float* qCb  = tgt2 + SZ_Q;
  __half* kCb = (__half*)(qCb + SZ_Q);   // head-major fp16 kT (cross)
  __half* vCb = (__half*)(qCb + SZ_Q + SZ_S);
  float* oCb  = qCb + SZ_Q + 2 * SZ_S;
  float* coP  = oCb + SZ_Q;              // (layout stability)
  float* tgt3 = coP + SZ_Q;
  float* ffh  = tgt3 + SZ_Q;
  float* part = ffh + SZ_FFH;            // 4 * SZ_Q partials scratch
  float* tsb  = part + 4 * SZ_Q;
  float* Stab = tsb + RPEn;
  float* Btab = Stab + (RPEn + 1) * Hn;
  __half* biasb = (__half*)(Btab + (RPEn + 1) * Hn);

  const int MQ = Bb * NQn;  // 512

  // 1. prep: cpb tables + self QKV + cross KV (fp16/fdot2 GEMM bodies)
  prep_kernel<<<dim3(96 + 256 + 1), dim3(512), 0, stream>>>(
      qSb, kSb, vSb, kCb, vCb, tgt, qpos, src, spe, ipw, ipb,
      kw, kb, vw, vb, cpbw1, cpbb1, cpbw2, tsb, Stab, Btab);

  // 2. fused: flash self (512 blocks) + fp16 bias materialization (512 blocks)
  fsb_kernel<<<dim3(1024), dim3(256), 0, stream>>>(
      oSb, qSb, kSb, vSb, biasb, rel, pad, tsb, Stab, Btab);

  // 3. self out-proj, split-K x2 -> partials (bias deferred to reducer)
  gemm32_kernel<<<dim3(Dn / 32, MQ / 32, 2), dim3(256), 0, stream>>>(
      part, oSb, nullptr, outw, nullptr, Dn, 128, Dn, 1.f, 0);

  // 4. tgt2 = LN2(tgt + sum(part) + outb)
  reduce_ln_kernel<<<dim3(MQ), dim3(256), 0, stream>>>(
      tgt2, part, outb, tgt, ln2g, ln2b, 2);

  // 5. cross q
  gemm32_kernel<<<dim3(Dn / 32, MQ / 32, 1), dim3(256), 0, stream>>>(
      qCb, tgt2, qpos, qw, qb, Dn, Dn, Dn, SCALEf, 0);

  // 6. cross attention (CHUNK=256 flash, fp16 K/V + fp16 staged bias)
  flash_kernel<<<dim3(NQn / 8, Bb * Hn), dim3(256), 0, stream>>>(
      oCb, qCb, kCb, vCb, biasb, NSn);

  // 7. cross out-proj, split-K x2 -> partials
  gemm32_kernel<<<dim3(Dn / 32, MQ / 32, 2), dim3(256), 0, stream>>>(
      part, oCb, nullptr, projw, nullptr, Dn, 128, Dn, 1.f, 0);

  // 8. tgt3 = LN1(tgt2 + sum(part) + projb)
  reduce_ln_kernel<<<dim3(MQ), dim3(256), 0, stream>>>(
      tgt3, part, projb, tgt2, ln1g, ln1b, 2);

  // 9. FFN1 (relu) as gemm32: 512 blocks (full GPU)
  gemm32_kernel<<<dim3(FFNn / 32, MQ / 32, 1), dim3(256), 0, stream>>>(
      ffh, tgt3, nullptr, ff1w, ff1b, FFNn, Dn, Dn, 1.f, 1);

  // 10. FFN2 split-K x4 -> partials
  gemm32_kernel<<<dim3(Dn / 32, MQ / 32, 4), dim3(256), 0, stream>>>(
      part, ffh, nullptr, ff2w, nullptr, Dn, 256, FFNn, 1.f, 0);

  // 11. out = LN3(tgt3 + sum(part) + ff2b)
  reduce_ln_kernel<<<dim3(MQ), dim3(256), 0, stream>>>(
      out, part, ff2b, tgt3, ln3g, ln3b, 4);
}

// Round 23
// 103.464 us; speedup vs baseline: 1.2293x; 1.0024x over previous
//
#include <hip/hip_runtime.h>
#include <hip/hip_bf16.h>
#include <hip/hip_fp16.h>
#include <math.h>

#define Bb 2
#define NQn 256
#define NSn 1024
#define Dn 256
#define Hn 8
#define DHn 32
#define FFNn 1024
#define RPEn 512
#define SCALEf 0.17677669529663687f
#define EPSf 1e-5f

#if defined(__has_builtin)
#if __has_builtin(__builtin_amdgcn_fdot2)
#define HAS_FDOT2 1
#endif
#endif
#ifndef HAS_FDOT2
#define HAS_FDOT2 0
#endif

typedef _Float16 h2f __attribute__((ext_vector_type(2)));

// async global->LDS, 16B per lane. LDS dest must be linear in lane order
// (wave-uniform base + lane*16); global src is per-lane (pre-swizzled).
#define GLDS16(g, l)                                                         \
  __builtin_amdgcn_global_load_lds(                                          \
      (const __attribute__((address_space(1))) void*)(const void*)(g),       \
      (__attribute__((address_space(3))) void*)(void*)(l), 16, 0, 0)

__device__ __forceinline__ float fdot2e(h2f a, h2f b, float c) {
#if HAS_FDOT2
  return __builtin_amdgcn_fdot2(a, b, c, false);
#else
  return c + (float)a.x * (float)b.x + (float)a.y * (float)b.y;
#endif
}

// ---------------------------------------------------------------------------
// gemm64h body (r21): 64x64 tile, 512 threads, K-step 32, float4 loads with
// reg prefetch; A and W staged as PACKED FP16 (h2f); inner loop = 16 k-pairs
// x 8 v_dot2_f32_f16 with f32 accumulation. Epilogue: f32 acc + bias + scale
// + relu; trsh != 0 writes transposed head-major FP16.
// ---------------------------------------------------------------------------
__device__ __forceinline__ void gemm64h_body(
    float* __restrict__ C, __half* __restrict__ Ch, int ldc,
    const float* __restrict__ A, const float* __restrict__ A2, int ld,
    const float* __restrict__ W, const float* __restrict__ bias,
    int K, int bm, int bnC, int bnW, float scale, int do_relu, int trsh,
    float* smem)
{
  h2f (*Ah)[17] = (h2f(*)[17])smem;            // [row][kpair]
  h2f (*WhT)[68] = (h2f(*)[68])(smem + 1088);  // [kpair][col]
  const int tid = threadIdx.x;
  const int tx = tid & 15, ty = tid >> 4;       // ty 0..31
  const int lr = tid >> 3, lc = (tid & 7) * 4;  // staging: row, k-offset
  const int lp = lc >> 1;                       // k-pair index
  float4 ra, rw;
  {
    ra = *(const float4*)(A + (size_t)(bm + lr) * ld + lc);
    if (A2) {
      float4 t = *(const float4*)(A2 + (size_t)(bm + lr) * ld + lc);
      ra.x += t.x; ra.y += t.y; ra.z += t.z; ra.w += t.w;
    }
    rw = *(const float4*)(W + (size_t)(bnW + lr) * ld + lc);
  }
  float acc[2][4] = {};
  for (int k0 = 0; k0 < K; k0 += 32) {
    {
      h2f a01, a23, w01, w23;
      a01.x = (_Float16)ra.x; a01.y = (_Float16)ra.y;
      a23.x = (_Float16)ra.z; a23.y = (_Float16)ra.w;
      w01.x = (_Float16)rw.x; w01.y = (_Float16)rw.y;
      w23.x = (_Float16)rw.z; w23.y = (_Float16)rw.w;
      Ah[lr][lp] = a01; Ah[lr][lp + 1] = a23;
      WhT[lp][lr] = w01; WhT[lp + 1][lr] = w23;
    }
    __syncthreads();
    if (k0 + 32 < K) {
      ra = *(const float4*)(A + (size_t)(bm + lr) * ld + k0 + 32 + lc);
      if (A2) {
        float4 t = *(const float4*)(A2 + (size_t)(bm + lr) * ld + k0 + 32 + lc);
        ra.x += t.x; ra.y += t.y; ra.z += t.z; ra.w += t.w;
      }
      rw = *(const float4*)(W + (size_t)(bnW + lr) * ld + k0 + 32 + lc);
    }
#pragma unroll
    for (int kp = 0; kp < 16; ++kp) {
      h2f a0 = Ah[ty][kp], a1 = Ah[ty + 32][kp];
      float4 wr = *(const float4*)&WhT[kp][tx * 4];
      const h2f* wp = (const h2f*)&wr;
      acc[0][0] = fdot2e(a0, wp[0], acc[0][0]);
      acc[0][1] = fdot2e(a0, wp[1], acc[0][1]);
      acc[0][2] = fdot2e(a0, wp[2], acc[0][2]);
      acc[0][3] = fdot2e(a0, wp[3], acc[0][3]);
      acc[1][0] = fdot2e(a1, wp[0], acc[1][0]);
      acc[1][1] = fdot2e(a1, wp[1], acc[1][1]);
      acc[1][2] = fdot2e(a1, wp[2], acc[1][2]);
      acc[1][3] = fdot2e(a1, wp[3], acc[1][3]);
    }
    __syncthreads();
  }
#pragma unroll
  for (int i = 0; i < 2; ++i) {
    int m = bm + ty + i * 32;
#pragma unroll
    for (int j = 0; j < 4; ++j) {
      float v = acc[i][j];
      if (bias) v += bias[bnW + tx * 4 + j];
      v *= scale;
      if (do_relu) v = fmaxf(v, 0.f);
      if (trsh == 0) {
        C[(size_t)m * ldc + bnC + tx * 4 + j] = v;
      } else {
        const int nC = bnC + tx * 4 + j;
        const int bb = m >> trsh, kseq = m & ((1 << trsh) - 1);
        const int hh = nC >> 5, d = nC & 31;
        Ch[((((size_t)(bb * Hn + hh)) << trsh) + kseq) * 32 + d] =
            __float2half(v);
      }
    }
  }
}

// ---------------------------------------------------------------------------
// prep: fused build_cpb (1 block) + self QKV GEMM (96 blocks; K/V written
// head-major transposed fp16) + cross KV GEMM (256 blocks). 512 threads.
// ---------------------------------------------------------------------------
__global__ __launch_bounds__(512) void prep_kernel(
    float* __restrict__ qSb, __half* __restrict__ kSb, __half* __restrict__ vSb,
    __half* __restrict__ kCb, __half* __restrict__ vCb,
    const float* __restrict__ tgt, const float* __restrict__ qpos,
    const float* __restrict__ src, const float* __restrict__ spe,
    const float* __restrict__ ipw, const float* __restrict__ ipb,
    const float* __restrict__ kw, const float* __restrict__ kb,
    const float* __restrict__ vw, const float* __restrict__ vb,
    const float* __restrict__ w1p, const float* __restrict__ b1p,
    const float* __restrict__ w2p,
    float* __restrict__ tout, float* __restrict__ Stab, float* __restrict__ Btab)
{
  __shared__ float smem[4288];
  const int bx = blockIdx.x;
  const int tid = threadIdx.x;
  if (bx < 96) {
    int my = bx & 7, nx = bx >> 3;
    int sec = nx >> 2;
    gemm64h_body(qSb, sec == 1 ? kSb : vSb, Dn, tgt,
                 sec < 2 ? qpos : nullptr, Dn, ipw, ipb,
                 Dn, my * 64, (nx & 3) * 64, nx * 64,
                 sec == 0 ? SCALEf : 1.f, 0, sec == 0 ? 0 : 8, smem);
    return;
  }
  if (bx < 96 + 256) {
    int idx = bx - 96;
    int my = idx & 31, nx = idx >> 5;
    int sec = nx >> 2;
    gemm64h_body(nullptr, sec ? vCb : kCb, Dn, src, sec ? nullptr : spe, Dn,
                 sec ? vw : kw, sec ? vb : kb,
                 Dn, my * 64, (nx & 3) * 64, (nx & 3) * 64, 1.f, 0, 10, smem);
    return;
  }
  // ---- cpb piecewise-linear table build (verified rounds 1-22) ----
  float* key = smem;
  int* pidx = (int*)(smem + 512);
  float* w1s = smem + 1024;
  float* b1s = smem + 1536;
  {
    float w = w1p[tid], bb = b1p[tid];
    key[tid] = (w != 0.f) ? (-bb / w) : 3.0e38f;
    pidx[tid] = tid;
  }
  __syncthreads();
  for (int k = 2; k <= RPEn; k <<= 1) {
    for (int j = k >> 1; j > 0; j >>= 1) {
      int ixj = tid ^ j;
      if (ixj > tid) {
        float a = key[tid], c = key[ixj];
        bool asc = ((tid & k) == 0);
        bool sw = asc ? (a > c) : (a < c);
        if (sw) {
          key[tid] = c; key[ixj] = a;
          int tmp = pidx[tid]; pidx[tid] = pidx[ixj]; pidx[ixj] = tmp;
        }
      }
      __syncthreads();
    }
  }
  w1s[tid] = w1p[pidx[tid]];
  b1s[tid] = b1p[pidx[tid]];
  tout[tid] = key[tid];
  __syncthreads();
  const int lane = tid & 63;
  const int h = tid >> 6;
  const int j0 = lane * 8;
  float sp[8], bp[8], sn[8], bn[8];
  float csp = 0.f, cbp = 0.f, csn = 0.f, cbn = 0.f, ccc = 0.f;
#pragma unroll
  for (int e = 0; e < 8; ++e) {
    int j = j0 + e;
    float w = w1s[j], b = b1s[j];
    float c = w2p[h * RPEn + pidx[j]];
    sp[e] = csp; bp[e] = cbp; sn[e] = csn; bn[e] = cbn;
    if (w > 0.f)      { csp += w * c; cbp += b * c; }
    else if (w < 0.f) { csn += w * c; cbn += b * c; }
    else              { ccc += fmaxf(b, 0.f) * c; }
  }
  float isp = csp, ibp = cbp, isn = csn, ibn = cbn, icc = ccc;
#pragma unroll
  for (int d = 1; d < 64; d <<= 1) {
    float t0 = __shfl_up(isp, d);
    float t1 = __shfl_up(ibp, d);
    float t2 = __shfl_up(isn, d);
    float t3 = __shfl_up(ibn, d);
    if (lane >= d) { isp += t0; ibp += t1; isn += t2; ibn += t3; }
    icc += __shfl_xor(icc, d);
  }
  const float tsn = __shfl(isn, 63);
  const float tbn = __shfl(ibn, 63);
  const float esp = isp - csp, ebp = ibp - cbp;
  const float esn = isn - csn, ebn = ibn - cbn;
#pragma unroll
  for (int e = 0; e < 8; ++e) {
    int j = j0 + e;
    Stab[j * Hn + h] = (esp + sp[e]) + (tsn - (esn + sn[e]));
    Btab[j * Hn + h] = (ebp + bp[e]) + (tbn - (ebn + bn[e])) + icc;
  }
  if (lane == 63) {
    Stab[RPEn * Hn + h] = isp;
    Btab[RPEn * Hn + h] = ibp + icc;
  }
}

// ---------------------------------------------------------------------------
// bias body: fp16 bias[b,h,q,k] = Sh[lo]*m + Bh[lo] - 100*pad.
// ---------------------------------------------------------------------------
__device__ __forceinline__ void bias_body(
    char* smemraw, int idx,
    __half* __restrict__ biasb, const float* __restrict__ rel,
    const float* __restrict__ pad, const float* __restrict__ tsg,
    const float* __restrict__ Stabg, const float* __restrict__ Btabg)
{
  float* ts = (float*)smemraw;                    // 512 f
  float* Sh = (float*)(smemraw + 2048);           // 4104 f
  float* Bh = (float*)(smemraw + 18464);          // 4104 f
  const int tid = threadIdx.x;
  const int b = idx >> 8, q = idx & 255;
  ts[tid] = tsg[tid];
  ts[tid + 256] = tsg[tid + 256];
  for (int i = tid; i < (RPEn + 1) * Hn; i += 256) {
    Sh[i] = Stabg[i];
    Bh[i] = Btabg[i];
  }
  __syncthreads();
#pragma unroll
  for (int j = 0; j < 4; ++j) {
    const int k = tid + j * 256;
    const float m = rel[((size_t)b * NQn + q) * NSn + k];
    const float padv = -100.f * pad[b * NSn + k];
    int lo = 0, hi = RPEn;
#pragma unroll
    for (int it = 0; it < 9; ++it) {
      int mid = (lo + hi) >> 1;
      if (ts[mid] < m) lo = mid + 1; else hi = mid;
    }
#pragma unroll
    for (int h = 0; h < Hn; ++h) {
      biasb[(((size_t)(b * Hn + h)) * NQn + q) * NSn + k] =
          __float2half(Sh[lo * Hn + h] * m + Bh[lo * Hn + h] + padv);
    }
  }
}

// ---------------------------------------------------------------------------
// Flash body, templated on CHUNK. R=2 rows/thread, HEAD-MAJOR FP16 K/V.
// r19 QK fdot2; r20 packed-fp16 PV; r23: O written as FP16 (halved writes,
// feeds the fp16-A gemm32 path).
// ---------------------------------------------------------------------------
template <int CHUNK>
__device__ __forceinline__ void flash_body(
    char* smemraw, int qb, int bh,
    __half* __restrict__ O, const float* __restrict__ Q,
    const __half* __restrict__ kT, const __half* __restrict__ vT,
    const __half* __restrict__ biasb, int NK)
{
  constexpr int NJ = CHUNK / 64;
  constexpr int NS = CHUNK / 64;
  float4 (*Ks)[CHUNK * 4] = (float4(*)[CHUNK * 4])smemraw;
  float4 (*Vs)[CHUNK * 4] = (float4(*)[CHUNK * 4])(smemraw + CHUNK * 128);
  float4* Qs = (float4*)(smemraw + CHUNK * 256);
  const int b = bh >> 3, h = bh & 7;
  const int q0 = qb * 8;
  const int tid = threadIdx.x;
  const int w = tid >> 6, kc = tid & 63;
  const float4* Ktp = (const float4*)kT + (size_t)bh * NK * 4;
  const float4* Vtp = (const float4*)vT + (size_t)bh * NK * 4;
  if (tid < 64)
    Qs[tid] = ((const float4*)Q)[(size_t)(b * NQn + q0 + (tid >> 3)) * 64 +
                                 h * 8 + (tid & 7)];

  const __half* brow0 =
      biasb ? biasb + ((size_t)bh * NQn + q0 + 2 * w) * NK : nullptr;
  const __half* brow1 = biasb ? brow0 + NK : nullptr;

  auto stage = [&](int buf, int kb0) {
#pragma unroll
    for (int u = 0; u < NS; ++u) {
      const int s = tid + u * 256;
      const int k = s >> 2, e = s & 3;
      const int ok = (k + (k >> 2)) & 3;
      const int g = (kb0 + k) * 4 + ((e - ok) & 3);
      GLDS16(Ktp + g, &Ks[buf][s]);
      GLDS16(Vtp + g, &Vs[buf][s]);
    }
  };

  stage(0, 0);
  float cb[2][NJ];
  if (biasb) {
#pragma unroll
    for (int j = 0; j < NJ; ++j) {
      cb[0][j] = __half2float(brow0[kc + j * 64]);
      cb[1][j] = __half2float(brow1[kc + j * 64]);
    }
  }
  __syncthreads();

  h2f qh[2][16];
#pragma unroll
  for (int dd = 0; dd < 8; ++dd) {
    float4 v0 = Qs[(2 * w) * 8 + dd];
    float4 v1 = Qs[(2 * w + 1) * 8 + dd];
    h2f t;
    t.x = (_Float16)v0.x; t.y = (_Float16)v0.y; qh[0][2 * dd] = t;
    t.x = (_Float16)v0.z; t.y = (_Float16)v0.w; qh[0][2 * dd + 1] = t;
    t.x = (_Float16)v1.x; t.y = (_Float16)v1.y; qh[1][2 * dd] = t;
    t.x = (_Float16)v1.z; t.y = (_Float16)v1.w; qh[1][2 * dd + 1] = t;
  }
  h2f oh[2][16];
#pragma unroll
  for (int i = 0; i < 16; ++i) {
    oh[0][i] = (h2f)(_Float16)0;
    oh[1][i] = (h2f)(_Float16)0;
  }
  float m_run[2] = {-3.0e38f, -3.0e38f};
  float l_run[2] = {0.f, 0.f};
  const int nchunk = NK / CHUNK;
  const int ox = (kc + (kc >> 2)) & 3;

  for (int c = 0; c < nchunk; ++c) {
    const int cur = c & 1;
    float nb[2][NJ];
    if (c + 1 < nchunk) {
      stage(cur ^ 1, (c + 1) * CHUNK);
      if (biasb) {
#pragma unroll
        for (int j = 0; j < NJ; ++j) {
          nb[0][j] = __half2float(brow0[(c + 1) * CHUNK + kc + j * 64]);
          nb[1][j] = __half2float(brow1[(c + 1) * CHUNK + kc + j * 64]);
        }
      }
    }
    float s[2][NJ];
#pragma unroll
    for (int j = 0; j < NJ; ++j) {
      const int kbase = (kc + j * 64) * 4;
      float a0 = 0.f, a1 = 0.f;
#pragma unroll
      for (int u = 0; u < 4; ++u) {
        float4 raw = Ks[cur][kbase + ((u + ox) & 3)];
        const h2f* kp = (const h2f*)&raw;
#pragma unroll
        for (int m2 = 0; m2 < 4; ++m2) {
          a0 = fdot2e(qh[0][4 * u + m2], kp[m2], a0);
          a1 = fdot2e(qh[1][4 * u + m2], kp[m2], a1);
        }
      }
      s[0][j] = a0;
      s[1][j] = a1;
      if (biasb) { s[0][j] += cb[0][j]; s[1][j] += cb[1][j]; }
    }
    float f[2];
#pragma unroll
    for (int r = 0; r < 2; ++r) {
      float cmax = s[r][0];
#pragma unroll
      for (int j = 1; j < NJ; ++j) cmax = fmaxf(cmax, s[r][j]);
#pragma unroll
      for (int off = 1; off < 64; off <<= 1)
        cmax = fmaxf(cmax, __shfl_xor(cmax, off));
      const float m_new = fmaxf(m_run[r], cmax);
      f[r] = __expf(m_run[r] - m_new);
      float ls = 0.f;
#pragma unroll
      for (int j = 0; j < NJ; ++j) {
        s[r][j] = __expf(s[r][j] - m_new);
        ls += s[r][j];
      }
#pragma unroll
      for (int off = 1; off < 64; off <<= 1) ls += __shfl_xor(ls, off);
      l_run[r] = l_run[r] * f[r] + ls;
      m_run[r] = m_new;
    }
    {
      h2f f0h, f1h;
      f0h.x = (_Float16)f[0]; f0h.y = f0h.x;
      f1h.x = (_Float16)f[1]; f1h.y = f1h.x;
#pragma unroll
      for (int i = 0; i < 16; ++i) {
        oh[0][i] *= f0h;   // v_pk_mul_f16
        oh[1][i] *= f1h;
      }
    }
#pragma unroll
    for (int j = 0; j < NJ; ++j) {
      const int kbase = (kc + j * 64) * 4;
      h2f p0h, p1h;
      p0h.x = (_Float16)s[0][j]; p0h.y = p0h.x;
      p1h.x = (_Float16)s[1][j]; p1h.y = p1h.x;
#pragma unroll
      for (int u = 0; u < 4; ++u) {
        float4 raw = Vs[cur][kbase + ((u + ox) & 3)];
        const h2f* vp = (const h2f*)&raw;
#pragma unroll
        for (int m2 = 0; m2 < 4; ++m2) {
          oh[0][4 * u + m2] += p0h * vp[m2];   // v_pk_fma_f16
          oh[1][4 * u + m2] += p1h * vp[m2];
        }
      }
    }
    if (biasb && c + 1 < nchunk) {
#pragma unroll
      for (int j = 0; j < NJ; ++j) {
        cb[0][j] = nb[0][j];
        cb[1][j] = nb[1][j];
      }
    }
    __syncthreads();
  }
  // convert fp16 accumulators to f32 once, then cross-lane reduce
  float4 o[2][8];
#pragma unroll
  for (int dd = 0; dd < 8; ++dd) {
#pragma unroll
    for (int r = 0; r < 2; ++r) {
      o[r][dd].x = (float)oh[r][2 * dd].x;
      o[r][dd].y = (float)oh[r][2 * dd].y;
      o[r][dd].z = (float)oh[r][2 * dd + 1].x;
      o[r][dd].w = (float)oh[r][2 * dd + 1].y;
    }
  }
#pragma unroll
  for (int off = 1; off < 64; off <<= 1) {
#pragma unroll
    for (int dd = 0; dd < 8; ++dd) {
      o[0][dd].x += __shfl_xor(o[0][dd].x, off);
      o[0][dd].y += __shfl_xor(o[0][dd].y, off);
      o[0][dd].z += __shfl_xor(o[0][dd].z, off);
      o[0][dd].w += __shfl_xor(o[0][dd].w, off);
      o[1][dd].x += __shfl_xor(o[1][dd].x, off);
      o[1][dd].y += __shfl_xor(o[1][dd].y, off);
      o[1][dd].z += __shfl_xor(o[1][dd].z, off);
      o[1][dd].w += __shfl_xor(o[1][dd].w, off);
    }
  }
  if (kc == 0) {
    const float inv = 1.f / l_run[0];
    __half2* op = (__half2*)(O + (size_t)(b * NQn + q0 + 2 * w) * Dn + h * DHn);
#pragma unroll
    for (int dd = 0; dd < 8; ++dd) {
      op[2 * dd]     = __floats2half2_rn(o[0][dd].x * inv, o[0][dd].y * inv);
      op[2 * dd + 1] = __floats2half2_rn(o[0][dd].z * inv, o[0][dd].w * inv);
    }
  } else if (kc == 1) {
    const float inv = 1.f / l_run[1];
    __half2* op =
        (__half2*)(O + (size_t)(b * NQn + q0 + 2 * w + 1) * Dn + h * DHn);
#pragma unroll
    for (int dd = 0; dd < 8; ++dd) {
      op[2 * dd]     = __floats2half2_rn(o[1][dd].x * inv, o[1][dd].y * inv);
      op[2 * dd + 1] = __floats2half2_rn(o[1][dd].z * inv, o[1][dd].w * inv);
    }
  }
}

// ---------------------------------------------------------------------------
// fsb: fused flash-self (blocks 0..511, CHUNK=128) + bias materialization.
// ---------------------------------------------------------------------------
__global__ __launch_bounds__(256, 2) void fsb_kernel(
    __half* __restrict__ O, const float* __restrict__ Q,
    const __half* __restrict__ kT, const __half* __restrict__ vT,
    __half* __restrict__ biasb, const float* __restrict__ rel,
    const float* __restrict__ pad, const float* __restrict__ tsg,
    const float* __restrict__ Stabg, const float* __restrict__ Btabg)
{
  __shared__ __align__(16) char smem[34880];
  const int bx = blockIdx.x;
  if (bx < 512) {
    flash_body<128>(smem, bx & 31, bx >> 5, O, Q, kT, vT, nullptr, NQn);
  } else {
    bias_body(smem, bx - 512, biasb, rel, pad, tsg, Stabg, Btabg);
  }
}

// ---------------------------------------------------------------------------
// flash standalone (cross, CHUNK=256): grid (NQ/8, B*H), 256 threads.
// ---------------------------------------------------------------------------
__global__ __launch_bounds__(256, 2) void flash_kernel(
    __half* __restrict__ O, const float* __restrict__ Q,
    const __half* __restrict__ kT, const __half* __restrict__ vT,
    const __half* __restrict__ biasb, int NK)
{
  __shared__ __align__(16) char smem[66560];
  flash_body<256>(smem, blockIdx.x, blockIdx.y, O, Q, kT, vT, biasb, NK);
}

// ---------------------------------------------------------------------------
// gemm32h (r22/r23): 32x32 tile, 256 threads, K-step 32, reg prefetch;
// fp16 LDS staging + fdot2 inner loop (f32 acc). Templates:
//   AHALF: A is fp16 global (8B/thread loads, no cvt in staging; A2 ignored)
//   CHALF: C stored as fp16. Split-K via blockIdx.z. relu opt.
// ---------------------------------------------------------------------------
template <int AHALF, int CHALF>
__global__ __launch_bounds__(256) void gemm32_kernel(
    void* __restrict__ Cv, const void* __restrict__ Av,
    const float* __restrict__ A2,
    const float* __restrict__ W, const float* __restrict__ bias,
    int N, int Kchunk, int Ktot, float scale, int do_relu)
{
  __shared__ h2f Ah[32][17];
  __shared__ h2f Wh[32][17];
  const int bm = blockIdx.y * 32, bn = blockIdx.x * 32;
  const int kz = blockIdx.z;
  const int M = gridDim.y * 32;
  const int tid = threadIdx.x;
  const int tx = tid & 15, ty = tid >> 4;
  const int lr = tid >> 3, lc = (tid & 7) * 4;
  const int lp = lc >> 1;  // k-pair index
  float acc[2][2] = {};
  const int k00 = kz * Kchunk;
  float4 av;
  float2 avh;
  float4 wv;
  if (AHALF) {
    avh = *(const float2*)((const __half*)Av +
                           (size_t)(bm + lr) * Ktot + k00 + lc);
  } else {
    av = *(const float4*)((const float*)Av +
                          (size_t)(bm + lr) * Ktot + k00 + lc);
    if (A2) {
      float4 bv = *(const float4*)(A2 + (size_t)(bm + lr) * Ktot + k00 + lc);
      av.x += bv.x; av.y += bv.y; av.z += bv.z; av.w += bv.w;
    }
  }
  wv = *(const float4*)(W + (size_t)(bn + lr) * Ktot + k00 + lc);
  for (int k0 = k00; k0 < k00 + Kchunk; k0 += 32) {
    {
      if (AHALF) {
        const h2f* pr = (const h2f*)&avh;
        Ah[lr][lp] = pr[0]; Ah[lr][lp + 1] = pr[1];
      } else {
        h2f a01, a23;
        a01.x = (_Float16)av.x; a01.y = (_Float16)av.y;
        a23.x = (_Float16)av.z; a23.y = (_Float16)av.w;
        Ah[lr][lp] = a01; Ah[lr][lp + 1] = a23;
      }
      h2f w01, w23;
      w01.x = (_Float16)wv.x; w01.y = (_Float16)wv.y;
      w23.x = (_Float16)wv.z; w23.y = (_Float16)wv.w;
      Wh[lr][lp] = w01; Wh[lr][lp + 1] = w23;
    }
    __syncthreads();
    if (k0 + 32 < k00 + Kchunk) {
      if (AHALF) {
        avh = *(const float2*)((const __half*)Av +
                               (size_t)(bm + lr) * Ktot + k0 + 32 + lc);
      } else {
        av = *(const float4*)((const float*)Av +
                              (size_t)(bm + lr) * Ktot + k0 + 32 + lc);
        if (A2) {
          float4 bv =
              *(const float4*)(A2 + (size_t)(bm + lr) * Ktot + k0 + 32 + lc);
          av.x += bv.x; av.y += bv.y; av.z += bv.z; av.w += bv.w;
        }
      }
      wv = *(const float4*)(W + (size_t)(bn + lr) * Ktot + k0 + 32 + lc);
    }
#pragma unroll
    for (int kp = 0; kp < 16; ++kp) {
      h2f a0 = Ah[ty * 2][kp], a1 = Ah[ty * 2 + 1][kp];
      h2f w0 = Wh[tx * 2][kp], w1 = Wh[tx * 2 + 1][kp];
      acc[0][0] = fdot2e(a0, w0, acc[0][0]);
      acc[0][1] = fdot2e(a0, w1, acc[0][1]);
      acc[1][0] = fdot2e(a1, w0, acc[1][0]);
      acc[1][1] = fdot2e(a1, w1, acc[1][1]);
    }
    __syncthreads();
  }
#pragma unroll
  for (int i = 0; i < 2; ++i) {
    int m = bm + ty * 2 + i;
#pragma unroll
    for (int j = 0; j < 2; ++j) {
      int n = bn + tx * 2 + j;
      float v = acc[i][j];
      if (bias) v += bias[n];
      v *= scale;
      if (do_relu) v = fmaxf(v, 0.f);
      if (CHALF) {
        ((__half*)Cv)[(size_t)kz * M * N + (size_t)m * N + n] = __float2half(v);
      } else {
        ((float*)Cv)[(size_t)kz * M * N + (size_t)m * N + n] = v;
      }
    }
  }
}

// ---------------------------------------------------------------------------
// out = LayerNorm(resid + sum_{s<nsplit} part[s] + bias) * g + b.
// ---------------------------------------------------------------------------
__global__ __launch_bounds__(256) void reduce_ln_kernel(
    float* __restrict__ out, const float* __restrict__ part,
    const float* __restrict__ bias, const float* __restrict__ resid,
    const float* __restrict__ g, const float* __restrict__ bt, int nsplit)
{
  const int row = blockIdx.x;
  const int t = threadIdx.x;
  const size_t idx = (size_t)row * Dn + t;
  const size_t STR = (size_t)Bb * NQn * Dn;
  float v = bias[t] + resid[idx];
  for (int s = 0; s < nsplit; ++s) v += part[idx + (size_t)s * STR];
  float sm = v, s2 = v * v;
#pragma unroll
  for (int off = 32; off > 0; off >>= 1) {
    sm += __shfl_down(sm, off);
    s2 += __shfl_down(s2, off);
  }
  __shared__ float rs[4], rs2[4], fin[2];
  const int lane = t & 63, wid = t >> 6;
  if (lane == 0) { rs[wid] = sm; rs2[wid] = s2; }
  __syncthreads();
  if (t == 0) {
    float a = rs[0] + rs[1] + rs[2] + rs[3];
    float a2 = rs2[0] + rs2[1] + rs2[2] + rs2[3];
    float mean = a * (1.f / Dn);
    float var = a2 * (1.f / Dn) - mean * mean;
    fin[0] = mean;
    fin[1] = rsqrtf(var + EPSf);
  }
  __syncthreads();
  out[idx] = (v - fin[0]) * fin[1] * g[t] + bt[t];
}

extern "C" void kernel_launch(void* const* d_in, const int* in_sizes, int n_in,
                              void* d_out, int out_size, void* d_ws, size_t ws_size,
                              hipStream_t stream)
{
  const float* tgt   = (const float*)d_in[0];
  const float* qpos  = (const float*)d_in[1];
  const float* src   = (const float*)d_in[2];
  const float* spe   = (const float*)d_in[3];
  const float* pad   = (const float*)d_in[4];
  const float* rel   = (const float*)d_in[5];
  const float* qw    = (const float*)d_in[6];
  const float* qb    = (const float*)d_in[7];
  const float* kw    = (const float*)d_in[8];
  const float* kb    = (const float*)d_in[9];
  const float* vw    = (const float*)d_in[10];
  const float* vb    = (const float*)d_in[11];
  const float* projw = (const float*)d_in[12];
  const float* projb = (const float*)d_in[13];
  const float* cpbw1 = (const float*)d_in[14];
  const float* cpbb1 = (const float*)d_in[15];
  const float* cpbw2 = (const float*)d_in[16];
  const float* ipw   = (const float*)d_in[17];
  const float* ipb   = (const float*)d_in[18];
  const float* outw  = (const float*)d_in[19];
  const float* outb  = (const float*)d_in[20];
  const float* ln1g  = (const float*)d_in[21];
  const float* ln1b  = (const float*)d_in[22];
  const float* ln2g  = (const float*)d_in[23];
  const float* ln2b  = (const float*)d_in[24];
  const float* ln3g  = (const float*)d_in[25];
  const float* ln3b  = (const float*)d_in[26];
  const float* ff1w  = (const float*)d_in[27];
  const float* ff1b  = (const float*)d_in[28];
  const float* ff2w  = (const float*)d_in[29];
  const float* ff2b  = (const float*)d_in[30];
  float* out = (float*)d_out;
  float* ws = (float*)d_ws;

  constexpr size_t SZ_Q   = (size_t)Bb * NQn * Dn;   // 131072
  constexpr size_t SZ_S   = (size_t)Bb * NSn * Dn;   // 524288
  constexpr size_t SZ_FFH = (size_t)Bb * NQn * FFNn; // 524288

  float* qSb  = ws;
  __half* kSb = (__half*)(qSb + SZ_Q);   // head-major fp16 kT (self)
  __half* vSb = (__half*)(qSb + 2 * SZ_Q);
  __half* oSb = (__half*)(ws + 3 * SZ_Q);   // fp16 self-attn output (r23)
  float* soP  = ws + 3 * SZ_Q + SZ_Q;       // (layout stability)
  float* tgt2 = soP + SZ_Q;
  float* qCb  = tgt2 + SZ_Q;
  __half* kCb = (__half*)(qCb + SZ_Q);   // head-major fp16 kT (cross)
  __half* vCb = (__half*)(qCb + SZ_Q + SZ_S);
  __half* oCb = (__half*)(qCb + SZ_Q + 2 * SZ_S);  // fp16 cross-attn output
  float* coP  = qCb + SZ_Q + 2 * SZ_S + SZ_Q;      // (layout stability)
  float* tgt3 = coP + SZ_Q;
  __half* ffh = (__half*)(tgt3 + SZ_Q);            // fp16 FFN hidden (r23)
  float* part = tgt3 + SZ_Q + SZ_FFH;    // 4 * SZ_Q partials scratch
  float* tsb  = part + 4 * SZ_Q;
  float* Stab = tsb + RPEn;
  float* Btab = Stab + (RPEn + 1) * Hn;
  __half* biasb = (__half*)(Btab + (RPEn + 1) * Hn);

  const int MQ = Bb * NQn;  // 512

  // 1. prep: cpb tables + self QKV + cross KV (fp16/fdot2 GEMM bodies)
  prep_kernel<<<dim3(96 + 256 + 1), dim3(512), 0, stream>>>(
      qSb, kSb, vSb, kCb, vCb, tgt, qpos, src, spe, ipw, ipb,
      kw, kb, vw, vb, cpbw1, cpbb1, cpbw2, tsb, Stab, Btab);

  // 2. fused: flash self (512 blocks, fp16 O) + fp16 bias materialization
  fsb_kernel<<<dim3(1024), dim3(256), 0, stream>>>(
      oSb, qSb, kSb, vSb, biasb, rel, pad, tsb, Stab, Btab);

  // 3. self out-proj (fp16 A), split-K x2 -> partials
  gemm32_kernel<1, 0><<<dim3(Dn / 32, MQ / 32, 2), dim3(256), 0, stream>>>(
      part, oSb, nullptr, outw, nullptr, Dn, 128, Dn, 1.f, 0);

  // 4. tgt2 = LN2(tgt + sum(part) + outb)
  reduce_ln_kernel<<<dim3(MQ), dim3(256), 0, stream>>>(
      tgt2, part, outb, tgt, ln2g, ln2b, 2);

  // 5. cross q (f32 A + qpos)
  gemm32_kernel<0, 0><<<dim3(Dn / 32, MQ / 32, 1), dim3(256), 0, stream>>>(
      qCb, tgt2, qpos, qw, qb, Dn, Dn, Dn, SCALEf, 0);

  // 6. cross attention (CHUNK=256 flash, fp16 K/V/bias, fp16 O)
  flash_kernel<<<dim3(NQn / 8, Bb * Hn), dim3(256), 0, stream>>>(
      oCb, qCb, kCb, vCb, biasb, NSn);

  // 7. cross out-proj (fp16 A), split-K x2 -> partials
  gemm32_kernel<1, 0><<<dim3(Dn / 32, MQ / 32, 2), dim3(256), 0, stream>>>(
      part, oCb, nullptr, projw, nullptr, Dn, 128, Dn, 1.f, 0);

  // 8. tgt3 = LN1(tgt2 + sum(part) + projb)
  reduce_ln_kernel<<<dim3(MQ), dim3(256), 0, stream>>>(
      tgt3, part, projb, tgt2, ln1g, ln1b, 2);

  // 9. FFN1 (relu, fp16 C): 512 blocks (full GPU)
  gemm32_kernel<0, 1><<<dim3(FFNn / 32, MQ / 32, 1), dim3(256), 0, stream>>>(
      ffh, tgt3, nullptr, ff1w, ff1b, FFNn, Dn, Dn, 1.f, 1);

  // 10. FFN2 (fp16 A) split-K x4 -> partials
  gemm32_kernel<1, 0><<<dim3(Dn / 32, MQ / 32, 4), dim3(256), 0, stream>>>(
      part, ffh, nullptr, ff2w, nullptr, Dn, 256, FFNn, 1.f, 0);

  // 11. out = LN3(tgt3 + sum(part) + ff2b)
  reduce_ln_kernel<<<dim3(MQ), dim3(256), 0, stream>>>(
      out, part, ff2b, tgt3, ln3g, ln3b, 4);
}